// Round 11
// baseline (993.438 us; speedup 1.0000x reference)
//
#include <hip/hip_runtime.h>
#include <cfloat>
#include <cstdint>

#define B_  8
#define L_  4096
#define DM  1024
#define NH  16
#define DH  64
#define SK  45

typedef __attribute__((ext_vector_type(4))) float f32x4;
typedef _Float16 f16;
typedef __attribute__((ext_vector_type(4))) _Float16 f16x4;
typedef __attribute__((ext_vector_type(8))) _Float16 f16x8;

__device__ __forceinline__ void gload_lds16(const void* g, void* l) {
  __builtin_amdgcn_global_load_lds(
      (const __attribute__((address_space(1))) unsigned int*)g,
      (__attribute__((address_space(3))) unsigned int*)l, 16, 0, 0);
}

// XOR-swizzled f16 index into a [rows][32] f16 tile (64B rows), granule 8 f16.
__device__ __forceinline__ int swz(int row, int c) {
  return row * 32 + (c ^ (((row >> 1) & 3) << 3));
}

// ---------------- x f32 -> f16 hi ----------------
__global__ __launch_bounds__(256) void xsplit16_kernel(const float* __restrict__ x,
    f16* __restrict__ xh, int n4) {
  int i = blockIdx.x * 256 + threadIdx.x;
  int stride = gridDim.x * 256;
  for (; i < n4; i += stride) {
    f32x4 v = ((const f32x4*)x)[i];
    f16x4 h;
    #pragma unroll
    for (int j = 0; j < 4; ++j) h[j] = (f16)v[j];
    ((f16x4*)xh)[i] = h;
  }
}

// ---------------- W f32 -> f16 hi (+ scaled lo) ----------------
__global__ __launch_bounds__(256) void wsplit16_kernel(const float* __restrict__ w,
    f16* __restrict__ wh, f16* __restrict__ wl, int n4, int withlo) {
  int i = blockIdx.x * 256 + threadIdx.x;
  int stride = gridDim.x * 256;
  for (; i < n4; i += stride) {
    f32x4 v = ((const f32x4*)w)[i];
    f16x4 h, l;
    #pragma unroll
    for (int j = 0; j < 4; ++j) {
      h[j] = (f16)v[j];
      l[j] = (f16)((v[j] - (float)h[j]) * 2048.0f);
    }
    ((f16x4*)wh)[i] = h;
    if (withlo) ((f16x4*)wl)[i] = l;
  }
}

// ---------------- mean over L from XH (f16) ----------------
__global__ __launch_bounds__(256) void meansum_kernel(const f16* __restrict__ xh,
                                                      float* __restrict__ meanx) {
  int b = blockIdx.x;
  int d = blockIdx.y * 256 + threadIdx.x;
  int l0 = blockIdx.z * 256;
  const f16* p = xh + ((size_t)b * L_ + l0) * DM + d;
  float s = 0.f;
  for (int i = 0; i < 256; ++i) s += (float)p[(size_t)i * DM];
  atomicAdd(&meanx[b * DM + d], s);
}

// f32 mean fallback (small-ws diagnostic path)
__global__ __launch_bounds__(256) void meansum32_kernel(const float* __restrict__ x,
                                                        float* __restrict__ meanx) {
  int b = blockIdx.x;
  int d = blockIdx.y * 256 + threadIdx.x;
  int l0 = blockIdx.z * 256;
  const float* p = x + ((size_t)b * L_ + l0) * DM + d;
  float s = 0.f;
  for (int i = 0; i < 256; ++i) s += p[(size_t)i * DM];
  atomicAdd(&meanx[b * DM + d], s);
}

// vout(b,n) = (vin(b,:) . W[n,:]) * scale + bias[n]
__global__ __launch_bounds__(256) void proj_vec_kernel(const float* __restrict__ vin,
    const float* __restrict__ W, const float* __restrict__ bias,
    float* __restrict__ vout, float scale) {
  int g = blockIdx.x * 256 + threadIdx.x;
  int b = g >> 10, n = g & 1023;
  const float* xr = vin + b * DM;
  const float* wr = W + (size_t)n * DM;
  float a0 = 0, a1 = 0, a2 = 0, a3 = 0;
  for (int d = 0; d < DM; d += 4) {
    a0 += xr[d + 0] * wr[d + 0];
    a1 += xr[d + 1] * wr[d + 1];
    a2 += xr[d + 2] * wr[d + 2];
    a3 += xr[d + 3] * wr[d + 3];
  }
  vout[g] = ((a0 + a1) + (a2 + a3)) * scale + bias[n];
}

// ---------------- k_sample rows, f32 LDS-tiled: KS[b][s][n] ----------------
__global__ __launch_bounds__(256, 4) void ksample_kernel(const float* __restrict__ x,
    const float* __restrict__ Wk, const float* __restrict__ bk,
    const int* __restrict__ sidx, float* __restrict__ KS) {
  const int b = blockIdx.x, nc = blockIdx.y, sg = blockIdx.z;
  __shared__ float xs[5][32];
  __shared__ float wk[64][33];
  __shared__ float red[4][5][64];
  __shared__ int ls[5];
  const int tid = threadIdx.x;
  const int nl = tid & 63, kq = tid >> 6;
  if (tid < 5) ls[tid] = sidx[sg * 5 + tid];
  float acc[5] = {0.f, 0.f, 0.f, 0.f, 0.f};
  const int wrow = tid >> 2, wq = tid & 3;
  for (int kt = 0; kt < 32; ++kt) {
    const int d0 = kt * 32;
    __syncthreads();
    if (tid < 40) {
      int s = tid >> 3, q = tid & 7;
      *(f32x4*)&xs[s][q * 4] = *(const f32x4*)&x[((size_t)b * L_ + ls[s]) * DM + d0 + q * 4];
    }
    {
      const float* src = &Wk[(size_t)(nc * 64 + wrow) * DM + d0 + wq * 8];
      *(f32x4*)&wk[wrow][wq * 8]     = *(const f32x4*)src;
      *(f32x4*)&wk[wrow][wq * 8 + 4] = *(const f32x4*)(src + 4);
    }
    __syncthreads();
    #pragma unroll
    for (int i = 0; i < 2; ++i) {
      f32x4 w = *(const f32x4*)&wk[nl][kq * 8 + i * 4];
      #pragma unroll
      for (int s = 0; s < 5; ++s) {
        f32x4 xv = *(const f32x4*)&xs[s][kq * 8 + i * 4];
        acc[s] += xv[0] * w[0] + xv[1] * w[1] + xv[2] * w[2] + xv[3] * w[3];
      }
    }
  }
  #pragma unroll
  for (int s = 0; s < 5; ++s) red[kq][s][nl] = acc[s];
  __syncthreads();
  for (int t = tid; t < 5 * 64; t += 256) {
    int s = t >> 6, j = t & 63;
    int nj = nc * 64 + j;
    KS[((size_t)b * SK + sg * 5 + s) * DM + nj] =
        red[0][s][j] + red[1][s][j] + red[2][s][j] + red[3][s][j] + bk[nj];
  }
}

// ---- P[b][h*48+s][n] = sum_d Wq[h*64+d][n] * KS[b][s][h*64+d], f16-split out -----
__global__ __launch_bounds__(256, 4) void pcomp_kernel(const float* __restrict__ Wq,
    const float* __restrict__ KS, f16* __restrict__ PH, f16* __restrict__ PL) {
  const int b = blockIdx.x, h = blockIdx.y;
  __shared__ float ks[45][64];
  __shared__ float wqT[64][68];
  const int tid = threadIdx.x;
  for (int i = tid; i < 45 * 64; i += 256) {
    int s = i >> 6, d = i & 63;
    ks[s][d] = KS[((size_t)b * SK + s) * DM + h * 64 + d];
  }
  for (int nc = 0; nc < 16; ++nc) {
    const int n0 = nc * 64;
    __syncthreads();   // nc=0: ks staged; nc>0: prior wqT reads done
    for (int t = tid; t < 1024; t += 256) {
      int row = t >> 4, cg = t & 15;
      f32x4 v = *(const f32x4*)&Wq[(size_t)(h * 64 + row) * DM + n0 + cg * 4];
      #pragma unroll
      for (int j = 0; j < 4; ++j) wqT[cg * 4 + j][row] = v[j];
    }
    __syncthreads();
    for (int t = tid; t < 48 * 64; t += 256) {
      int s = t >> 6, c = t & 63;
      float acc = 0.f;
      if (s < SK) {
        const f32x4* wr = (const f32x4*)&wqT[c][0];
        const f32x4* kr = (const f32x4*)&ks[s][0];
        float a0 = 0, a1 = 0, a2 = 0, a3 = 0;
        #pragma unroll
        for (int i = 0; i < 16; ++i) {
          f32x4 wv = wr[i], kv = kr[i];
          a0 += wv[0] * kv[0]; a1 += wv[1] * kv[1];
          a2 += wv[2] * kv[2]; a3 += wv[3] * kv[3];
        }
        acc = (a0 + a1) + (a2 + a3);
      }
      f16 hv = (f16)acc;
      size_t off = ((size_t)b * 768 + h * 48 + s) * DM + n0 + c;
      PH[off] = hv;
      PL[off] = (f16)((acc - (float)hv) * 2048.0f);
    }
  }
}

// ---- scores GEMM: SC[b*4096+l][col] = 0.125 * (x @ P^T), f16-split, N=768 --------
__global__ __launch_bounds__(256, 2) void gemm_sc(const float* __restrict__ x,
    const f16* __restrict__ PH, const f16* __restrict__ PL,
    float* __restrict__ SC) {
  __shared__ f16 xh[128 * 32];
  __shared__ f16 xl[128 * 32];
  __shared__ f16 wh[128 * 32];
  __shared__ f16 wl[128 * 32];
  const int tid = threadIdx.x;
  const int g = blockIdx.y * 8 + blockIdx.x;    // XCD = g & 7
  const int q = g >> 3;                          // 0..191
  const int nt = q % 6;                          // N-tile cycles fastest
  const int mt = (g & 7) + (q / 6) * 8;          // A-panel pinned to XCD
  const int n0 = nt * 128;
  const int m0 = mt * 128;
  const int bb = mt >> 5;                        // batch of this M-tile
  const int lane = tid & 63;
  const int wave = tid >> 6;
  const int wr = (wave >> 1) * 64;
  const int wc = (wave & 1) * 64;
  const int frow = lane & 15;
  const int fk = (lane >> 4) * 8;

  f32x4 aH[4][4], aL[4][4];
  #pragma unroll
  for (int i = 0; i < 4; ++i)
    #pragma unroll
    for (int j = 0; j < 4; ++j)
      #pragma unroll
      for (int z = 0; z < 4; ++z) { aH[i][j][z] = 0.f; aL[i][j][z] = 0.f; }

  const int ar = tid >> 1;
  const int ac = (tid & 1) * 16;
  const int r2 = tid >> 2;
  const int cb = (tid & 3) * 8;
  const int cbs = cb ^ (((r2 >> 1) & 3) << 3);

  const size_t pbase = (size_t)bb * 768;
  for (int kt = 0; kt < 32; ++kt) {
    const float* gx = x + (size_t)(m0 + ar) * DM + kt * 32 + ac;
    #pragma unroll
    for (int gi = 0; gi < 4; ++gi) {
      f32x4 v = ((const f32x4*)gx)[gi];
      f16x4 h, l;
      #pragma unroll
      for (int z = 0; z < 4; ++z) {
        h[z] = (f16)v[z];
        l[z] = (f16)((v[z] - (float)h[z]) * 2048.0f);
      }
      *(f16x4*)(xh + swz(ar, ac + gi * 4)) = h;
      *(f16x4*)(xl + swz(ar, ac + gi * 4)) = l;
    }
    gload_lds16(PH + (pbase + n0 + r2) * DM + kt * 32 + cbs,      wh + r2 * 32 + cb);
    gload_lds16(PH + (pbase + n0 + r2 + 64) * DM + kt * 32 + cbs, wh + (r2 + 64) * 32 + cb);
    gload_lds16(PL + (pbase + n0 + r2) * DM + kt * 32 + cbs,      wl + r2 * 32 + cb);
    gload_lds16(PL + (pbase + n0 + r2 + 64) * DM + kt * 32 + cbs, wl + (r2 + 64) * 32 + cb);
    __syncthreads();
    f16x8 ah[4], al[4], bh[4], bl[4];
    #pragma unroll
    for (int mi = 0; mi < 4; ++mi) {
      ah[mi] = *(const f16x8*)(xh + swz(wr + mi * 16 + frow, fk));
      al[mi] = *(const f16x8*)(xl + swz(wr + mi * 16 + frow, fk));
    }
    #pragma unroll
    for (int ni = 0; ni < 4; ++ni) {
      bh[ni] = *(const f16x8*)(wh + swz(wc + ni * 16 + frow, fk));
      bl[ni] = *(const f16x8*)(wl + swz(wc + ni * 16 + frow, fk));
    }
    #pragma unroll
    for (int mi = 0; mi < 4; ++mi)
      #pragma unroll
      for (int ni = 0; ni < 4; ++ni) {
        aH[mi][ni] = __builtin_amdgcn_mfma_f32_16x16x32_f16(ah[mi], bh[ni], aH[mi][ni], 0, 0, 0);
        aL[mi][ni] = __builtin_amdgcn_mfma_f32_16x16x32_f16(ah[mi], bl[ni], aL[mi][ni], 0, 0, 0);
        aL[mi][ni] = __builtin_amdgcn_mfma_f32_16x16x32_f16(al[mi], bh[ni], aL[mi][ni], 0, 0, 0);
      }
    __syncthreads();
  }

  #pragma unroll
  for (int mi = 0; mi < 4; ++mi) {
    int rowb = m0 + wr + mi * 16 + (lane >> 4) * 4;
    #pragma unroll
    for (int ni = 0; ni < 4; ++ni) {
      int col = n0 + wc + ni * 16 + (lane & 15);
      #pragma unroll
      for (int j = 0; j < 4; ++j) {
        SC[(size_t)(rowb + j) * 768 + col] =
            (aH[mi][ni][j] + aL[mi][ni][j] * (1.0f / 2048.0f)) * 0.125f;
      }
    }
  }
}

// ---------------- m = max - mean over the 45 sampled scores -----------------------
__global__ __launch_bounds__(256) void mcompute_kernel(const float* __restrict__ SC,
    float* __restrict__ Mout) {
  const int b = blockIdx.x;
  const int l = blockIdx.y * 16 + (threadIdx.x >> 4);
  const int h = threadIdx.x & 15;
  const float* p = SC + ((size_t)(b * L_ + l)) * 768 + h * 48;
  float mx = -FLT_MAX, sum = 0.f;
  #pragma unroll
  for (int i = 0; i < 11; ++i) {
    f32x4 v = *(const f32x4*)(p + i * 4);
    #pragma unroll
    for (int j = 0; j < 4; ++j) { mx = fmaxf(mx, v[j]); sum += v[j]; }
  }
  { float v = p[44]; mx = fmaxf(mx, v); sum += v; }
  Mout[((size_t)(b * NH + h)) * L_ + l] = mx - sum * (1.0f / SK);
}

// ---------------- top-45 per (b,h): iterative argmax ----------------
__global__ __launch_bounds__(256) void topk_kernel(const float* __restrict__ M,
                                                   int* __restrict__ topi) {
  __shared__ float vals[L_];
  __shared__ float wv[4];
  __shared__ int wi[4];
  const int bh = blockIdx.x, tid = threadIdx.x;
  for (int i = tid; i < L_; i += 256) vals[i] = M[(size_t)bh * L_ + i];
  __syncthreads();
  const int lane = tid & 63, wave = tid >> 6;
  for (int it = 0; it < SK; ++it) {
    float best = -FLT_MAX;
    int bi = 1 << 30;
    for (int i = tid; i < L_; i += 256) {
      float v = vals[i];
      if (v > best || (v == best && i < bi)) { best = v; bi = i; }
    }
    #pragma unroll
    for (int off = 32; off; off >>= 1) {
      float ov = __shfl_down(best, off);
      int oi = __shfl_down(bi, off);
      if (ov > best || (ov == best && oi < bi)) { best = ov; bi = oi; }
    }
    if (lane == 0) { wv[wave] = best; wi[wave] = bi; }
    __syncthreads();
    if (tid == 0) {
      float bb = wv[0]; int bj = wi[0];
      for (int w = 1; w < 4; ++w)
        if (wv[w] > bb || (wv[w] == bb && wi[w] < bj)) { bb = wv[w]; bj = wi[w]; }
      topi[bh * SK + it] = bj;
      vals[bj] = -FLT_MAX;
    }
    __syncthreads();
  }
}

// ---------------- q_top recompute (f16-split, exact rows): QT[bh][48][64] ---------
__global__ __launch_bounds__(256) void qtop_kernel(const float* __restrict__ x,
    const f16* __restrict__ WQH, const f16* __restrict__ WQL,
    const float* __restrict__ bq, const int* __restrict__ topi,
    f16* __restrict__ QT) {
  __shared__ f16 xsh[48 * 32], xsl[48 * 32];
  __shared__ f16 wqh[64 * 32], wql[64 * 32];
  __shared__ int lidx[48];
  const int bh = blockIdx.x;
  const int b = bh >> 4, h = bh & 15;
  const int tid = threadIdx.x;
  const int lane = tid & 63;
  const int frow = lane & 15, fk = (lane >> 4) * 8;
  if (tid < 48) lidx[tid] = (tid < SK) ? topi[bh * SK + tid] : 0;
  f32x4 accH[3][4], accL[3][4];
  #pragma unroll
  for (int i = 0; i < 3; ++i)
    #pragma unroll
    for (int j = 0; j < 4; ++j)
      #pragma unroll
      for (int z = 0; z < 4; ++z) { accH[i][j][z] = 0.f; accL[i][j][z] = 0.f; }
  const int r2 = tid >> 2, cb = (tid & 3) * 8;
  const int cbs = cb ^ (((r2 >> 1) & 3) << 3);
  for (int kt = 0; kt < 32; ++kt) {
    __syncthreads();   // kt=0: lidx ready; kt>0: prior frag reads done
    for (int i = tid; i < 48 * 32; i += 256) {
      int u = i >> 5, c = i & 31;
      float v = (u < SK) ? x[((size_t)b * L_ + lidx[u]) * DM + kt * 32 + c] : 0.f;
      f16 hv = (f16)v;
      xsh[swz(u, c)] = hv;
      xsl[swz(u, c)] = (f16)((v - (float)hv) * 2048.0f);
    }
    gload_lds16(WQH + (size_t)(h * 64 + r2) * DM + kt * 32 + cbs, wqh + r2 * 32 + cb);
    gload_lds16(WQL + (size_t)(h * 64 + r2) * DM + kt * 32 + cbs, wql + r2 * 32 + cb);
    __syncthreads();
    f16x8 ah[3], al[3], wbh[4], wbl[4];
    #pragma unroll
    for (int mu = 0; mu < 3; ++mu) {
      ah[mu] = *(const f16x8*)(xsh + swz(mu * 16 + frow, fk));
      al[mu] = *(const f16x8*)(xsl + swz(mu * 16 + frow, fk));
    }
    #pragma unroll
    for (int ni = 0; ni < 4; ++ni) {
      wbh[ni] = *(const f16x8*)(wqh + swz(ni * 16 + frow, fk));
      wbl[ni] = *(const f16x8*)(wql + swz(ni * 16 + frow, fk));
    }
    #pragma unroll
    for (int mu = 0; mu < 3; ++mu)
      #pragma unroll
      for (int ni = 0; ni < 4; ++ni) {
        accH[mu][ni] = __builtin_amdgcn_mfma_f32_16x16x32_f16(ah[mu], wbh[ni], accH[mu][ni], 0, 0, 0);
        accL[mu][ni] = __builtin_amdgcn_mfma_f32_16x16x32_f16(ah[mu], wbl[ni], accL[mu][ni], 0, 0, 0);
        accL[mu][ni] = __builtin_amdgcn_mfma_f32_16x16x32_f16(al[mu], wbh[ni], accL[mu][ni], 0, 0, 0);
      }
  }
  #pragma unroll
  for (int mu = 0; mu < 3; ++mu)
    #pragma unroll
    for (int ni = 0; ni < 4; ++ni) {
      int d = ni * 16 + (lane & 15);
      float bc = bq[h * 64 + d];
      #pragma unroll
      for (int z = 0; z < 4; ++z) {
        int u = mu * 16 + (lane >> 4) * 4 + z;
        QT[bh * 3072 + u * 64 + d] = (u < SK)
            ? (f16)(accH[mu][ni][z] + accL[mu][ni][z] * (1.0f / 2048.0f) + bc)
            : (f16)0.f;
      }
    }
}

// ---------------- fused K+V GEMM + raw scores: S f16, V f16 (d-major) to d_out ----
__global__ __launch_bounds__(256, 2) void kscore_kernel(const f16* __restrict__ XH,
    const f16* __restrict__ WKH, const f16* __restrict__ WVH,
    const float* __restrict__ bk, const float* __restrict__ bvec,
    const f16* __restrict__ QT, f16* __restrict__ S, f16* __restrict__ Vg) {
  __shared__ __align__(16) char smem[68352];
  f16* qs = (f16*)smem;
  f16* xh = (f16*)(smem + 6912);
  f16* wh = (f16*)(smem + 23296);
  f16* Kt = (f16*)(smem + 31488);
  f16* Vt = Kt;
  const int g = blockIdx.y * 128 + blockIdx.x;  // XCD = g & 7
  const int b = g & 7;
  const int p = g >> 3;
  const int jc = p >> 4;
  const int h = p & 15;
  const int bh = b * 16 + h;
  const int tid = threadIdx.x;
  const int lane = tid & 63, wave = tid >> 6;
  const int frow = lane & 15;
  const int fk = (lane >> 4) * 8;

  for (int i = tid; i < 48 * 64; i += 256)
    qs[(i >> 6) * 72 + (i & 63)] = QT[bh * 3072 + i];

  f32x4 accK[4][4], accV[4][4];
  #pragma unroll
  for (int i = 0; i < 4; ++i)
    #pragma unroll
    for (int j = 0; j < 4; ++j)
      #pragma unroll
      for (int z = 0; z < 4; ++z) { accK[i][j][z] = 0.f; accV[i][j][z] = 0.f; }

  const int r2 = tid >> 2, cb = (tid & 3) * 8;
  const int cbs = cb ^ (((r2 >> 1) & 3) << 3);
  for (int kt = 0; kt < 32; ++kt) {
    #pragma unroll
    for (int i = 0; i < 4; ++i)
      gload_lds16(XH + (size_t)(b * L_ + jc * 256 + i * 64 + r2) * DM + kt * 32 + cbs,
                  xh + (i * 64 + r2) * 32 + cb);
    gload_lds16(WKH + (size_t)(h * 64 + r2) * DM + kt * 32 + cbs, wh + r2 * 32 + cb);
    gload_lds16(WVH + (size_t)(h * 64 + r2) * DM + kt * 32 + cbs, wh + (r2 + 64) * 32 + cb);
    __syncthreads();
    f16x8 am[4], bnK[4], bnV[4];
    #pragma unroll
    for (int mi = 0; mi < 4; ++mi)
      am[mi] = *(const f16x8*)(xh + swz(wave * 64 + mi * 16 + frow, fk));
    #pragma unroll
    for (int ni = 0; ni < 4; ++ni) {
      bnK[ni] = *(const f16x8*)(wh + swz(ni * 16 + frow, fk));
      bnV[ni] = *(const f16x8*)(wh + swz(64 + ni * 16 + frow, fk));
    }
    #pragma unroll
    for (int mi = 0; mi < 4; ++mi)
      #pragma unroll
      for (int ni = 0; ni < 4; ++ni) {
        accK[mi][ni] = __builtin_amdgcn_mfma_f32_16x16x32_f16(am[mi], bnK[ni], accK[mi][ni], 0, 0, 0);
        accV[mi][ni] = __builtin_amdgcn_mfma_f32_16x16x32_f16(am[mi], bnV[ni], accV[mi][ni], 0, 0, 0);
      }
    __syncthreads();
  }

  #pragma unroll
  for (int mi = 0; mi < 4; ++mi) {
    int jl = wave * 64 + mi * 16 + (lane >> 4) * 4;
    #pragma unroll
    for (int ni = 0; ni < 4; ++ni) {
      int d = ni * 16 + (lane & 15);
      float bc = bk[h * 64 + d];
      #pragma unroll
      for (int z = 0; z < 4; ++z)
        Kt[(jl + z) * 72 + d] = (f16)(accK[mi][ni][z] + bc);
    }
  }
  __syncthreads();

  f32x4 accS[3][4];
  #pragma unroll
  for (int i = 0; i < 3; ++i)
    #pragma unroll
    for (int j = 0; j < 4; ++j)
      #pragma unroll
      for (int z = 0; z < 4; ++z) accS[i][j][z] = 0.f;
  #pragma unroll
  for (int ks = 0; ks < 2; ++ks) {
    f16x8 aq[3], bv[4];
    #pragma unroll
    for (int mu = 0; mu < 3; ++mu)
      aq[mu] = *(const f16x8*)(qs + (mu * 16 + frow) * 72 + ks * 32 + fk);
    #pragma unroll
    for (int nj = 0; nj < 4; ++nj)
      bv[nj] = *(const f16x8*)(Kt + (wave * 64 + nj * 16 + frow) * 72 + ks * 32 + fk);
    #pragma unroll
    for (int mu = 0; mu < 3; ++mu)
      #pragma unroll
      for (int nj = 0; nj < 4; ++nj)
        accS[mu][nj] = __builtin_amdgcn_mfma_f32_16x16x32_f16(aq[mu], bv[nj], accS[mu][nj], 0, 0, 0);
  }
  __syncthreads();   // all Kt/qs reads done before Vt (aliased) is written

  #pragma unroll
  for (int mi = 0; mi < 4; ++mi) {
    int jl = wave * 64 + mi * 16 + (lane >> 4) * 4;
    #pragma unroll
    for (int ni = 0; ni < 4; ++ni) {
      int d = ni * 16 + (lane & 15);
      float bc = bvec[h * 64 + d];
      #pragma unroll
      for (int z = 0; z < 4; ++z)
        Vt[d * 264 + jl + z] = (f16)(accV[mi][ni][z] + bc);
    }
  }
  __syncthreads();

  for (int t = tid; t < 64 * 32; t += 256) {
    int d = t >> 5, j8 = t & 31;
    f16x8 v = *(const f16x8*)(Vt + d * 264 + j8 * 8);
    *(f16x8*)(Vg + ((size_t)bh * 64 + d) * L_ + jc * 256 + j8 * 8) = v;
  }

  #pragma unroll
  for (int mu = 0; mu < 3; ++mu) {
    #pragma unroll
    for (int nj = 0; nj < 4; ++nj) {
      int j = jc * 256 + wave * 64 + nj * 16 + (lane & 15);
      #pragma unroll
      for (int z = 0; z < 4; ++z) {
        int u = mu * 16 + (lane >> 4) * 4 + z;
        if (u < SK)
          S[((size_t)bh * SK + u) * L_ + j] = (f16)(accS[mu][nj][z] * 0.125f);
      }
    }
  }
}

// ---------------- PV: unnormalized exp, Z via atomics, V from global --------------
__global__ __launch_bounds__(256, 2) void pv_kernel(const f16* __restrict__ S,
    const f16* __restrict__ Vg, float* __restrict__ OT, float* __restrict__ Zb) {
  __shared__ float red[4 * 48 * 64];
  const int g = blockIdx.y * 128 + blockIdx.x;
  const int b = g & 7;
  const int p = g >> 3;
  const int jc = p >> 4;
  const int h = p & 15;
  const int bh = b * 16 + h;
  const int tid = threadIdx.x;
  const int lane = tid & 63, wave = tid >> 6;
  const int frow = lane & 15;
  const int fk = (lane >> 4) * 8;

  f32x4 accO[3][4];
  float zacc[3] = {0.f, 0.f, 0.f};
  #pragma unroll
  for (int i = 0; i < 3; ++i)
    #pragma unroll
    for (int j = 0; j < 4; ++j)
      #pragma unroll
      for (int z = 0; z < 4; ++z) accO[i][j][z] = 0.f;

  #pragma unroll
  for (int ks = 0; ks < 2; ++ks) {
    f16x8 ap[3], bv[4];
    #pragma unroll
    for (int mu = 0; mu < 3; ++mu) {
      int urow = mu * 16 + frow;
      int ur = (urow < SK) ? urow : 0;
      const f16* aptr = S + ((size_t)bh * SK + ur) * L_ + jc * 256 + wave * 64 + ks * 32 + fk;
      f16x8 raw = *(const f16x8*)aptr;
      f16x8 pp;
      float zs = 0.f;
      #pragma unroll
      for (int j = 0; j < 8; ++j) {
        f16 e = (f16)__expf((float)raw[j]);
        pp[j] = e;
        zs += (float)e;
      }
      zacc[mu] += zs;
      ap[mu] = pp;
    }
    #pragma unroll
    for (int nd = 0; nd < 4; ++nd)
      bv[nd] = *(const f16x8*)(Vg + ((size_t)bh * 64 + nd * 16 + frow) * L_ +
                               jc * 256 + wave * 64 + ks * 32 + fk);
    #pragma unroll
    for (int mu = 0; mu < 3; ++mu)
      #pragma unroll
      for (int nd = 0; nd < 4; ++nd)
        accO[mu][nd] = __builtin_amdgcn_mfma_f32_16x16x32_f16(ap[mu], bv[nd], accO[mu][nd], 0, 0, 0);
  }

  #pragma unroll
  for (int mu = 0; mu < 3; ++mu) {
    float z = zacc[mu];
    z += __shfl_xor(z, 16);
    z += __shfl_xor(z, 32);
    int u = mu * 16 + frow;
    if ((lane >> 4) == 0 && u < SK) atomicAdd(&Zb[bh * 48 + u], z);
  }

  #pragma unroll
  for (int mu = 0; mu < 3; ++mu) {
    #pragma unroll
    for (int nd = 0; nd < 4; ++nd) {
      int d = nd * 16 + (lane & 15);
      #pragma unroll
      for (int z = 0; z < 4; ++z) {
        int u = mu * 16 + (lane >> 4) * 4 + z;
        red[wave * 3072 + u * 64 + d] = accO[mu][nd][z];
      }
    }
  }
  __syncthreads();
  for (int i = tid; i < 3072; i += 256) {
    int u = i >> 6;
    if (u < SK)
      atomicAdd(&OT[((size_t)bh * SK + u) * DH + (i & 63)],
                red[i] + red[3072 + i] + red[6144 + i] + red[9216 + i]);
  }
}

// ---------------- out = broadcast(base) ----------------
__global__ __launch_bounds__(256) void basewrite_kernel(const float* __restrict__ base,
                                                        float* __restrict__ out) {
  size_t i = (size_t)blockIdx.x * 256 + threadIdx.x;
  const size_t stride = (size_t)gridDim.x * 256;
  const size_t total = (size_t)B_ * L_ * (DM / 4);
  for (; i < total; i += stride) {
    size_t b = i >> 20;
    size_t c = i & 255;
    ((f32x4*)out)[i] = ((const f32x4*)base)[b * 256 + c];
  }
}

// ---------------- corrections: out[b, top_u, n] += (OT/Z - MV) . Wo[n, h*64:] -----
__global__ __launch_bounds__(256, 2) void corr_kernel(const float* __restrict__ OT,
    const float* __restrict__ Zb, const float* __restrict__ MV,
    const float* __restrict__ Wo, const int* __restrict__ topi,
    float* __restrict__ out) {
  __shared__ float dv[SK][64];
  __shared__ float wo[64][65];
  __shared__ float invz[SK];
  __shared__ int lidx[SK];
  const int bh = blockIdx.x, q = blockIdx.y, tid = threadIdx.x;
  const int b = bh >> 4, h = bh & 15;
  if (tid < SK) {
    invz[tid] = 1.0f / Zb[bh * 48 + tid];
    lidx[tid] = topi[bh * SK + tid];
  }
  __syncthreads();
  for (int i = tid; i < SK * 64; i += 256) {
    int u = i >> 6, d = i & 63;
    dv[u][d] = OT[((size_t)bh * SK + u) * DH + d] * invz[u] - MV[b * DM + h * DH + d];
  }
  const int nn = tid & 63, ug = tid >> 6;
  for (int c = 0; c < 4; ++c) {
    const int n0 = q * 256 + c * 64;
    __syncthreads();
    for (int t = tid; t < 1024; t += 256) {
      int row = t >> 4, vc = t & 15;
      f32x4 v = *(const f32x4*)&Wo[(size_t)(n0 + row) * DM + h * DH + vc * 4];
      *(f32x4*)&wo[row][vc * 4] = v;
    }
    __syncthreads();
    #pragma unroll
    for (int i = 0; i < 12; ++i) {
      int u = ug + i * 4;
      if (u >= SK) break;
      float a0 = 0, a1 = 0, a2 = 0, a3 = 0;
      #pragma unroll
      for (int d4 = 0; d4 < 16; ++d4) {
        f32x4 w = *(const f32x4*)&wo[nn][d4 * 4];
        f32x4 dd = *(const f32x4*)&dv[u][d4 * 4];
        a0 += dd[0] * w[0]; a1 += dd[1] * w[1];
        a2 += dd[2] * w[2]; a3 += dd[3] * w[3];
      }
      atomicAdd(&out[((size_t)b * L_ + lidx[u]) * DM + n0 + nn], (a0 + a1) + (a2 + a3));
    }
  }
}

// ---------------- workspace layout (unchanged size, PH/PL overlay S) --------------
static const size_t OFF_XH   = 0;                        // 67108864
static const size_t OFF_WQH  = OFF_XH + 67108864;        // 2097152
static const size_t OFF_WQL  = OFF_WQH + 2097152;
static const size_t OFF_WKH  = OFF_WQL + 2097152;
static const size_t OFF_WVH  = OFF_WKH + 2097152;
static const size_t OFF_KS   = OFF_WVH + 2097152;        // 1474560
static const size_t OFF_M    = OFF_KS + 1474560;         // 2097152
static const size_t OFF_TOPI = OFF_M + 2097152;          // 23040
static const size_t OFF_MEANX= OFF_TOPI + 23040;         // 32768
static const size_t OFF_MV   = OFF_MEANX + 32768;
static const size_t OFF_BASE = OFF_MV + 32768;
static const size_t OFF_ZB   = OFF_BASE + 32768;         // 24576
static const size_t OFF_QT   = OFF_ZB + 24576;           // 786432
static const size_t OFF_S    = OFF_QT + 786432;          // 47185920 (PH/PL overlay: 2x12582912)
static const size_t OFF_OT   = OFF_S + 47185920;         // 1474560
static const size_t WS_NEED  = OFF_OT + 1474560;

extern "C" void kernel_launch(void* const* d_in, const int* in_sizes, int n_in,
                              void* d_out, int out_size, void* d_ws, size_t ws_size,
                              hipStream_t stream) {
  const float* x  = (const float*)d_in[0];
  const float* Wq = (const float*)d_in[1];
  const float* bq = (const float*)d_in[2];
  const float* Wk = (const float*)d_in[3];
  const float* bk = (const float*)d_in[4];
  const float* Wv = (const float*)d_in[5];
  const float* bv = (const float*)d_in[6];
  const float* Wo = (const float*)d_in[7];
  const float* bo = (const float*)d_in[8];
  const int* sidx = (const int*)d_in[9];
  float* out = (float*)d_out;
  char* ws = (char*)d_ws;

  if (ws_size < WS_NEED) {
    if (ws_size < 131072) return;
    float* MEANX = (float*)(ws + 0);
    float* MV    = (float*)(ws + 32768);
    float* BASE  = (float*)(ws + 65536);
    hipMemsetAsync(MEANX, 0, 32768, stream);
    meansum32_kernel<<<dim3(B_, 4, 16), 256, 0, stream>>>(x, MEANX);
    proj_vec_kernel<<<32, 256, 0, stream>>>(MEANX, Wv, bv, MV, 1.0f / L_);
    proj_vec_kernel<<<32, 256, 0, stream>>>(MV, Wo, bo, BASE, 1.0f);
    basewrite_kernel<<<2048, 256, 0, stream>>>(BASE, out);
    return;
  }

  f16*   XH   = (f16*)(ws + OFF_XH);
  f16*   WQH  = (f16*)(ws + OFF_WQH);
  f16*   WQL  = (f16*)(ws + OFF_WQL);
  f16*   WKH  = (f16*)(ws + OFF_WKH);
  f16*   WVH  = (f16*)(ws + OFF_WVH);
  float* KS   = (float*)(ws + OFF_KS);
  float* Mb   = (float*)(ws + OFF_M);
  int*   TOPI = (int*)(ws + OFF_TOPI);
  float* MEANX= (float*)(ws + OFF_MEANX);
  float* MV   = (float*)(ws + OFF_MV);
  float* BASE = (float*)(ws + OFF_BASE);
  float* ZB   = (float*)(ws + OFF_ZB);
  f16*   QT   = (f16*)(ws + OFF_QT);
  f16*   PH   = (f16*)(ws + OFF_S);              // overlay: dead before kscore
  f16*   PL   = (f16*)(ws + OFF_S + 12582912);
  f16*   Sb   = (f16*)(ws + OFF_S);
  float* OT   = (float*)(ws + OFF_OT);
  float* SC   = (float*)out;  // sampled-score matrix lives in d_out (100.7 MB)
  f16*   Vg   = (f16*)out;    // then V (67 MB) reuses d_out after SC is dead

  // 1. conversions / splits / zeroing
  xsplit16_kernel<<<2048, 256, 0, stream>>>(x, XH, (int)((size_t)B_ * L_ * DM / 4));
  wsplit16_kernel<<<256, 256, 0, stream>>>(Wq, WQH, WQL, DM * DM / 4, 1);
  wsplit16_kernel<<<256, 256, 0, stream>>>(Wk, WKH, WKH, DM * DM / 4, 0);
  wsplit16_kernel<<<256, 256, 0, stream>>>(Wv, WVH, WVH, DM * DM / 4, 0);
  hipMemsetAsync(MEANX, 0, 32768, stream);
  hipMemsetAsync(OT, 0, 1474560, stream);
  hipMemsetAsync(ZB, 0, 24576, stream);

  // 2. mean path (reads XH f16)
  meansum_kernel<<<dim3(B_, 4, 16), 256, 0, stream>>>(XH, MEANX);
  proj_vec_kernel<<<32, 256, 0, stream>>>(MEANX, Wv, bv, MV, 1.0f / L_);
  proj_vec_kernel<<<32, 256, 0, stream>>>(MV, Wo, bo, BASE, 1.0f);

  // 3. sampled K rows -> P = Wq_h^T k_s -> sampled scores GEMM (no full Q!)
  ksample_kernel<<<dim3(B_, 16, 9), 256, 0, stream>>>(x, Wk, bk, sidx, KS);
  pcomp_kernel<<<dim3(B_, NH), 256, 0, stream>>>(Wq, KS, PH, PL);
  gemm_sc<<<dim3(8, 192), 256, 0, stream>>>(x, PH, PL, SC);
  mcompute_kernel<<<dim3(B_, 256), 256, 0, stream>>>(SC, Mb);

  // 4. top-k + exact q_top recompute
  topk_kernel<<<B_ * NH, 256, 0, stream>>>(Mb, TOPI);
  qtop_kernel<<<B_ * NH, 256, 0, stream>>>(x, WQH, WQL, bq, TOPI, QT);

  // 5. fused K+V GEMM + raw scores (V -> d_out, overwrites SC), PV with exp + Z
  kscore_kernel<<<dim3(128, 16), 256, 0, stream>>>(XH, WKH, WVH, bk, bv, QT, Sb, Vg);
  pv_kernel<<<dim3(128, 16), 256, 0, stream>>>(Sb, Vg, OT, ZB);

  // 6. output assembly
  basewrite_kernel<<<2048, 256, 0, stream>>>(BASE, out);
  corr_kernel<<<dim3(B_ * NH, 4), 256, 0, stream>>>(OT, ZB, MV, Wo, TOPI, out);
}

// Round 12
// 854.337 us; speedup vs baseline: 1.1628x; 1.1628x over previous
//
#include <hip/hip_runtime.h>
#include <cfloat>
#include <cstdint>

#define B_  8
#define L_  4096
#define DM  1024
#define NH  16
#define DH  64
#define SK  45

typedef __attribute__((ext_vector_type(4))) float f32x4;
typedef _Float16 f16;
typedef __attribute__((ext_vector_type(4))) _Float16 f16x4;
typedef __attribute__((ext_vector_type(8))) _Float16 f16x8;

__device__ __forceinline__ void gload_lds16(const void* g, void* l) {
  __builtin_amdgcn_global_load_lds(
      (const __attribute__((address_space(1))) unsigned int*)g,
      (__attribute__((address_space(3))) unsigned int*)l, 16, 0, 0);
}

// XOR-swizzled f16 index into a [rows][32] f16 tile (64B rows), granule 8 f16.
__device__ __forceinline__ int swz(int row, int c) {
  return row * 32 + (c ^ (((row >> 1) & 3) << 3));
}

// ---------------- x f32 -> f16 hi ----------------
__global__ __launch_bounds__(256) void xsplit16_kernel(const float* __restrict__ x,
    f16* __restrict__ xh, int n4) {
  int i = blockIdx.x * 256 + threadIdx.x;
  int stride = gridDim.x * 256;
  for (; i < n4; i += stride) {
    f32x4 v = ((const f32x4*)x)[i];
    f16x4 h;
    #pragma unroll
    for (int j = 0; j < 4; ++j) h[j] = (f16)v[j];
    ((f16x4*)xh)[i] = h;
  }
}

// ---------------- W f32 -> f16 hi (+ scaled lo) ----------------
__global__ __launch_bounds__(256) void wsplit16_kernel(const float* __restrict__ w,
    f16* __restrict__ wh, f16* __restrict__ wl, int n4, int withlo) {
  int i = blockIdx.x * 256 + threadIdx.x;
  int stride = gridDim.x * 256;
  for (; i < n4; i += stride) {
    f32x4 v = ((const f32x4*)w)[i];
    f16x4 h, l;
    #pragma unroll
    for (int j = 0; j < 4; ++j) {
      h[j] = (f16)v[j];
      l[j] = (f16)((v[j] - (float)h[j]) * 2048.0f);
    }
    ((f16x4*)wh)[i] = h;
    if (withlo) ((f16x4*)wl)[i] = l;
  }
}

// ---------------- mean over L from XH (f16) ----------------
__global__ __launch_bounds__(256) void meansum_kernel(const f16* __restrict__ xh,
                                                      float* __restrict__ meanx) {
  int b = blockIdx.x;
  int d = blockIdx.y * 256 + threadIdx.x;
  int l0 = blockIdx.z * 256;
  const f16* p = xh + ((size_t)b * L_ + l0) * DM + d;
  float s = 0.f;
  for (int i = 0; i < 256; ++i) s += (float)p[(size_t)i * DM];
  atomicAdd(&meanx[b * DM + d], s);
}

// f32 mean fallback (small-ws diagnostic path)
__global__ __launch_bounds__(256) void meansum32_kernel(const float* __restrict__ x,
                                                        float* __restrict__ meanx) {
  int b = blockIdx.x;
  int d = blockIdx.y * 256 + threadIdx.x;
  int l0 = blockIdx.z * 256;
  const float* p = x + ((size_t)b * L_ + l0) * DM + d;
  float s = 0.f;
  for (int i = 0; i < 256; ++i) s += p[(size_t)i * DM];
  atomicAdd(&meanx[b * DM + d], s);
}

// vout(b,n) = (vin(b,:) . W[n,:]) * scale + bias[n]
__global__ __launch_bounds__(256) void proj_vec_kernel(const float* __restrict__ vin,
    const float* __restrict__ W, const float* __restrict__ bias,
    float* __restrict__ vout, float scale) {
  int g = blockIdx.x * 256 + threadIdx.x;
  int b = g >> 10, n = g & 1023;
  const float* xr = vin + b * DM;
  const float* wr = W + (size_t)n * DM;
  float a0 = 0, a1 = 0, a2 = 0, a3 = 0;
  for (int d = 0; d < DM; d += 4) {
    a0 += xr[d + 0] * wr[d + 0];
    a1 += xr[d + 1] * wr[d + 1];
    a2 += xr[d + 2] * wr[d + 2];
    a3 += xr[d + 3] * wr[d + 3];
  }
  vout[g] = ((a0 + a1) + (a2 + a3)) * scale + bias[n];
}

// ---------------- k_sample rows, f32 LDS-tiled: KS[b][s][n] ----------------
__global__ __launch_bounds__(256, 4) void ksample_kernel(const float* __restrict__ x,
    const float* __restrict__ Wk, const float* __restrict__ bk,
    const int* __restrict__ sidx, float* __restrict__ KS) {
  const int b = blockIdx.x, nc = blockIdx.y, sg = blockIdx.z;
  __shared__ float xs[5][32];
  __shared__ float wk[64][33];
  __shared__ float red[4][5][64];
  __shared__ int ls[5];
  const int tid = threadIdx.x;
  const int nl = tid & 63, kq = tid >> 6;
  if (tid < 5) ls[tid] = sidx[sg * 5 + tid];
  float acc[5] = {0.f, 0.f, 0.f, 0.f, 0.f};
  const int wrow = tid >> 2, wq = tid & 3;
  for (int kt = 0; kt < 32; ++kt) {
    const int d0 = kt * 32;
    __syncthreads();
    if (tid < 40) {
      int s = tid >> 3, q = tid & 7;
      *(f32x4*)&xs[s][q * 4] = *(const f32x4*)&x[((size_t)b * L_ + ls[s]) * DM + d0 + q * 4];
    }
    {
      const float* src = &Wk[(size_t)(nc * 64 + wrow) * DM + d0 + wq * 8];
      *(f32x4*)&wk[wrow][wq * 8]     = *(const f32x4*)src;
      *(f32x4*)&wk[wrow][wq * 8 + 4] = *(const f32x4*)(src + 4);
    }
    __syncthreads();
    #pragma unroll
    for (int i = 0; i < 2; ++i) {
      f32x4 w = *(const f32x4*)&wk[nl][kq * 8 + i * 4];
      #pragma unroll
      for (int s = 0; s < 5; ++s) {
        f32x4 xv = *(const f32x4*)&xs[s][kq * 8 + i * 4];
        acc[s] += xv[0] * w[0] + xv[1] * w[1] + xv[2] * w[2] + xv[3] * w[3];
      }
    }
  }
  #pragma unroll
  for (int s = 0; s < 5; ++s) red[kq][s][nl] = acc[s];
  __syncthreads();
  for (int t = tid; t < 5 * 64; t += 256) {
    int s = t >> 6, j = t & 63;
    int nj = nc * 64 + j;
    KS[((size_t)b * SK + sg * 5 + s) * DM + nj] =
        red[0][s][j] + red[1][s][j] + red[2][s][j] + red[3][s][j] + bk[nj];
  }
}

// ---- P[b][h*48+s][nc*64+c] = sum_d Wq[h*64+d][nc*64+c] * KS[b][s][h*64+d] --------
// grid (B, NH, 16): one 64-col chunk per block (2048 blocks).
__global__ __launch_bounds__(256, 4) void pcomp_kernel(const float* __restrict__ Wq,
    const float* __restrict__ KS, f16* __restrict__ PH, f16* __restrict__ PL) {
  const int b = blockIdx.x, h = blockIdx.y, nc = blockIdx.z;
  __shared__ float ks[45][64];
  __shared__ float wqT[64][68];
  const int tid = threadIdx.x;
  const int n0 = nc * 64;
  for (int i = tid; i < 45 * 64; i += 256) {
    int s = i >> 6, d = i & 63;
    ks[s][d] = KS[((size_t)b * SK + s) * DM + h * 64 + d];
  }
  for (int t = tid; t < 1024; t += 256) {
    int row = t >> 4, cg = t & 15;
    f32x4 v = *(const f32x4*)&Wq[(size_t)(h * 64 + row) * DM + n0 + cg * 4];
    #pragma unroll
    for (int j = 0; j < 4; ++j) wqT[cg * 4 + j][row] = v[j];
  }
  __syncthreads();
  for (int t = tid; t < 48 * 64; t += 256) {
    int s = t >> 6, c = t & 63;
    float acc = 0.f;
    if (s < SK) {
      const f32x4* wr = (const f32x4*)&wqT[c][0];
      const f32x4* kr = (const f32x4*)&ks[s][0];
      float a0 = 0, a1 = 0, a2 = 0, a3 = 0;
      #pragma unroll
      for (int i = 0; i < 16; ++i) {
        f32x4 wv = wr[i], kv = kr[i];
        a0 += wv[0] * kv[0]; a1 += wv[1] * kv[1];
        a2 += wv[2] * kv[2]; a3 += wv[3] * kv[3];
      }
      acc = (a0 + a1) + (a2 + a3);
    }
    f16 hv = (f16)acc;
    size_t off = ((size_t)b * 768 + h * 48 + s) * DM + n0 + c;
    PH[off] = hv;
    PL[off] = (f16)((acc - (float)hv) * 2048.0f);
  }
}

// ---- scores GEMM: SC[b*4096+l][col] = 0.125 * (x @ P^T), f16-split, N=768 --------
__global__ __launch_bounds__(256, 2) void gemm_sc(const float* __restrict__ x,
    const f16* __restrict__ PH, const f16* __restrict__ PL,
    float* __restrict__ SC) {
  __shared__ f16 xh[128 * 32];
  __shared__ f16 xl[128 * 32];
  __shared__ f16 wh[128 * 32];
  __shared__ f16 wl[128 * 32];
  const int tid = threadIdx.x;
  const int g = blockIdx.y * 8 + blockIdx.x;    // XCD = g & 7
  const int q = g >> 3;                          // 0..191
  const int nt = q % 6;                          // N-tile cycles fastest
  const int mt = (g & 7) + (q / 6) * 8;          // A-panel pinned to XCD
  const int n0 = nt * 128;
  const int m0 = mt * 128;
  const int bb = mt >> 5;                        // batch of this M-tile
  const int lane = tid & 63;
  const int wave = tid >> 6;
  const int wr = (wave >> 1) * 64;
  const int wc = (wave & 1) * 64;
  const int frow = lane & 15;
  const int fk = (lane >> 4) * 8;

  f32x4 aH[4][4], aL[4][4];
  #pragma unroll
  for (int i = 0; i < 4; ++i)
    #pragma unroll
    for (int j = 0; j < 4; ++j)
      #pragma unroll
      for (int z = 0; z < 4; ++z) { aH[i][j][z] = 0.f; aL[i][j][z] = 0.f; }

  const int ar = tid >> 1;
  const int ac = (tid & 1) * 16;
  const int r2 = tid >> 2;
  const int cb = (tid & 3) * 8;
  const int cbs = cb ^ (((r2 >> 1) & 3) << 3);

  const size_t pbase = (size_t)bb * 768;
  for (int kt = 0; kt < 32; ++kt) {
    const float* gx = x + (size_t)(m0 + ar) * DM + kt * 32 + ac;
    #pragma unroll
    for (int gi = 0; gi < 4; ++gi) {
      f32x4 v = ((const f32x4*)gx)[gi];
      f16x4 h, l;
      #pragma unroll
      for (int z = 0; z < 4; ++z) {
        h[z] = (f16)v[z];
        l[z] = (f16)((v[z] - (float)h[z]) * 2048.0f);
      }
      *(f16x4*)(xh + swz(ar, ac + gi * 4)) = h;
      *(f16x4*)(xl + swz(ar, ac + gi * 4)) = l;
    }
    gload_lds16(PH + (pbase + n0 + r2) * DM + kt * 32 + cbs,      wh + r2 * 32 + cb);
    gload_lds16(PH + (pbase + n0 + r2 + 64) * DM + kt * 32 + cbs, wh + (r2 + 64) * 32 + cb);
    gload_lds16(PL + (pbase + n0 + r2) * DM + kt * 32 + cbs,      wl + r2 * 32 + cb);
    gload_lds16(PL + (pbase + n0 + r2 + 64) * DM + kt * 32 + cbs, wl + (r2 + 64) * 32 + cb);
    __syncthreads();
    f16x8 ah[4], al[4], bh[4], bl[4];
    #pragma unroll
    for (int mi = 0; mi < 4; ++mi) {
      ah[mi] = *(const f16x8*)(xh + swz(wr + mi * 16 + frow, fk));
      al[mi] = *(const f16x8*)(xl + swz(wr + mi * 16 + frow, fk));
    }
    #pragma unroll
    for (int ni = 0; ni < 4; ++ni) {
      bh[ni] = *(const f16x8*)(wh + swz(wc + ni * 16 + frow, fk));
      bl[ni] = *(const f16x8*)(wl + swz(wc + ni * 16 + frow, fk));
    }
    #pragma unroll
    for (int mi = 0; mi < 4; ++mi)
      #pragma unroll
      for (int ni = 0; ni < 4; ++ni) {
        aH[mi][ni] = __builtin_amdgcn_mfma_f32_16x16x32_f16(ah[mi], bh[ni], aH[mi][ni], 0, 0, 0);
        aL[mi][ni] = __builtin_amdgcn_mfma_f32_16x16x32_f16(ah[mi], bl[ni], aL[mi][ni], 0, 0, 0);
        aL[mi][ni] = __builtin_amdgcn_mfma_f32_16x16x32_f16(al[mi], bh[ni], aL[mi][ni], 0, 0, 0);
      }
    __syncthreads();
  }

  #pragma unroll
  for (int mi = 0; mi < 4; ++mi) {
    int rowb = m0 + wr + mi * 16 + (lane >> 4) * 4;
    #pragma unroll
    for (int ni = 0; ni < 4; ++ni) {
      int col = n0 + wc + ni * 16 + (lane & 15);
      #pragma unroll
      for (int j = 0; j < 4; ++j) {
        SC[(size_t)(rowb + j) * 768 + col] =
            (aH[mi][ni][j] + aL[mi][ni][j] * (1.0f / 2048.0f)) * 0.125f;
      }
    }
  }
}

// ---------------- m = max - mean over the 45 sampled scores -----------------------
__global__ __launch_bounds__(256) void mcompute_kernel(const float* __restrict__ SC,
    float* __restrict__ Mout) {
  const int b = blockIdx.x;
  const int l = blockIdx.y * 16 + (threadIdx.x >> 4);
  const int h = threadIdx.x & 15;
  const float* p = SC + ((size_t)(b * L_ + l)) * 768 + h * 48;
  float mx = -FLT_MAX, sum = 0.f;
  #pragma unroll
  for (int i = 0; i < 11; ++i) {
    f32x4 v = *(const f32x4*)(p + i * 4);
    #pragma unroll
    for (int j = 0; j < 4; ++j) { mx = fmaxf(mx, v[j]); sum += v[j]; }
  }
  { float v = p[44]; mx = fmaxf(mx, v); sum += v; }
  Mout[((size_t)(b * NH + h)) * L_ + l] = mx - sum * (1.0f / SK);
}

// ---------------- top-45 per (b,h): iterative argmax ----------------
__global__ __launch_bounds__(256) void topk_kernel(const float* __restrict__ M,
                                                   int* __restrict__ topi) {
  __shared__ float vals[L_];
  __shared__ float wv[4];
  __shared__ int wi[4];
  const int bh = blockIdx.x, tid = threadIdx.x;
  for (int i = tid; i < L_; i += 256) vals[i] = M[(size_t)bh * L_ + i];
  __syncthreads();
  const int lane = tid & 63, wave = tid >> 6;
  for (int it = 0; it < SK; ++it) {
    float best = -FLT_MAX;
    int bi = 1 << 30;
    for (int i = tid; i < L_; i += 256) {
      float v = vals[i];
      if (v > best || (v == best && i < bi)) { best = v; bi = i; }
    }
    #pragma unroll
    for (int off = 32; off; off >>= 1) {
      float ov = __shfl_down(best, off);
      int oi = __shfl_down(bi, off);
      if (ov > best || (ov == best && oi < bi)) { best = ov; bi = oi; }
    }
    if (lane == 0) { wv[wave] = best; wi[wave] = bi; }
    __syncthreads();
    if (tid == 0) {
      float bb = wv[0]; int bj = wi[0];
      for (int w = 1; w < 4; ++w)
        if (wv[w] > bb || (wv[w] == bb && wi[w] < bj)) { bb = wv[w]; bj = wi[w]; }
      topi[bh * SK + it] = bj;
      vals[bj] = -FLT_MAX;
    }
    __syncthreads();
  }
}

// ---- q_top recompute, ksample-style f32 tiles: QT[bh][48][64] f16 ----------------
// grid (B, NH, 9): 5 gathered rows per block (1152 blocks).
__global__ __launch_bounds__(256, 4) void qtop5_kernel(const float* __restrict__ x,
    const float* __restrict__ Wq, const float* __restrict__ bq,
    const int* __restrict__ topi, f16* __restrict__ QT) {
  const int b = blockIdx.x, h = blockIdx.y, sg = blockIdx.z;
  const int bh = b * NH + h;
  __shared__ float xs[5][32];
  __shared__ float wq[64][33];
  __shared__ float red[4][5][64];
  __shared__ int ls[5];
  const int tid = threadIdx.x;
  const int nl = tid & 63, kq = tid >> 6;
  if (tid < 5) ls[tid] = topi[bh * SK + sg * 5 + tid];
  float acc[5] = {0.f, 0.f, 0.f, 0.f, 0.f};
  const int wrow = tid >> 2, wqc = tid & 3;
  for (int kt = 0; kt < 32; ++kt) {
    const int d0 = kt * 32;
    __syncthreads();
    if (tid < 40) {
      int s = tid >> 3, q = tid & 7;
      *(f32x4*)&xs[s][q * 4] = *(const f32x4*)&x[((size_t)b * L_ + ls[s]) * DM + d0 + q * 4];
    }
    {
      const float* src = &Wq[(size_t)(h * 64 + wrow) * DM + d0 + wqc * 8];
      *(f32x4*)&wq[wrow][wqc * 8]     = *(const f32x4*)src;
      *(f32x4*)&wq[wrow][wqc * 8 + 4] = *(const f32x4*)(src + 4);
    }
    __syncthreads();
    #pragma unroll
    for (int i = 0; i < 2; ++i) {
      f32x4 w = *(const f32x4*)&wq[nl][kq * 8 + i * 4];
      #pragma unroll
      for (int s = 0; s < 5; ++s) {
        f32x4 xv = *(const f32x4*)&xs[s][kq * 8 + i * 4];
        acc[s] += xv[0] * w[0] + xv[1] * w[1] + xv[2] * w[2] + xv[3] * w[3];
      }
    }
  }
  #pragma unroll
  for (int s = 0; s < 5; ++s) red[kq][s][nl] = acc[s];
  __syncthreads();
  for (int t = tid; t < 5 * 64; t += 256) {
    int s = t >> 6, j = t & 63;
    QT[bh * 3072 + (sg * 5 + s) * 64 + j] =
        (f16)(red[0][s][j] + red[1][s][j] + red[2][s][j] + red[3][s][j] + bq[h * 64 + j]);
  }
}

// ---------------- fused K+V GEMM + raw scores: S f16, V f16 (d-major) to d_out ----
__global__ __launch_bounds__(256, 2) void kscore_kernel(const f16* __restrict__ XH,
    const f16* __restrict__ WKH, const f16* __restrict__ WVH,
    const float* __restrict__ bk, const float* __restrict__ bvec,
    const f16* __restrict__ QT, f16* __restrict__ S, f16* __restrict__ Vg) {
  __shared__ __align__(16) char smem[68352];
  f16* qs = (f16*)smem;
  f16* xh = (f16*)(smem + 6912);
  f16* wh = (f16*)(smem + 23296);
  f16* Kt = (f16*)(smem + 31488);
  f16* Vt = Kt;
  const int g = blockIdx.y * 128 + blockIdx.x;  // XCD = g & 7
  const int b = g & 7;
  const int p = g >> 3;
  const int jc = p >> 4;
  const int h = p & 15;
  const int bh = b * 16 + h;
  const int tid = threadIdx.x;
  const int lane = tid & 63, wave = tid >> 6;
  const int frow = lane & 15;
  const int fk = (lane >> 4) * 8;

  for (int i = tid; i < 48 * 64; i += 256)
    qs[(i >> 6) * 72 + (i & 63)] = QT[bh * 3072 + i];

  f32x4 accK[4][4], accV[4][4];
  #pragma unroll
  for (int i = 0; i < 4; ++i)
    #pragma unroll
    for (int j = 0; j < 4; ++j)
      #pragma unroll
      for (int z = 0; z < 4; ++z) { accK[i][j][z] = 0.f; accV[i][j][z] = 0.f; }

  const int r2 = tid >> 2, cb = (tid & 3) * 8;
  const int cbs = cb ^ (((r2 >> 1) & 3) << 3);
  for (int kt = 0; kt < 32; ++kt) {
    #pragma unroll
    for (int i = 0; i < 4; ++i)
      gload_lds16(XH + (size_t)(b * L_ + jc * 256 + i * 64 + r2) * DM + kt * 32 + cbs,
                  xh + (i * 64 + r2) * 32 + cb);
    gload_lds16(WKH + (size_t)(h * 64 + r2) * DM + kt * 32 + cbs, wh + r2 * 32 + cb);
    gload_lds16(WVH + (size_t)(h * 64 + r2) * DM + kt * 32 + cbs, wh + (r2 + 64) * 32 + cb);
    __syncthreads();
    f16x8 am[4], bnK[4], bnV[4];
    #pragma unroll
    for (int mi = 0; mi < 4; ++mi)
      am[mi] = *(const f16x8*)(xh + swz(wave * 64 + mi * 16 + frow, fk));
    #pragma unroll
    for (int ni = 0; ni < 4; ++ni) {
      bnK[ni] = *(const f16x8*)(wh + swz(ni * 16 + frow, fk));
      bnV[ni] = *(const f16x8*)(wh + swz(64 + ni * 16 + frow, fk));
    }
    #pragma unroll
    for (int mi = 0; mi < 4; ++mi)
      #pragma unroll
      for (int ni = 0; ni < 4; ++ni) {
        accK[mi][ni] = __builtin_amdgcn_mfma_f32_16x16x32_f16(am[mi], bnK[ni], accK[mi][ni], 0, 0, 0);
        accV[mi][ni] = __builtin_amdgcn_mfma_f32_16x16x32_f16(am[mi], bnV[ni], accV[mi][ni], 0, 0, 0);
      }
    __syncthreads();
  }

  #pragma unroll
  for (int mi = 0; mi < 4; ++mi) {
    int jl = wave * 64 + mi * 16 + (lane >> 4) * 4;
    #pragma unroll
    for (int ni = 0; ni < 4; ++ni) {
      int d = ni * 16 + (lane & 15);
      float bc = bk[h * 64 + d];
      #pragma unroll
      for (int z = 0; z < 4; ++z)
        Kt[(jl + z) * 72 + d] = (f16)(accK[mi][ni][z] + bc);
    }
  }
  __syncthreads();

  f32x4 accS[3][4];
  #pragma unroll
  for (int i = 0; i < 3; ++i)
    #pragma unroll
    for (int j = 0; j < 4; ++j)
      #pragma unroll
      for (int z = 0; z < 4; ++z) accS[i][j][z] = 0.f;
  #pragma unroll
  for (int ks = 0; ks < 2; ++ks) {
    f16x8 aq[3], bv[4];
    #pragma unroll
    for (int mu = 0; mu < 3; ++mu)
      aq[mu] = *(const f16x8*)(qs + (mu * 16 + frow) * 72 + ks * 32 + fk);
    #pragma unroll
    for (int nj = 0; nj < 4; ++nj)
      bv[nj] = *(const f16x8*)(Kt + (wave * 64 + nj * 16 + frow) * 72 + ks * 32 + fk);
    #pragma unroll
    for (int mu = 0; mu < 3; ++mu)
      #pragma unroll
      for (int nj = 0; nj < 4; ++nj)
        accS[mu][nj] = __builtin_amdgcn_mfma_f32_16x16x32_f16(aq[mu], bv[nj], accS[mu][nj], 0, 0, 0);
  }
  __syncthreads();   // all Kt/qs reads done before Vt (aliased) is written

  #pragma unroll
  for (int mi = 0; mi < 4; ++mi) {
    int jl = wave * 64 + mi * 16 + (lane >> 4) * 4;
    #pragma unroll
    for (int ni = 0; ni < 4; ++ni) {
      int d = ni * 16 + (lane & 15);
      float bc = bvec[h * 64 + d];
      #pragma unroll
      for (int z = 0; z < 4; ++z)
        Vt[d * 264 + jl + z] = (f16)(accV[mi][ni][z] + bc);
    }
  }
  __syncthreads();

  for (int t = tid; t < 64 * 32; t += 256) {
    int d = t >> 5, j8 = t & 31;
    f16x8 v = *(const f16x8*)(Vt + d * 264 + j8 * 8);
    *(f16x8*)(Vg + ((size_t)bh * 64 + d) * L_ + jc * 256 + j8 * 8) = v;
  }

  #pragma unroll
  for (int mu = 0; mu < 3; ++mu) {
    #pragma unroll
    for (int nj = 0; nj < 4; ++nj) {
      int j = jc * 256 + wave * 64 + nj * 16 + (lane & 15);
      #pragma unroll
      for (int z = 0; z < 4; ++z) {
        int u = mu * 16 + (lane >> 4) * 4 + z;
        if (u < SK)
          S[((size_t)bh * SK + u) * L_ + j] = (f16)(accS[mu][nj][z] * 0.125f);
      }
    }
  }
}

// ---------------- PV: unnormalized exp, Z via atomics, V from global --------------
__global__ __launch_bounds__(256, 2) void pv_kernel(const f16* __restrict__ S,
    const f16* __restrict__ Vg, float* __restrict__ OT, float* __restrict__ Zb) {
  __shared__ float red[4 * 48 * 64];
  const int g = blockIdx.y * 128 + blockIdx.x;
  const int b = g & 7;
  const int p = g >> 3;
  const int jc = p >> 4;
  const int h = p & 15;
  const int bh = b * 16 + h;
  const int tid = threadIdx.x;
  const int lane = tid & 63, wave = tid >> 6;
  const int frow = lane & 15;
  const int fk = (lane >> 4) * 8;

  f32x4 accO[3][4];
  float zacc[3] = {0.f, 0.f, 0.f};
  #pragma unroll
  for (int i = 0; i < 3; ++i)
    #pragma unroll
    for (int j = 0; j < 4; ++j)
      #pragma unroll
      for (int z = 0; z < 4; ++z) accO[i][j][z] = 0.f;

  #pragma unroll
  for (int ks = 0; ks < 2; ++ks) {
    f16x8 ap[3], bv[4];
    #pragma unroll
    for (int mu = 0; mu < 3; ++mu) {
      int urow = mu * 16 + frow;
      int ur = (urow < SK) ? urow : 0;
      const f16* aptr = S + ((size_t)bh * SK + ur) * L_ + jc * 256 + wave * 64 + ks * 32 + fk;
      f16x8 raw = *(const f16x8*)aptr;
      f16x8 pp;
      float zs = 0.f;
      #pragma unroll
      for (int j = 0; j < 8; ++j) {
        f16 e = (f16)__expf((float)raw[j]);
        pp[j] = e;
        zs += (float)e;
      }
      zacc[mu] += zs;
      ap[mu] = pp;
    }
    #pragma unroll
    for (int nd = 0; nd < 4; ++nd)
      bv[nd] = *(const f16x8*)(Vg + ((size_t)bh * 64 + nd * 16 + frow) * L_ +
                               jc * 256 + wave * 64 + ks * 32 + fk);
    #pragma unroll
    for (int mu = 0; mu < 3; ++mu)
      #pragma unroll
      for (int nd = 0; nd < 4; ++nd)
        accO[mu][nd] = __builtin_amdgcn_mfma_f32_16x16x32_f16(ap[mu], bv[nd], accO[mu][nd], 0, 0, 0);
  }

  #pragma unroll
  for (int mu = 0; mu < 3; ++mu) {
    float z = zacc[mu];
    z += __shfl_xor(z, 16);
    z += __shfl_xor(z, 32);
    int u = mu * 16 + frow;
    if ((lane >> 4) == 0 && u < SK) atomicAdd(&Zb[bh * 48 + u], z);
  }

  #pragma unroll
  for (int mu = 0; mu < 3; ++mu) {
    #pragma unroll
    for (int nd = 0; nd < 4; ++nd) {
      int d = nd * 16 + (lane & 15);
      #pragma unroll
      for (int z = 0; z < 4; ++z) {
        int u = mu * 16 + (lane >> 4) * 4 + z;
        red[wave * 3072 + u * 64 + d] = accO[mu][nd][z];
      }
    }
  }
  __syncthreads();
  for (int i = tid; i < 3072; i += 256) {
    int u = i >> 6;
    if (u < SK)
      atomicAdd(&OT[((size_t)bh * SK + u) * DH + (i & 63)],
                red[i] + red[3072 + i] + red[6144 + i] + red[9216 + i]);
  }
}

// ---------------- out = broadcast(base) ----------------
__global__ __launch_bounds__(256) void basewrite_kernel(const float* __restrict__ base,
                                                        float* __restrict__ out) {
  size_t i = (size_t)blockIdx.x * 256 + threadIdx.x;
  const size_t stride = (size_t)gridDim.x * 256;
  const size_t total = (size_t)B_ * L_ * (DM / 4);
  for (; i < total; i += stride) {
    size_t b = i >> 20;
    size_t c = i & 255;
    ((f32x4*)out)[i] = ((const f32x4*)base)[b * 256 + c];
  }
}

// ---------------- corrections: out[b, top_u, n] += (OT/Z - MV) . Wo[n, h*64:] -----
__global__ __launch_bounds__(256, 2) void corr_kernel(const float* __restrict__ OT,
    const float* __restrict__ Zb, const float* __restrict__ MV,
    const float* __restrict__ Wo, const int* __restrict__ topi,
    float* __restrict__ out) {
  __shared__ float dv[SK][64];
  __shared__ float wo[64][65];
  __shared__ float invz[SK];
  __shared__ int lidx[SK];
  const int bh = blockIdx.x, q = blockIdx.y, tid = threadIdx.x;
  const int b = bh >> 4, h = bh & 15;
  if (tid < SK) {
    invz[tid] = 1.0f / Zb[bh * 48 + tid];
    lidx[tid] = topi[bh * SK + tid];
  }
  __syncthreads();
  for (int i = tid; i < SK * 64; i += 256) {
    int u = i >> 6, d = i & 63;
    dv[u][d] = OT[((size_t)bh * SK + u) * DH + d] * invz[u] - MV[b * DM + h * DH + d];
  }
  const int nn = tid & 63, ug = tid >> 6;
  for (int c = 0; c < 4; ++c) {
    const int n0 = q * 256 + c * 64;
    __syncthreads();
    for (int t = tid; t < 1024; t += 256) {
      int row = t >> 4, vc = t & 15;
      f32x4 v = *(const f32x4*)&Wo[(size_t)(n0 + row) * DM + h * DH + vc * 4];
      *(f32x4*)&wo[row][vc * 4] = v;
    }
    __syncthreads();
    #pragma unroll
    for (int i = 0; i < 12; ++i) {
      int u = ug + i * 4;
      if (u >= SK) break;
      float a0 = 0, a1 = 0, a2 = 0, a3 = 0;
      #pragma unroll
      for (int d4 = 0; d4 < 16; ++d4) {
        f32x4 w = *(const f32x4*)&wo[nn][d4 * 4];
        f32x4 dd = *(const f32x4*)&dv[u][d4 * 4];
        a0 += dd[0] * w[0]; a1 += dd[1] * w[1];
        a2 += dd[2] * w[2]; a3 += dd[3] * w[3];
      }
      atomicAdd(&out[((size_t)b * L_ + lidx[u]) * DM + n0 + nn], (a0 + a1) + (a2 + a3));
    }
  }
}

// ---------------- workspace layout (unchanged size, PH/PL overlay S) --------------
static const size_t OFF_XH   = 0;                        // 67108864
static const size_t OFF_WQH  = OFF_XH + 67108864;        // 2097152
static const size_t OFF_WQL  = OFF_WQH + 2097152;
static const size_t OFF_WKH  = OFF_WQL + 2097152;
static const size_t OFF_WVH  = OFF_WKH + 2097152;
static const size_t OFF_KS   = OFF_WVH + 2097152;        // 1474560
static const size_t OFF_M    = OFF_KS + 1474560;         // 2097152
static const size_t OFF_TOPI = OFF_M + 2097152;          // 23040
static const size_t OFF_MEANX= OFF_TOPI + 23040;         // 32768
static const size_t OFF_MV   = OFF_MEANX + 32768;
static const size_t OFF_BASE = OFF_MV + 32768;
static const size_t OFF_ZB   = OFF_BASE + 32768;         // 24576
static const size_t OFF_QT   = OFF_ZB + 24576;           // 786432
static const size_t OFF_S    = OFF_QT + 786432;          // 47185920 (PH/PL overlay: 2x12582912)
static const size_t OFF_OT   = OFF_S + 47185920;         // 1474560
static const size_t WS_NEED  = OFF_OT + 1474560;

extern "C" void kernel_launch(void* const* d_in, const int* in_sizes, int n_in,
                              void* d_out, int out_size, void* d_ws, size_t ws_size,
                              hipStream_t stream) {
  const float* x  = (const float*)d_in[0];
  const float* Wq = (const float*)d_in[1];
  const float* bq = (const float*)d_in[2];
  const float* Wk = (const float*)d_in[3];
  const float* bk = (const float*)d_in[4];
  const float* Wv = (const float*)d_in[5];
  const float* bv = (const float*)d_in[6];
  const float* Wo = (const float*)d_in[7];
  const float* bo = (const float*)d_in[8];
  const int* sidx = (const int*)d_in[9];
  float* out = (float*)d_out;
  char* ws = (char*)d_ws;

  if (ws_size < WS_NEED) {
    if (ws_size < 131072) return;
    float* MEANX = (float*)(ws + 0);
    float* MV    = (float*)(ws + 32768);
    float* BASE  = (float*)(ws + 65536);
    hipMemsetAsync(MEANX, 0, 32768, stream);
    meansum32_kernel<<<dim3(B_, 4, 16), 256, 0, stream>>>(x, MEANX);
    proj_vec_kernel<<<32, 256, 0, stream>>>(MEANX, Wv, bv, MV, 1.0f / L_);
    proj_vec_kernel<<<32, 256, 0, stream>>>(MV, Wo, bo, BASE, 1.0f);
    basewrite_kernel<<<2048, 256, 0, stream>>>(BASE, out);
    return;
  }

  f16*   XH   = (f16*)(ws + OFF_XH);
  f16*   WQH  = (f16*)(ws + OFF_WQH);
  f16*   WQL  = (f16*)(ws + OFF_WQL);
  f16*   WKH  = (f16*)(ws + OFF_WKH);
  f16*   WVH  = (f16*)(ws + OFF_WVH);
  float* KS   = (float*)(ws + OFF_KS);
  float* Mb   = (float*)(ws + OFF_M);
  int*   TOPI = (int*)(ws + OFF_TOPI);
  float* MEANX= (float*)(ws + OFF_MEANX);
  float* MV   = (float*)(ws + OFF_MV);
  float* BASE = (float*)(ws + OFF_BASE);
  float* ZB   = (float*)(ws + OFF_ZB);
  f16*   QT   = (f16*)(ws + OFF_QT);
  f16*   PH   = (f16*)(ws + OFF_S);              // overlay: dead before kscore
  f16*   PL   = (f16*)(ws + OFF_S + 12582912);
  f16*   Sb   = (f16*)(ws + OFF_S);
  float* OT   = (float*)(ws + OFF_OT);
  float* SC   = (float*)out;  // sampled-score matrix lives in d_out (100.7 MB)
  f16*   Vg   = (f16*)out;    // then V (67 MB) reuses d_out after SC is dead

  // 1. conversions / splits / zeroing
  xsplit16_kernel<<<2048, 256, 0, stream>>>(x, XH, (int)((size_t)B_ * L_ * DM / 4));
  wsplit16_kernel<<<256, 256, 0, stream>>>(Wq, WQH, WQL, DM * DM / 4, 1);
  wsplit16_kernel<<<256, 256, 0, stream>>>(Wk, WKH, WKH, DM * DM / 4, 0);
  wsplit16_kernel<<<256, 256, 0, stream>>>(Wv, WVH, WVH, DM * DM / 4, 0);
  hipMemsetAsync(MEANX, 0, 32768, stream);
  hipMemsetAsync(OT, 0, 1474560, stream);
  hipMemsetAsync(ZB, 0, 24576, stream);
  hipMemsetAsync(QT, 0, 786432, stream);

  // 2. mean path (reads XH f16)
  meansum_kernel<<<dim3(B_, 4, 16), 256, 0, stream>>>(XH, MEANX);
  proj_vec_kernel<<<32, 256, 0, stream>>>(MEANX, Wv, bv, MV, 1.0f / L_);
  proj_vec_kernel<<<32, 256, 0, stream>>>(MV, Wo, bo, BASE, 1.0f);

  // 3. sampled K rows -> P = Wq_h^T k_s -> sampled scores GEMM (no full Q!)
  ksample_kernel<<<dim3(B_, 16, 9), 256, 0, stream>>>(x, Wk, bk, sidx, KS);
  pcomp_kernel<<<dim3(B_, NH, 16), 256, 0, stream>>>(Wq, KS, PH, PL);
  gemm_sc<<<dim3(8, 192), 256, 0, stream>>>(x, PH, PL, SC);
  mcompute_kernel<<<dim3(B_, 256), 256, 0, stream>>>(SC, Mb);

  // 4. top-k + q_top recompute (ksample-style, 1152 blocks)
  topk_kernel<<<B_ * NH, 256, 0, stream>>>(Mb, TOPI);
  qtop5_kernel<<<dim3(B_, NH, 9), 256, 0, stream>>>(x, Wq, bq, TOPI, QT);

  // 5. fused K+V GEMM + raw scores (V -> d_out, overwrites SC), PV with exp + Z
  kscore_kernel<<<dim3(128, 16), 256, 0, stream>>>(XH, WKH, WVH, bk, bv, QT, Sb, Vg);
  pv_kernel<<<dim3(128, 16), 256, 0, stream>>>(Sb, Vg, OT, ZB);

  // 6. output assembly
  basewrite_kernel<<<2048, 256, 0, stream>>>(BASE, out);
  corr_kernel<<<dim3(B_ * NH, 4), 256, 0, stream>>>(OT, ZB, MV, Wo, TOPI, out);
}

// Round 13
// 825.347 us; speedup vs baseline: 1.2037x; 1.0351x over previous
//
#include <hip/hip_runtime.h>
#include <cfloat>
#include <cstdint>

#define B_  8
#define L_  4096
#define DM  1024
#define NH  16
#define DH  64
#define SK  45

typedef __attribute__((ext_vector_type(4))) float f32x4;
typedef _Float16 f16;
typedef __attribute__((ext_vector_type(4))) _Float16 f16x4;
typedef __attribute__((ext_vector_type(8))) _Float16 f16x8;

__device__ __forceinline__ void gload_lds16(const void* g, void* l) {
  __builtin_amdgcn_global_load_lds(
      (const __attribute__((address_space(1))) unsigned int*)g,
      (__attribute__((address_space(3))) unsigned int*)l, 16, 0, 0);
}

// XOR-swizzled f16 index into a [rows][32] f16 tile (64B rows), granule 8 f16.
__device__ __forceinline__ int swz(int row, int c) {
  return row * 32 + (c ^ (((row >> 1) & 3) << 3));
}

// ---------------- x f32 -> f16 hi ----------------
__global__ __launch_bounds__(256) void xsplit16_kernel(const float* __restrict__ x,
    f16* __restrict__ xh, int n4) {
  int i = blockIdx.x * 256 + threadIdx.x;
  int stride = gridDim.x * 256;
  for (; i < n4; i += stride) {
    f32x4 v = ((const f32x4*)x)[i];
    f16x4 h;
    #pragma unroll
    for (int j = 0; j < 4; ++j) h[j] = (f16)v[j];
    ((f16x4*)xh)[i] = h;
  }
}

// ---------------- W f32 -> f16 hi (+ scaled lo) ----------------
__global__ __launch_bounds__(256) void wsplit16_kernel(const float* __restrict__ w,
    f16* __restrict__ wh, f16* __restrict__ wl, int n4, int withlo) {
  int i = blockIdx.x * 256 + threadIdx.x;
  int stride = gridDim.x * 256;
  for (; i < n4; i += stride) {
    f32x4 v = ((const f32x4*)w)[i];
    f16x4 h, l;
    #pragma unroll
    for (int j = 0; j < 4; ++j) {
      h[j] = (f16)v[j];
      l[j] = (f16)((v[j] - (float)h[j]) * 2048.0f);
    }
    ((f16x4*)wh)[i] = h;
    if (withlo) ((f16x4*)wl)[i] = l;
  }
}

// ---------------- mean over L from XH (f16) ----------------
__global__ __launch_bounds__(256) void meansum_kernel(const f16* __restrict__ xh,
                                                      float* __restrict__ meanx) {
  int b = blockIdx.x;
  int d = blockIdx.y * 256 + threadIdx.x;
  int l0 = blockIdx.z * 256;
  const f16* p = xh + ((size_t)b * L_ + l0) * DM + d;
  float s = 0.f;
  for (int i = 0; i < 256; ++i) s += (float)p[(size_t)i * DM];
  atomicAdd(&meanx[b * DM + d], s);
}

// f32 mean fallback (small-ws diagnostic path)
__global__ __launch_bounds__(256) void meansum32_kernel(const float* __restrict__ x,
                                                        float* __restrict__ meanx) {
  int b = blockIdx.x;
  int d = blockIdx.y * 256 + threadIdx.x;
  int l0 = blockIdx.z * 256;
  const float* p = x + ((size_t)b * L_ + l0) * DM + d;
  float s = 0.f;
  for (int i = 0; i < 256; ++i) s += p[(size_t)i * DM];
  atomicAdd(&meanx[b * DM + d], s);
}

// vout(b,n) = (vin(b,:) . W[n,:]) * scale + bias[n]
__global__ __launch_bounds__(256) void proj_vec_kernel(const float* __restrict__ vin,
    const float* __restrict__ W, const float* __restrict__ bias,
    float* __restrict__ vout, float scale) {
  int g = blockIdx.x * 256 + threadIdx.x;
  int b = g >> 10, n = g & 1023;
  const float* xr = vin + b * DM;
  const float* wr = W + (size_t)n * DM;
  float a0 = 0, a1 = 0, a2 = 0, a3 = 0;
  for (int d = 0; d < DM; d += 4) {
    a0 += xr[d + 0] * wr[d + 0];
    a1 += xr[d + 1] * wr[d + 1];
    a2 += xr[d + 2] * wr[d + 2];
    a3 += xr[d + 3] * wr[d + 3];
  }
  vout[g] = ((a0 + a1) + (a2 + a3)) * scale + bias[n];
}

// ---------------- k_sample rows, f32 LDS-tiled: KS[b][s][n] ----------------
__global__ __launch_bounds__(256, 4) void ksample_kernel(const float* __restrict__ x,
    const float* __restrict__ Wk, const float* __restrict__ bk,
    const int* __restrict__ sidx, float* __restrict__ KS) {
  const int b = blockIdx.x, nc = blockIdx.y, sg = blockIdx.z;
  __shared__ float xs[5][32];
  __shared__ float wk[64][33];
  __shared__ float red[4][5][64];
  __shared__ int ls[5];
  const int tid = threadIdx.x;
  const int nl = tid & 63, kq = tid >> 6;
  if (tid < 5) ls[tid] = sidx[sg * 5 + tid];
  float acc[5] = {0.f, 0.f, 0.f, 0.f, 0.f};
  const int wrow = tid >> 2, wq = tid & 3;
  for (int kt = 0; kt < 32; ++kt) {
    const int d0 = kt * 32;
    __syncthreads();
    if (tid < 40) {
      int s = tid >> 3, q = tid & 7;
      *(f32x4*)&xs[s][q * 4] = *(const f32x4*)&x[((size_t)b * L_ + ls[s]) * DM + d0 + q * 4];
    }
    {
      const float* src = &Wk[(size_t)(nc * 64 + wrow) * DM + d0 + wq * 8];
      *(f32x4*)&wk[wrow][wq * 8]     = *(const f32x4*)src;
      *(f32x4*)&wk[wrow][wq * 8 + 4] = *(const f32x4*)(src + 4);
    }
    __syncthreads();
    #pragma unroll
    for (int i = 0; i < 2; ++i) {
      f32x4 w = *(const f32x4*)&wk[nl][kq * 8 + i * 4];
      #pragma unroll
      for (int s = 0; s < 5; ++s) {
        f32x4 xv = *(const f32x4*)&xs[s][kq * 8 + i * 4];
        acc[s] += xv[0] * w[0] + xv[1] * w[1] + xv[2] * w[2] + xv[3] * w[3];
      }
    }
  }
  #pragma unroll
  for (int s = 0; s < 5; ++s) red[kq][s][nl] = acc[s];
  __syncthreads();
  for (int t = tid; t < 5 * 64; t += 256) {
    int s = t >> 6, j = t & 63;
    int nj = nc * 64 + j;
    KS[((size_t)b * SK + sg * 5 + s) * DM + nj] =
        red[0][s][j] + red[1][s][j] + red[2][s][j] + red[3][s][j] + bk[nj];
  }
}

// ---- P[b][h*48+s][nc*64+c] = sum_d Wq[h*64+d][nc*64+c] * KS[b][s][h*64+d] --------
__global__ __launch_bounds__(256, 4) void pcomp_kernel(const float* __restrict__ Wq,
    const float* __restrict__ KS, f16* __restrict__ PH, f16* __restrict__ PL) {
  const int b = blockIdx.x, h = blockIdx.y, nc = blockIdx.z;
  __shared__ float ks[45][64];
  __shared__ float wqT[64][68];
  const int tid = threadIdx.x;
  const int n0 = nc * 64;
  for (int i = tid; i < 45 * 64; i += 256) {
    int s = i >> 6, d = i & 63;
    ks[s][d] = KS[((size_t)b * SK + s) * DM + h * 64 + d];
  }
  for (int t = tid; t < 1024; t += 256) {
    int row = t >> 4, cg = t & 15;
    f32x4 v = *(const f32x4*)&Wq[(size_t)(h * 64 + row) * DM + n0 + cg * 4];
    #pragma unroll
    for (int j = 0; j < 4; ++j) wqT[cg * 4 + j][row] = v[j];
  }
  __syncthreads();
  for (int t = tid; t < 48 * 64; t += 256) {
    int s = t >> 6, c = t & 63;
    float acc = 0.f;
    if (s < SK) {
      const f32x4* wr = (const f32x4*)&wqT[c][0];
      const f32x4* kr = (const f32x4*)&ks[s][0];
      float a0 = 0, a1 = 0, a2 = 0, a3 = 0;
      #pragma unroll
      for (int i = 0; i < 16; ++i) {
        f32x4 wv = wr[i], kv = kr[i];
        a0 += wv[0] * kv[0]; a1 += wv[1] * kv[1];
        a2 += wv[2] * kv[2]; a3 += wv[3] * kv[3];
      }
      acc = (a0 + a1) + (a2 + a3);
    }
    f16 hv = (f16)acc;
    size_t off = ((size_t)b * 768 + h * 48 + s) * DM + n0 + c;
    PH[off] = hv;
    PL[off] = (f16)((acc - (float)hv) * 2048.0f);
  }
}

// ---- scores GEMM: SC[b*4096+l][col] = 0.125 * (x @ P^T), f16-split, N=768 --------
__global__ __launch_bounds__(256, 2) void gemm_sc(const float* __restrict__ x,
    const f16* __restrict__ PH, const f16* __restrict__ PL,
    float* __restrict__ SC) {
  __shared__ f16 xh[128 * 32];
  __shared__ f16 xl[128 * 32];
  __shared__ f16 wh[128 * 32];
  __shared__ f16 wl[128 * 32];
  const int tid = threadIdx.x;
  const int g = blockIdx.y * 8 + blockIdx.x;    // XCD = g & 7
  const int q = g >> 3;                          // 0..191
  const int nt = q % 6;                          // N-tile cycles fastest
  const int mt = (g & 7) + (q / 6) * 8;          // A-panel pinned to XCD
  const int n0 = nt * 128;
  const int m0 = mt * 128;
  const int bb = mt >> 5;                        // batch of this M-tile
  const int lane = tid & 63;
  const int wave = tid >> 6;
  const int wr = (wave >> 1) * 64;
  const int wc = (wave & 1) * 64;
  const int frow = lane & 15;
  const int fk = (lane >> 4) * 8;

  f32x4 aH[4][4], aL[4][4];
  #pragma unroll
  for (int i = 0; i < 4; ++i)
    #pragma unroll
    for (int j = 0; j < 4; ++j)
      #pragma unroll
      for (int z = 0; z < 4; ++z) { aH[i][j][z] = 0.f; aL[i][j][z] = 0.f; }

  const int ar = tid >> 1;
  const int ac = (tid & 1) * 16;
  const int r2 = tid >> 2;
  const int cb = (tid & 3) * 8;
  const int cbs = cb ^ (((r2 >> 1) & 3) << 3);

  const size_t pbase = (size_t)bb * 768;
  for (int kt = 0; kt < 32; ++kt) {
    const float* gx = x + (size_t)(m0 + ar) * DM + kt * 32 + ac;
    #pragma unroll
    for (int gi = 0; gi < 4; ++gi) {
      f32x4 v = ((const f32x4*)gx)[gi];
      f16x4 h, l;
      #pragma unroll
      for (int z = 0; z < 4; ++z) {
        h[z] = (f16)v[z];
        l[z] = (f16)((v[z] - (float)h[z]) * 2048.0f);
      }
      *(f16x4*)(xh + swz(ar, ac + gi * 4)) = h;
      *(f16x4*)(xl + swz(ar, ac + gi * 4)) = l;
    }
    gload_lds16(PH + (pbase + n0 + r2) * DM + kt * 32 + cbs,      wh + r2 * 32 + cb);
    gload_lds16(PH + (pbase + n0 + r2 + 64) * DM + kt * 32 + cbs, wh + (r2 + 64) * 32 + cb);
    gload_lds16(PL + (pbase + n0 + r2) * DM + kt * 32 + cbs,      wl + r2 * 32 + cb);
    gload_lds16(PL + (pbase + n0 + r2 + 64) * DM + kt * 32 + cbs, wl + (r2 + 64) * 32 + cb);
    __syncthreads();
    f16x8 ah[4], al[4], bh[4], bl[4];
    #pragma unroll
    for (int mi = 0; mi < 4; ++mi) {
      ah[mi] = *(const f16x8*)(xh + swz(wr + mi * 16 + frow, fk));
      al[mi] = *(const f16x8*)(xl + swz(wr + mi * 16 + frow, fk));
    }
    #pragma unroll
    for (int ni = 0; ni < 4; ++ni) {
      bh[ni] = *(const f16x8*)(wh + swz(wc + ni * 16 + frow, fk));
      bl[ni] = *(const f16x8*)(wl + swz(wc + ni * 16 + frow, fk));
    }
    #pragma unroll
    for (int mi = 0; mi < 4; ++mi)
      #pragma unroll
      for (int ni = 0; ni < 4; ++ni) {
        aH[mi][ni] = __builtin_amdgcn_mfma_f32_16x16x32_f16(ah[mi], bh[ni], aH[mi][ni], 0, 0, 0);
        aL[mi][ni] = __builtin_amdgcn_mfma_f32_16x16x32_f16(ah[mi], bl[ni], aL[mi][ni], 0, 0, 0);
        aL[mi][ni] = __builtin_amdgcn_mfma_f32_16x16x32_f16(al[mi], bh[ni], aL[mi][ni], 0, 0, 0);
      }
    __syncthreads();
  }

  #pragma unroll
  for (int mi = 0; mi < 4; ++mi) {
    int rowb = m0 + wr + mi * 16 + (lane >> 4) * 4;
    #pragma unroll
    for (int ni = 0; ni < 4; ++ni) {
      int col = n0 + wc + ni * 16 + (lane & 15);
      #pragma unroll
      for (int j = 0; j < 4; ++j) {
        SC[(size_t)(rowb + j) * 768 + col] =
            (aH[mi][ni][j] + aL[mi][ni][j] * (1.0f / 2048.0f)) * 0.125f;
      }
    }
  }
}

// ---------------- m = max - mean over the 45 sampled scores -----------------------
__global__ __launch_bounds__(256) void mcompute_kernel(const float* __restrict__ SC,
    float* __restrict__ Mout) {
  const int b = blockIdx.x;
  const int l = blockIdx.y * 16 + (threadIdx.x >> 4);
  const int h = threadIdx.x & 15;
  const float* p = SC + ((size_t)(b * L_ + l)) * 768 + h * 48;
  float mx = -FLT_MAX, sum = 0.f;
  #pragma unroll
  for (int i = 0; i < 11; ++i) {
    f32x4 v = *(const f32x4*)(p + i * 4);
    #pragma unroll
    for (int j = 0; j < 4; ++j) { mx = fmaxf(mx, v[j]); sum += v[j]; }
  }
  { float v = p[44]; mx = fmaxf(mx, v); sum += v; }
  Mout[((size_t)(b * NH + h)) * L_ + l] = mx - sum * (1.0f / SK);
}

// ---------------- top-45 per (b,h): iterative argmax ----------------
__global__ __launch_bounds__(256) void topk_kernel(const float* __restrict__ M,
                                                   int* __restrict__ topi) {
  __shared__ float vals[L_];
  __shared__ float wv[4];
  __shared__ int wi[4];
  const int bh = blockIdx.x, tid = threadIdx.x;
  for (int i = tid; i < L_; i += 256) vals[i] = M[(size_t)bh * L_ + i];
  __syncthreads();
  const int lane = tid & 63, wave = tid >> 6;
  for (int it = 0; it < SK; ++it) {
    float best = -FLT_MAX;
    int bi = 1 << 30;
    for (int i = tid; i < L_; i += 256) {
      float v = vals[i];
      if (v > best || (v == best && i < bi)) { best = v; bi = i; }
    }
    #pragma unroll
    for (int off = 32; off; off >>= 1) {
      float ov = __shfl_down(best, off);
      int oi = __shfl_down(bi, off);
      if (ov > best || (ov == best && oi < bi)) { best = ov; bi = oi; }
    }
    if (lane == 0) { wv[wave] = best; wi[wave] = bi; }
    __syncthreads();
    if (tid == 0) {
      float bb = wv[0]; int bj = wi[0];
      for (int w = 1; w < 4; ++w)
        if (wv[w] > bb || (wv[w] == bb && wi[w] < bj)) { bb = wv[w]; bj = wi[w]; }
      topi[bh * SK + it] = bj;
      vals[bj] = -FLT_MAX;
    }
    __syncthreads();
  }
}

// ---- q_top recompute, ksample-style f32 tiles: QT[bh][48][64] f16 ----------------
__global__ __launch_bounds__(256, 4) void qtop5_kernel(const float* __restrict__ x,
    const float* __restrict__ Wq, const float* __restrict__ bq,
    const int* __restrict__ topi, f16* __restrict__ QT) {
  const int b = blockIdx.x, h = blockIdx.y, sg = blockIdx.z;
  const int bh = b * NH + h;
  __shared__ float xs[5][32];
  __shared__ float wq[64][33];
  __shared__ float red[4][5][64];
  __shared__ int ls[5];
  const int tid = threadIdx.x;
  const int nl = tid & 63, kq = tid >> 6;
  if (tid < 5) ls[tid] = topi[bh * SK + sg * 5 + tid];
  float acc[5] = {0.f, 0.f, 0.f, 0.f, 0.f};
  const int wrow = tid >> 2, wqc = tid & 3;
  for (int kt = 0; kt < 32; ++kt) {
    const int d0 = kt * 32;
    __syncthreads();
    if (tid < 40) {
      int s = tid >> 3, q = tid & 7;
      *(f32x4*)&xs[s][q * 4] = *(const f32x4*)&x[((size_t)b * L_ + ls[s]) * DM + d0 + q * 4];
    }
    {
      const float* src = &Wq[(size_t)(h * 64 + wrow) * DM + d0 + wqc * 8];
      *(f32x4*)&wq[wrow][wqc * 8]     = *(const f32x4*)src;
      *(f32x4*)&wq[wrow][wqc * 8 + 4] = *(const f32x4*)(src + 4);
    }
    __syncthreads();
    #pragma unroll
    for (int i = 0; i < 2; ++i) {
      f32x4 w = *(const f32x4*)&wq[nl][kq * 8 + i * 4];
      #pragma unroll
      for (int s = 0; s < 5; ++s) {
        f32x4 xv = *(const f32x4*)&xs[s][kq * 8 + i * 4];
        acc[s] += xv[0] * w[0] + xv[1] * w[1] + xv[2] * w[2] + xv[3] * w[3];
      }
    }
  }
  #pragma unroll
  for (int s = 0; s < 5; ++s) red[kq][s][nl] = acc[s];
  __syncthreads();
  for (int t = tid; t < 5 * 64; t += 256) {
    int s = t >> 6, j = t & 63;
    QT[bh * 3072 + (sg * 5 + s) * 64 + j] =
        (f16)(red[0][s][j] + red[1][s][j] + red[2][s][j] + red[3][s][j] + bq[h * 64 + j]);
  }
}

// ---- fused K+V GEMM + scores + inline-exp PV: atomics into OT, Zb. No S/V in HBM.
__global__ __launch_bounds__(256, 2) void kscore_kernel(const f16* __restrict__ XH,
    const f16* __restrict__ WKH, const f16* __restrict__ WVH,
    const float* __restrict__ bk, const float* __restrict__ bvec,
    const f16* __restrict__ QT, float* __restrict__ OT, float* __restrict__ Zb) {
  __shared__ __align__(16) char smem[68352];
  f16* qs = (f16*)smem;                  // phase1-2: 48*72*2 = 6912
  f16* xh = (f16*)(smem + 6912);         // phase1:   16384
  f16* wh = (f16*)(smem + 23296);        // phase1:   8192
  f16* Kt = (f16*)(smem + 31488);        // phase2:   256*72*2 = 36864
  f16* Ps = (f16*)smem;                  // phase3-4: 48*264*2 = 25344 (over qs/xh)
  f16* Vt = (f16*)(smem + 31488);        // phase3-4: 64*264*2 = 33792 (over Kt)
  float* red = (float*)smem;             // phase5:   4*48*64*4 = 49152
  const int g = blockIdx.y * 128 + blockIdx.x;  // XCD = g & 7
  const int b = g & 7;
  const int p = g >> 3;
  const int jc = p >> 4;
  const int h = p & 15;
  const int bh = b * 16 + h;
  const int tid = threadIdx.x;
  const int lane = tid & 63, wave = tid >> 6;
  const int frow = lane & 15;
  const int fk = (lane >> 4) * 8;

  for (int i = tid; i < 48 * 64; i += 256)
    qs[(i >> 6) * 72 + (i & 63)] = QT[bh * 3072 + i];

  // ---- phase 1: K+V GEMM over the 256-row x panel ----
  f32x4 accK[4][4], accV[4][4];
  #pragma unroll
  for (int i = 0; i < 4; ++i)
    #pragma unroll
    for (int j = 0; j < 4; ++j)
      #pragma unroll
      for (int z = 0; z < 4; ++z) { accK[i][j][z] = 0.f; accV[i][j][z] = 0.f; }

  const int r2 = tid >> 2, cb = (tid & 3) * 8;
  const int cbs = cb ^ (((r2 >> 1) & 3) << 3);
  for (int kt = 0; kt < 32; ++kt) {
    #pragma unroll
    for (int i = 0; i < 4; ++i)
      gload_lds16(XH + (size_t)(b * L_ + jc * 256 + i * 64 + r2) * DM + kt * 32 + cbs,
                  xh + (i * 64 + r2) * 32 + cb);
    gload_lds16(WKH + (size_t)(h * 64 + r2) * DM + kt * 32 + cbs, wh + r2 * 32 + cb);
    gload_lds16(WVH + (size_t)(h * 64 + r2) * DM + kt * 32 + cbs, wh + (r2 + 64) * 32 + cb);
    __syncthreads();
    f16x8 am[4], bnK[4], bnV[4];
    #pragma unroll
    for (int mi = 0; mi < 4; ++mi)
      am[mi] = *(const f16x8*)(xh + swz(wave * 64 + mi * 16 + frow, fk));
    #pragma unroll
    for (int ni = 0; ni < 4; ++ni) {
      bnK[ni] = *(const f16x8*)(wh + swz(ni * 16 + frow, fk));
      bnV[ni] = *(const f16x8*)(wh + swz(64 + ni * 16 + frow, fk));
    }
    #pragma unroll
    for (int mi = 0; mi < 4; ++mi)
      #pragma unroll
      for (int ni = 0; ni < 4; ++ni) {
        accK[mi][ni] = __builtin_amdgcn_mfma_f32_16x16x32_f16(am[mi], bnK[ni], accK[mi][ni], 0, 0, 0);
        accV[mi][ni] = __builtin_amdgcn_mfma_f32_16x16x32_f16(am[mi], bnV[ni], accV[mi][ni], 0, 0, 0);
      }
    __syncthreads();
  }

  // ---- phase 2: K-tile -> LDS, scores = qs x Kt ----
  #pragma unroll
  for (int mi = 0; mi < 4; ++mi) {
    int jl = wave * 64 + mi * 16 + (lane >> 4) * 4;
    #pragma unroll
    for (int ni = 0; ni < 4; ++ni) {
      int d = ni * 16 + (lane & 15);
      float bc = bk[h * 64 + d];
      #pragma unroll
      for (int z = 0; z < 4; ++z)
        Kt[(jl + z) * 72 + d] = (f16)(accK[mi][ni][z] + bc);
    }
  }
  __syncthreads();

  f32x4 accS[3][4];
  #pragma unroll
  for (int i = 0; i < 3; ++i)
    #pragma unroll
    for (int j = 0; j < 4; ++j)
      #pragma unroll
      for (int z = 0; z < 4; ++z) accS[i][j][z] = 0.f;
  #pragma unroll
  for (int ks = 0; ks < 2; ++ks) {
    f16x8 aq[3], bv[4];
    #pragma unroll
    for (int mu = 0; mu < 3; ++mu)
      aq[mu] = *(const f16x8*)(qs + (mu * 16 + frow) * 72 + ks * 32 + fk);
    #pragma unroll
    for (int nj = 0; nj < 4; ++nj)
      bv[nj] = *(const f16x8*)(Kt + (wave * 64 + nj * 16 + frow) * 72 + ks * 32 + fk);
    #pragma unroll
    for (int mu = 0; mu < 3; ++mu)
      #pragma unroll
      for (int nj = 0; nj < 4; ++nj)
        accS[mu][nj] = __builtin_amdgcn_mfma_f32_16x16x32_f16(aq[mu], bv[nj], accS[mu][nj], 0, 0, 0);
  }
  __syncthreads();   // qs/Kt reads done; Ps/Vt (aliased) writes are now safe

  // ---- phase 3: Vt + Ps(=exp) -> LDS; Z partials from registers ----
  #pragma unroll
  for (int mi = 0; mi < 4; ++mi) {
    int jl = wave * 64 + mi * 16 + (lane >> 4) * 4;
    #pragma unroll
    for (int ni = 0; ni < 4; ++ni) {
      int d = ni * 16 + (lane & 15);
      float bc = bvec[h * 64 + d];
      #pragma unroll
      for (int z = 0; z < 4; ++z)
        Vt[d * 264 + jl + z] = (f16)(accV[mi][ni][z] + bc);
    }
  }
  {
    float zs[3][4];
    #pragma unroll
    for (int mu = 0; mu < 3; ++mu)
      #pragma unroll
      for (int z = 0; z < 4; ++z) zs[mu][z] = 0.f;
    #pragma unroll
    for (int mu = 0; mu < 3; ++mu)
      #pragma unroll
      for (int nj = 0; nj < 4; ++nj) {
        int j = wave * 64 + nj * 16 + (lane & 15);
        #pragma unroll
        for (int z = 0; z < 4; ++z) {
          int u = mu * 16 + (lane >> 4) * 4 + z;
          float pv = __expf(accS[mu][nj][z] * 0.125f);
          Ps[u * 264 + j] = (f16)pv;
          zs[mu][z] += pv;
        }
      }
    #pragma unroll
    for (int mu = 0; mu < 3; ++mu)
      #pragma unroll
      for (int z = 0; z < 4; ++z) {
        float v = zs[mu][z];
        v += __shfl_xor(v, 1);
        v += __shfl_xor(v, 2);
        v += __shfl_xor(v, 4);
        v += __shfl_xor(v, 8);
        int u = mu * 16 + (lane >> 4) * 4 + z;
        if ((lane & 15) == 0 && u < SK) atomicAdd(&Zb[bh * 48 + u], v);
      }
  }
  __syncthreads();

  // ---- phase 4: PV MFMA (each wave: its 64-j slice) ----
  f32x4 accO[3][4];
  #pragma unroll
  for (int i = 0; i < 3; ++i)
    #pragma unroll
    for (int j = 0; j < 4; ++j)
      #pragma unroll
      for (int z = 0; z < 4; ++z) accO[i][j][z] = 0.f;
  #pragma unroll
  for (int ks = 0; ks < 2; ++ks) {
    f16x8 ap[3], bvv[4];
    #pragma unroll
    for (int mu = 0; mu < 3; ++mu)
      ap[mu] = *(const f16x8*)(Ps + (mu * 16 + frow) * 264 + wave * 64 + ks * 32 + fk);
    #pragma unroll
    for (int nd = 0; nd < 4; ++nd)
      bvv[nd] = *(const f16x8*)(Vt + (nd * 16 + frow) * 264 + wave * 64 + ks * 32 + fk);
    #pragma unroll
    for (int mu = 0; mu < 3; ++mu)
      #pragma unroll
      for (int nd = 0; nd < 4; ++nd)
        accO[mu][nd] = __builtin_amdgcn_mfma_f32_16x16x32_f16(ap[mu], bvv[nd], accO[mu][nd], 0, 0, 0);
  }
  __syncthreads();   // Ps/Vt reads done; red (aliased) writes safe

  // ---- phase 5: cross-wave reduce + OT atomics ----
  #pragma unroll
  for (int mu = 0; mu < 3; ++mu) {
    #pragma unroll
    for (int nd = 0; nd < 4; ++nd) {
      int d = nd * 16 + (lane & 15);
      #pragma unroll
      for (int z = 0; z < 4; ++z) {
        int u = mu * 16 + (lane >> 4) * 4 + z;
        red[wave * 3072 + u * 64 + d] = accO[mu][nd][z];
      }
    }
  }
  __syncthreads();
  for (int i = tid; i < 3072; i += 256) {
    int u = i >> 6;
    if (u < SK)
      atomicAdd(&OT[((size_t)bh * SK + u) * DH + (i & 63)],
                red[i] + red[3072 + i] + red[6144 + i] + red[9216 + i]);
  }
}

// ---------------- out = broadcast(base) ----------------
__global__ __launch_bounds__(256) void basewrite_kernel(const float* __restrict__ base,
                                                        float* __restrict__ out) {
  size_t i = (size_t)blockIdx.x * 256 + threadIdx.x;
  const size_t stride = (size_t)gridDim.x * 256;
  const size_t total = (size_t)B_ * L_ * (DM / 4);
  for (; i < total; i += stride) {
    size_t b = i >> 20;
    size_t c = i & 255;
    ((f32x4*)out)[i] = ((const f32x4*)base)[b * 256 + c];
  }
}

// ---------------- corrections: out[b, top_u, n] += (OT/Z - MV) . Wo[n, h*64:] -----
__global__ __launch_bounds__(256, 2) void corr_kernel(const float* __restrict__ OT,
    const float* __restrict__ Zb, const float* __restrict__ MV,
    const float* __restrict__ Wo, const int* __restrict__ topi,
    float* __restrict__ out) {
  __shared__ float dv[SK][64];
  __shared__ float wo[64][65];
  __shared__ float invz[SK];
  __shared__ int lidx[SK];
  const int bh = blockIdx.x, q = blockIdx.y, tid = threadIdx.x;
  const int b = bh >> 4, h = bh & 15;
  if (tid < SK) {
    invz[tid] = 1.0f / Zb[bh * 48 + tid];
    lidx[tid] = topi[bh * SK + tid];
  }
  __syncthreads();
  for (int i = tid; i < SK * 64; i += 256) {
    int u = i >> 6, d = i & 63;
    dv[u][d] = OT[((size_t)bh * SK + u) * DH + d] * invz[u] - MV[b * DM + h * DH + d];
  }
  const int nn = tid & 63, ug = tid >> 6;
  for (int c = 0; c < 4; ++c) {
    const int n0 = q * 256 + c * 64;
    __syncthreads();
    for (int t = tid; t < 1024; t += 256) {
      int row = t >> 4, vc = t & 15;
      f32x4 v = *(const f32x4*)&Wo[(size_t)(n0 + row) * DM + h * DH + vc * 4];
      *(f32x4*)&wo[row][vc * 4] = v;
    }
    __syncthreads();
    #pragma unroll
    for (int i = 0; i < 12; ++i) {
      int u = ug + i * 4;
      if (u >= SK) break;
      float a0 = 0, a1 = 0, a2 = 0, a3 = 0;
      #pragma unroll
      for (int d4 = 0; d4 < 16; ++d4) {
        f32x4 w = *(const f32x4*)&wo[nn][d4 * 4];
        f32x4 dd = *(const f32x4*)&dv[u][d4 * 4];
        a0 += dd[0] * w[0]; a1 += dd[1] * w[1];
        a2 += dd[2] * w[2]; a3 += dd[3] * w[3];
      }
      atomicAdd(&out[((size_t)b * L_ + lidx[u]) * DM + n0 + nn], (a0 + a1) + (a2 + a3));
    }
  }
}

// ---------------- workspace layout (unchanged; PH/PL overlay old S region) --------
static const size_t OFF_XH   = 0;                        // 67108864
static const size_t OFF_WQH  = OFF_XH + 67108864;        // 2097152
static const size_t OFF_WQL  = OFF_WQH + 2097152;
static const size_t OFF_WKH  = OFF_WQL + 2097152;
static const size_t OFF_WVH  = OFF_WKH + 2097152;
static const size_t OFF_KS   = OFF_WVH + 2097152;        // 1474560
static const size_t OFF_M    = OFF_KS + 1474560;         // 2097152
static const size_t OFF_TOPI = OFF_M + 2097152;          // 23040
static const size_t OFF_MEANX= OFF_TOPI + 23040;         // 32768
static const size_t OFF_MV   = OFF_MEANX + 32768;
static const size_t OFF_BASE = OFF_MV + 32768;
static const size_t OFF_ZB   = OFF_BASE + 32768;         // 24576
static const size_t OFF_QT   = OFF_ZB + 24576;           // 786432
static const size_t OFF_S    = OFF_QT + 786432;          // 47185920 (PH/PL: 2x12582912)
static const size_t OFF_OT   = OFF_S + 47185920;         // 1474560
static const size_t WS_NEED  = OFF_OT + 1474560;

extern "C" void kernel_launch(void* const* d_in, const int* in_sizes, int n_in,
                              void* d_out, int out_size, void* d_ws, size_t ws_size,
                              hipStream_t stream) {
  const float* x  = (const float*)d_in[0];
  const float* Wq = (const float*)d_in[1];
  const float* bq = (const float*)d_in[2];
  const float* Wk = (const float*)d_in[3];
  const float* bk = (const float*)d_in[4];
  const float* Wv = (const float*)d_in[5];
  const float* bv = (const float*)d_in[6];
  const float* Wo = (const float*)d_in[7];
  const float* bo = (const float*)d_in[8];
  const int* sidx = (const int*)d_in[9];
  float* out = (float*)d_out;
  char* ws = (char*)d_ws;

  if (ws_size < WS_NEED) {
    if (ws_size < 131072) return;
    float* MEANX = (float*)(ws + 0);
    float* MV    = (float*)(ws + 32768);
    float* BASE  = (float*)(ws + 65536);
    hipMemsetAsync(MEANX, 0, 32768, stream);
    meansum32_kernel<<<dim3(B_, 4, 16), 256, 0, stream>>>(x, MEANX);
    proj_vec_kernel<<<32, 256, 0, stream>>>(MEANX, Wv, bv, MV, 1.0f / L_);
    proj_vec_kernel<<<32, 256, 0, stream>>>(MV, Wo, bo, BASE, 1.0f);
    basewrite_kernel<<<2048, 256, 0, stream>>>(BASE, out);
    return;
  }

  f16*   XH   = (f16*)(ws + OFF_XH);
  f16*   WQH  = (f16*)(ws + OFF_WQH);
  f16*   WQL  = (f16*)(ws + OFF_WQL);
  f16*   WKH  = (f16*)(ws + OFF_WKH);
  f16*   WVH  = (f16*)(ws + OFF_WVH);
  float* KS   = (float*)(ws + OFF_KS);
  float* Mb   = (float*)(ws + OFF_M);
  int*   TOPI = (int*)(ws + OFF_TOPI);
  float* MEANX= (float*)(ws + OFF_MEANX);
  float* MV   = (float*)(ws + OFF_MV);
  float* BASE = (float*)(ws + OFF_BASE);
  float* ZB   = (float*)(ws + OFF_ZB);
  f16*   QT   = (f16*)(ws + OFF_QT);
  f16*   PH   = (f16*)(ws + OFF_S);
  f16*   PL   = (f16*)(ws + OFF_S + 12582912);
  float* OT   = (float*)(ws + OFF_OT);
  float* SC   = (float*)out;  // sampled-score matrix lives in d_out (100.7 MB)

  // 1. conversions / splits / zeroing
  xsplit16_kernel<<<2048, 256, 0, stream>>>(x, XH, (int)((size_t)B_ * L_ * DM / 4));
  wsplit16_kernel<<<256, 256, 0, stream>>>(Wq, WQH, WQL, DM * DM / 4, 1);
  wsplit16_kernel<<<256, 256, 0, stream>>>(Wk, WKH, WKH, DM * DM / 4, 0);
  wsplit16_kernel<<<256, 256, 0, stream>>>(Wv, WVH, WVH, DM * DM / 4, 0);
  hipMemsetAsync(MEANX, 0, 32768, stream);
  hipMemsetAsync(OT, 0, 1474560, stream);
  hipMemsetAsync(ZB, 0, 24576, stream);
  hipMemsetAsync(QT, 0, 786432, stream);

  // 2. mean path (reads XH f16)
  meansum_kernel<<<dim3(B_, 4, 16), 256, 0, stream>>>(XH, MEANX);
  proj_vec_kernel<<<32, 256, 0, stream>>>(MEANX, Wv, bv, MV, 1.0f / L_);
  proj_vec_kernel<<<32, 256, 0, stream>>>(MV, Wo, bo, BASE, 1.0f);

  // 3. sampled K rows -> P = Wq_h^T k_s -> sampled scores GEMM (no full Q)
  ksample_kernel<<<dim3(B_, 16, 9), 256, 0, stream>>>(x, Wk, bk, sidx, KS);
  pcomp_kernel<<<dim3(B_, NH, 16), 256, 0, stream>>>(Wq, KS, PH, PL);
  gemm_sc<<<dim3(8, 192), 256, 0, stream>>>(x, PH, PL, SC);
  mcompute_kernel<<<dim3(B_, 256), 256, 0, stream>>>(SC, Mb);

  // 4. top-k + q_top recompute
  topk_kernel<<<B_ * NH, 256, 0, stream>>>(Mb, TOPI);
  qtop5_kernel<<<dim3(B_, NH, 9), 256, 0, stream>>>(x, Wq, bq, TOPI, QT);

  // 5. fully fused K+V GEMM + scores + exp-PV (no S/V HBM round-trip)
  kscore_kernel<<<dim3(128, 16), 256, 0, stream>>>(XH, WKH, WVH, bk, bv, QT, OT, ZB);

  // 6. output assembly
  basewrite_kernel<<<2048, 256, 0, stream>>>(BASE, out);
  corr_kernel<<<dim3(B_ * NH, 4), 256, 0, stream>>>(OT, ZB, MV, Wo, TOPI, out);
}

// Round 14
// 783.442 us; speedup vs baseline: 1.2680x; 1.0535x over previous
//
#include <hip/hip_runtime.h>
#include <cfloat>
#include <cstdint>

#define B_  8
#define L_  4096
#define DM  1024
#define NH  16
#define DH  64
#define SK  45

typedef __attribute__((ext_vector_type(4))) float f32x4;
typedef _Float16 f16;
typedef __attribute__((ext_vector_type(4))) _Float16 f16x4;
typedef __attribute__((ext_vector_type(8))) _Float16 f16x8;

__device__ __forceinline__ void gload_lds16(const void* g, void* l) {
  __builtin_amdgcn_global_load_lds(
      (const __attribute__((address_space(1))) unsigned int*)g,
      (__attribute__((address_space(3))) unsigned int*)l, 16, 0, 0);
}

// XOR-swizzled f16 index into a [rows][32] f16 tile (64B rows), granule 8 f16.
__device__ __forceinline__ int swz(int row, int c) {
  return row * 32 + (c ^ (((row >> 1) & 3) << 3));
}

// ---------------- x f32 -> f16 hi ----------------
__global__ __launch_bounds__(256) void xsplit16_kernel(const float* __restrict__ x,
    f16* __restrict__ xh, int n4) {
  int i = blockIdx.x * 256 + threadIdx.x;
  int stride = gridDim.x * 256;
  for (; i < n4; i += stride) {
    f32x4 v = ((const f32x4*)x)[i];
    f16x4 h;
    #pragma unroll
    for (int j = 0; j < 4; ++j) h[j] = (f16)v[j];
    ((f16x4*)xh)[i] = h;
  }
}

// ---------------- all three W f32 -> f16 (Wq also lo) in one launch --------------
__global__ __launch_bounds__(256) void wsplit3_kernel(const float* __restrict__ Wq,
    const float* __restrict__ Wk, const float* __restrict__ Wv,
    f16* __restrict__ WQH, f16* __restrict__ WQL,
    f16* __restrict__ WKH, f16* __restrict__ WVH, int n4) {
  const int which = blockIdx.y;
  const float* w = (which == 0) ? Wq : ((which == 1) ? Wk : Wv);
  f16* wh = (which == 0) ? WQH : ((which == 1) ? WKH : WVH);
  const int withlo = (which == 0);
  int i = blockIdx.x * 256 + threadIdx.x;
  int stride = gridDim.x * 256;
  for (; i < n4; i += stride) {
    f32x4 v = ((const f32x4*)w)[i];
    f16x4 h, l;
    #pragma unroll
    for (int j = 0; j < 4; ++j) {
      h[j] = (f16)v[j];
      l[j] = (f16)((v[j] - (float)h[j]) * 2048.0f);
    }
    ((f16x4*)wh)[i] = h;
    if (withlo) ((f16x4*)WQL)[i] = l;
  }
}

// ---------------- mean over L from XH (f16) ----------------
__global__ __launch_bounds__(256) void meansum_kernel(const f16* __restrict__ xh,
                                                      float* __restrict__ meanx) {
  int b = blockIdx.x;
  int d = blockIdx.y * 256 + threadIdx.x;
  int l0 = blockIdx.z * 256;
  const f16* p = xh + ((size_t)b * L_ + l0) * DM + d;
  float s = 0.f;
  for (int i = 0; i < 256; ++i) s += (float)p[(size_t)i * DM];
  atomicAdd(&meanx[b * DM + d], s);
}

// f32 mean fallback (small-ws diagnostic path)
__global__ __launch_bounds__(256) void meansum32_kernel(const float* __restrict__ x,
                                                        float* __restrict__ meanx) {
  int b = blockIdx.x;
  int d = blockIdx.y * 256 + threadIdx.x;
  int l0 = blockIdx.z * 256;
  const float* p = x + ((size_t)b * L_ + l0) * DM + d;
  float s = 0.f;
  for (int i = 0; i < 256; ++i) s += p[(size_t)i * DM];
  atomicAdd(&meanx[b * DM + d], s);
}

// vout(b,n) = (vin(b,:) . W[n,:]) * scale + bias[n]
__global__ __launch_bounds__(256) void proj_vec_kernel(const float* __restrict__ vin,
    const float* __restrict__ W, const float* __restrict__ bias,
    float* __restrict__ vout, float scale) {
  int g = blockIdx.x * 256 + threadIdx.x;
  int b = g >> 10, n = g & 1023;
  const float* xr = vin + b * DM;
  const float* wr = W + (size_t)n * DM;
  float a0 = 0, a1 = 0, a2 = 0, a3 = 0;
  for (int d = 0; d < DM; d += 4) {
    a0 += xr[d + 0] * wr[d + 0];
    a1 += xr[d + 1] * wr[d + 1];
    a2 += xr[d + 2] * wr[d + 2];
    a3 += xr[d + 3] * wr[d + 3];
  }
  vout[g] = ((a0 + a1) + (a2 + a3)) * scale + bias[n];
}

// ---------------- k_sample rows, f32 LDS-tiled: KS[b][s][n] ----------------
__global__ __launch_bounds__(256, 4) void ksample_kernel(const float* __restrict__ x,
    const float* __restrict__ Wk, const float* __restrict__ bk,
    const int* __restrict__ sidx, float* __restrict__ KS) {
  const int b = blockIdx.x, nc = blockIdx.y, sg = blockIdx.z;
  __shared__ float xs[5][32];
  __shared__ float wk[64][33];
  __shared__ float red[4][5][64];
  __shared__ int ls[5];
  const int tid = threadIdx.x;
  const int nl = tid & 63, kq = tid >> 6;
  if (tid < 5) ls[tid] = sidx[sg * 5 + tid];
  float acc[5] = {0.f, 0.f, 0.f, 0.f, 0.f};
  const int wrow = tid >> 2, wq = tid & 3;
  for (int kt = 0; kt < 32; ++kt) {
    const int d0 = kt * 32;
    __syncthreads();
    if (tid < 40) {
      int s = tid >> 3, q = tid & 7;
      *(f32x4*)&xs[s][q * 4] = *(const f32x4*)&x[((size_t)b * L_ + ls[s]) * DM + d0 + q * 4];
    }
    {
      const float* src = &Wk[(size_t)(nc * 64 + wrow) * DM + d0 + wq * 8];
      *(f32x4*)&wk[wrow][wq * 8]     = *(const f32x4*)src;
      *(f32x4*)&wk[wrow][wq * 8 + 4] = *(const f32x4*)(src + 4);
    }
    __syncthreads();
    #pragma unroll
    for (int i = 0; i < 2; ++i) {
      f32x4 w = *(const f32x4*)&wk[nl][kq * 8 + i * 4];
      #pragma unroll
      for (int s = 0; s < 5; ++s) {
        f32x4 xv = *(const f32x4*)&xs[s][kq * 8 + i * 4];
        acc[s] += xv[0] * w[0] + xv[1] * w[1] + xv[2] * w[2] + xv[3] * w[3];
      }
    }
  }
  #pragma unroll
  for (int s = 0; s < 5; ++s) red[kq][s][nl] = acc[s];
  __syncthreads();
  for (int t = tid; t < 5 * 64; t += 256) {
    int s = t >> 6, j = t & 63;
    int nj = nc * 64 + j;
    KS[((size_t)b * SK + sg * 5 + s) * DM + nj] =
        red[0][s][j] + red[1][s][j] + red[2][s][j] + red[3][s][j] + bk[nj];
  }
}

// ---- P[b][h*48+s][nc*64+c] = sum_d Wq[h*64+d][nc*64+c] * KS[b][s][h*64+d] --------
__global__ __launch_bounds__(256, 4) void pcomp_kernel(const float* __restrict__ Wq,
    const float* __restrict__ KS, f16* __restrict__ PH, f16* __restrict__ PL) {
  const int b = blockIdx.x, h = blockIdx.y, nc = blockIdx.z;
  __shared__ float ks[45][64];
  __shared__ float wqT[64][68];
  const int tid = threadIdx.x;
  const int n0 = nc * 64;
  for (int i = tid; i < 45 * 64; i += 256) {
    int s = i >> 6, d = i & 63;
    ks[s][d] = KS[((size_t)b * SK + s) * DM + h * 64 + d];
  }
  for (int t = tid; t < 1024; t += 256) {
    int row = t >> 4, cg = t & 15;
    f32x4 v = *(const f32x4*)&Wq[(size_t)(h * 64 + row) * DM + n0 + cg * 4];
    #pragma unroll
    for (int j = 0; j < 4; ++j) wqT[cg * 4 + j][row] = v[j];
  }
  __syncthreads();
  for (int t = tid; t < 48 * 64; t += 256) {
    int s = t >> 6, c = t & 63;
    float acc = 0.f;
    if (s < SK) {
      const f32x4* wr = (const f32x4*)&wqT[c][0];
      const f32x4* kr = (const f32x4*)&ks[s][0];
      float a0 = 0, a1 = 0, a2 = 0, a3 = 0;
      #pragma unroll
      for (int i = 0; i < 16; ++i) {
        f32x4 wv = wr[i], kv = kr[i];
        a0 += wv[0] * kv[0]; a1 += wv[1] * kv[1];
        a2 += wv[2] * kv[2]; a3 += wv[3] * kv[3];
      }
      acc = (a0 + a1) + (a2 + a3);
    }
    f16 hv = (f16)acc;
    size_t off = ((size_t)b * 768 + h * 48 + s) * DM + n0 + c;
    PH[off] = hv;
    PL[off] = (f16)((acc - (float)hv) * 2048.0f);
  }
}

// ---- scores GEMM + fused m-statistics (no SC materialization) --------------------
// Per block: partial max/sum per (row, h) over in-tile s range; atomics into
// MMAX (order-preserving uint encoding) and MSUM.
__global__ __launch_bounds__(256, 2) void gemm_sc(const float* __restrict__ x,
    const f16* __restrict__ PH, const f16* __restrict__ PL,
    unsigned* __restrict__ MMAXu, float* __restrict__ MSUM) {
  __shared__ __align__(16) char pool[33792];
  f16* xh = (f16*)pool;                 // phase A: 8192
  f16* xl = (f16*)(pool + 8192);
  f16* wh = (f16*)(pool + 16384);
  f16* wl = (f16*)(pool + 24576);       // ends 32768
  float* scf = (float*)pool;            // phase B: [64][132] f32 = 33792
  const int tid = threadIdx.x;
  const int g = blockIdx.y * 8 + blockIdx.x;    // XCD = g & 7
  const int q = g >> 3;                          // 0..191
  const int nt = q % 6;                          // N-tile cycles fastest
  const int mt = (g & 7) + (q / 6) * 8;          // A-panel pinned to XCD
  const int n0 = nt * 128;
  const int m0 = mt * 128;
  const int bb = mt >> 5;                        // batch of this M-tile
  const int lane = tid & 63;
  const int wave = tid >> 6;
  const int wr = (wave >> 1) * 64;
  const int wc = (wave & 1) * 64;
  const int frow = lane & 15;
  const int fk = (lane >> 4) * 8;

  f32x4 aH[4][4], aL[4][4];
  #pragma unroll
  for (int i = 0; i < 4; ++i)
    #pragma unroll
    for (int j = 0; j < 4; ++j)
      #pragma unroll
      for (int z = 0; z < 4; ++z) { aH[i][j][z] = 0.f; aL[i][j][z] = 0.f; }

  const int ar = tid >> 1;
  const int ac = (tid & 1) * 16;
  const int r2 = tid >> 2;
  const int cb = (tid & 3) * 8;
  const int cbs = cb ^ (((r2 >> 1) & 3) << 3);

  const size_t pbase = (size_t)bb * 768;
  for (int kt = 0; kt < 32; ++kt) {
    const float* gx = x + (size_t)(m0 + ar) * DM + kt * 32 + ac;
    #pragma unroll
    for (int gi = 0; gi < 4; ++gi) {
      f32x4 v = ((const f32x4*)gx)[gi];
      f16x4 h, l;
      #pragma unroll
      for (int z = 0; z < 4; ++z) {
        h[z] = (f16)v[z];
        l[z] = (f16)((v[z] - (float)h[z]) * 2048.0f);
      }
      *(f16x4*)(xh + swz(ar, ac + gi * 4)) = h;
      *(f16x4*)(xl + swz(ar, ac + gi * 4)) = l;
    }
    gload_lds16(PH + (pbase + n0 + r2) * DM + kt * 32 + cbs,      wh + r2 * 32 + cb);
    gload_lds16(PH + (pbase + n0 + r2 + 64) * DM + kt * 32 + cbs, wh + (r2 + 64) * 32 + cb);
    gload_lds16(PL + (pbase + n0 + r2) * DM + kt * 32 + cbs,      wl + r2 * 32 + cb);
    gload_lds16(PL + (pbase + n0 + r2 + 64) * DM + kt * 32 + cbs, wl + (r2 + 64) * 32 + cb);
    __syncthreads();
    f16x8 ah[4], al[4], bh[4], bl[4];
    #pragma unroll
    for (int mi = 0; mi < 4; ++mi) {
      ah[mi] = *(const f16x8*)(xh + swz(wr + mi * 16 + frow, fk));
      al[mi] = *(const f16x8*)(xl + swz(wr + mi * 16 + frow, fk));
    }
    #pragma unroll
    for (int ni = 0; ni < 4; ++ni) {
      bh[ni] = *(const f16x8*)(wh + swz(wc + ni * 16 + frow, fk));
      bl[ni] = *(const f16x8*)(wl + swz(wc + ni * 16 + frow, fk));
    }
    #pragma unroll
    for (int mi = 0; mi < 4; ++mi)
      #pragma unroll
      for (int ni = 0; ni < 4; ++ni) {
        aH[mi][ni] = __builtin_amdgcn_mfma_f32_16x16x32_f16(ah[mi], bh[ni], aH[mi][ni], 0, 0, 0);
        aL[mi][ni] = __builtin_amdgcn_mfma_f32_16x16x32_f16(ah[mi], bl[ni], aL[mi][ni], 0, 0, 0);
        aL[mi][ni] = __builtin_amdgcn_mfma_f32_16x16x32_f16(al[mi], bh[ni], aL[mi][ni], 0, 0, 0);
      }
    __syncthreads();
  }

  // fused epilogue: two 64-row halves through aliased LDS -> per-(row,h) partials
  const int hbase = n0 / 48;
  #pragma unroll
  for (int half = 0; half < 2; ++half) {
    __syncthreads();
    if ((wave >> 1) == half) {
      #pragma unroll
      for (int mi = 0; mi < 4; ++mi)
        #pragma unroll
        for (int ni = 0; ni < 4; ++ni) {
          int coll = wc + ni * 16 + (lane & 15);
          #pragma unroll
          for (int j = 0; j < 4; ++j) {
            int rowl = mi * 16 + (lane >> 4) * 4 + j;
            scf[rowl * 132 + coll] =
                (aH[mi][ni][j] + aL[mi][ni][j] * (1.0f / 2048.0f)) * 0.125f;
          }
        }
    }
    __syncthreads();
    {
      int row = tid >> 2, gidx = tid & 3;
      int h = hbase + gidx;
      if (h < NH) {
        int slo = n0 - h * 48; if (slo < 0) slo = 0;
        int shi = n0 + 128 - h * 48; if (shi > SK) shi = SK;
        if (slo < shi) {
          float mx = -FLT_MAX, sum = 0.f;
          const float* pr = scf + row * 132 + (h * 48 - n0);
          for (int s = slo; s < shi; ++s) {
            float v = pr[s];
            mx = fmaxf(mx, v);
            sum += v;
          }
          int gl = (m0 & 4095) + half * 64 + row;
          size_t idx = ((size_t)(bb * NH + h)) * L_ + gl;
          int bmx = __float_as_int(mx);
          unsigned key = (unsigned)(bmx ^ ((bmx >> 31) | (int)0x80000000));
          atomicMax(&MMAXu[idx], key);
          atomicAdd(&MSUM[idx], sum);
        }
      }
    }
  }
}

// ---------------- top-45 per (b,h): decode m = max - mean, iterative argmax -------
__global__ __launch_bounds__(256) void topk_kernel(const unsigned* __restrict__ MMAXu,
    const float* __restrict__ MSUM, int* __restrict__ topi) {
  __shared__ float vals[L_];
  __shared__ float wv[4];
  __shared__ int wi[4];
  const int bh = blockIdx.x, tid = threadIdx.x;
  for (int i = tid; i < L_; i += 256) {
    unsigned key = MMAXu[(size_t)bh * L_ + i];
    int bits = (key & 0x80000000u) ? (int)(key ^ 0x80000000u) : ~(int)key;
    vals[i] = __int_as_float(bits) - MSUM[(size_t)bh * L_ + i] * (1.0f / SK);
  }
  __syncthreads();
  const int lane = tid & 63, wave = tid >> 6;
  for (int it = 0; it < SK; ++it) {
    float best = -FLT_MAX;
    int bi = 1 << 30;
    for (int i = tid; i < L_; i += 256) {
      float v = vals[i];
      if (v > best || (v == best && i < bi)) { best = v; bi = i; }
    }
    #pragma unroll
    for (int off = 32; off; off >>= 1) {
      float ov = __shfl_down(best, off);
      int oi = __shfl_down(bi, off);
      if (ov > best || (ov == best && oi < bi)) { best = ov; bi = oi; }
    }
    if (lane == 0) { wv[wave] = best; wi[wave] = bi; }
    __syncthreads();
    if (tid == 0) {
      float bb = wv[0]; int bj = wi[0];
      for (int w = 1; w < 4; ++w)
        if (wv[w] > bb || (wv[w] == bb && wi[w] < bj)) { bb = wv[w]; bj = wi[w]; }
      topi[bh * SK + it] = bj;
      vals[bj] = -FLT_MAX;
    }
    __syncthreads();
  }
}

// ---- q_top recompute, ksample-style f32 tiles: QT[bh][48][64] f16 ----------------
__global__ __launch_bounds__(256, 4) void qtop5_kernel(const float* __restrict__ x,
    const float* __restrict__ Wq, const float* __restrict__ bq,
    const int* __restrict__ topi, f16* __restrict__ QT) {
  const int b = blockIdx.x, h = blockIdx.y, sg = blockIdx.z;
  const int bh = b * NH + h;
  __shared__ float xs[5][32];
  __shared__ float wq[64][33];
  __shared__ float red[4][5][64];
  __shared__ int ls[5];
  const int tid = threadIdx.x;
  const int nl = tid & 63, kq = tid >> 6;
  if (tid < 5) ls[tid] = topi[bh * SK + sg * 5 + tid];
  float acc[5] = {0.f, 0.f, 0.f, 0.f, 0.f};
  const int wrow = tid >> 2, wqc = tid & 3;
  for (int kt = 0; kt < 32; ++kt) {
    const int d0 = kt * 32;
    __syncthreads();
    if (tid < 40) {
      int s = tid >> 3, q = tid & 7;
      *(f32x4*)&xs[s][q * 4] = *(const f32x4*)&x[((size_t)b * L_ + ls[s]) * DM + d0 + q * 4];
    }
    {
      const float* src = &Wq[(size_t)(h * 64 + wrow) * DM + d0 + wqc * 8];
      *(f32x4*)&wq[wrow][wqc * 8]     = *(const f32x4*)src;
      *(f32x4*)&wq[wrow][wqc * 8 + 4] = *(const f32x4*)(src + 4);
    }
    __syncthreads();
    #pragma unroll
    for (int i = 0; i < 2; ++i) {
      f32x4 w = *(const f32x4*)&wq[nl][kq * 8 + i * 4];
      #pragma unroll
      for (int s = 0; s < 5; ++s) {
        f32x4 xv = *(const f32x4*)&xs[s][kq * 8 + i * 4];
        acc[s] += xv[0] * w[0] + xv[1] * w[1] + xv[2] * w[2] + xv[3] * w[3];
      }
    }
  }
  #pragma unroll
  for (int s = 0; s < 5; ++s) red[kq][s][nl] = acc[s];
  __syncthreads();
  for (int t = tid; t < 5 * 64; t += 256) {
    int s = t >> 6, j = t & 63;
    QT[bh * 3072 + (sg * 5 + s) * 64 + j] =
        (f16)(red[0][s][j] + red[1][s][j] + red[2][s][j] + red[3][s][j] + bq[h * 64 + j]);
  }
}

// ---- fused K+V GEMM + scores + inline-exp PV: atomics into OT, Zb. No S/V in HBM.
__global__ __launch_bounds__(256, 2) void kscore_kernel(const f16* __restrict__ XH,
    const f16* __restrict__ WKH, const f16* __restrict__ WVH,
    const float* __restrict__ bk, const float* __restrict__ bvec,
    const f16* __restrict__ QT, float* __restrict__ OT, float* __restrict__ Zb) {
  __shared__ __align__(16) char smem[68352];
  f16* qs = (f16*)smem;                  // phase1-2: 48*72*2 = 6912
  f16* xh = (f16*)(smem + 6912);         // phase1:   16384
  f16* wh = (f16*)(smem + 23296);        // phase1:   8192
  f16* Kt = (f16*)(smem + 31488);        // phase2:   256*72*2 = 36864
  f16* Ps = (f16*)smem;                  // phase3-4: 48*264*2 = 25344 (over qs/xh)
  f16* Vt = (f16*)(smem + 31488);        // phase3-4: 64*264*2 = 33792 (over Kt)
  float* red = (float*)smem;             // phase5:   4*48*64*4 = 49152
  const int g = blockIdx.y * 128 + blockIdx.x;  // XCD = g & 7
  const int b = g & 7;
  const int p = g >> 3;
  const int jc = p >> 4;
  const int h = p & 15;
  const int bh = b * 16 + h;
  const int tid = threadIdx.x;
  const int lane = tid & 63, wave = tid >> 6;
  const int frow = lane & 15;
  const int fk = (lane >> 4) * 8;

  for (int i = tid; i < 48 * 64; i += 256)
    qs[(i >> 6) * 72 + (i & 63)] = QT[bh * 3072 + i];

  f32x4 accK[4][4], accV[4][4];
  #pragma unroll
  for (int i = 0; i < 4; ++i)
    #pragma unroll
    for (int j = 0; j < 4; ++j)
      #pragma unroll
      for (int z = 0; z < 4; ++z) { accK[i][j][z] = 0.f; accV[i][j][z] = 0.f; }

  const int r2 = tid >> 2, cb = (tid & 3) * 8;
  const int cbs = cb ^ (((r2 >> 1) & 3) << 3);
  for (int kt = 0; kt < 32; ++kt) {
    #pragma unroll
    for (int i = 0; i < 4; ++i)
      gload_lds16(XH + (size_t)(b * L_ + jc * 256 + i * 64 + r2) * DM + kt * 32 + cbs,
                  xh + (i * 64 + r2) * 32 + cb);
    gload_lds16(WKH + (size_t)(h * 64 + r2) * DM + kt * 32 + cbs, wh + r2 * 32 + cb);
    gload_lds16(WVH + (size_t)(h * 64 + r2) * DM + kt * 32 + cbs, wh + (r2 + 64) * 32 + cb);
    __syncthreads();
    f16x8 am[4], bnK[4], bnV[4];
    #pragma unroll
    for (int mi = 0; mi < 4; ++mi)
      am[mi] = *(const f16x8*)(xh + swz(wave * 64 + mi * 16 + frow, fk));
    #pragma unroll
    for (int ni = 0; ni < 4; ++ni) {
      bnK[ni] = *(const f16x8*)(wh + swz(ni * 16 + frow, fk));
      bnV[ni] = *(const f16x8*)(wh + swz(64 + ni * 16 + frow, fk));
    }
    #pragma unroll
    for (int mi = 0; mi < 4; ++mi)
      #pragma unroll
      for (int ni = 0; ni < 4; ++ni) {
        accK[mi][ni] = __builtin_amdgcn_mfma_f32_16x16x32_f16(am[mi], bnK[ni], accK[mi][ni], 0, 0, 0);
        accV[mi][ni] = __builtin_amdgcn_mfma_f32_16x16x32_f16(am[mi], bnV[ni], accV[mi][ni], 0, 0, 0);
      }
    __syncthreads();
  }

  #pragma unroll
  for (int mi = 0; mi < 4; ++mi) {
    int jl = wave * 64 + mi * 16 + (lane >> 4) * 4;
    #pragma unroll
    for (int ni = 0; ni < 4; ++ni) {
      int d = ni * 16 + (lane & 15);
      float bc = bk[h * 64 + d];
      #pragma unroll
      for (int z = 0; z < 4; ++z)
        Kt[(jl + z) * 72 + d] = (f16)(accK[mi][ni][z] + bc);
    }
  }
  __syncthreads();

  f32x4 accS[3][4];
  #pragma unroll
  for (int i = 0; i < 3; ++i)
    #pragma unroll
    for (int j = 0; j < 4; ++j)
      #pragma unroll
      for (int z = 0; z < 4; ++z) accS[i][j][z] = 0.f;
  #pragma unroll
  for (int ks = 0; ks < 2; ++ks) {
    f16x8 aq[3], bv[4];
    #pragma unroll
    for (int mu = 0; mu < 3; ++mu)
      aq[mu] = *(const f16x8*)(qs + (mu * 16 + frow) * 72 + ks * 32 + fk);
    #pragma unroll
    for (int nj = 0; nj < 4; ++nj)
      bv[nj] = *(const f16x8*)(Kt + (wave * 64 + nj * 16 + frow) * 72 + ks * 32 + fk);
    #pragma unroll
    for (int mu = 0; mu < 3; ++mu)
      #pragma unroll
      for (int nj = 0; nj < 4; ++nj)
        accS[mu][nj] = __builtin_amdgcn_mfma_f32_16x16x32_f16(aq[mu], bv[nj], accS[mu][nj], 0, 0, 0);
  }
  __syncthreads();   // qs/Kt reads done; Ps/Vt (aliased) writes are now safe

  #pragma unroll
  for (int mi = 0; mi < 4; ++mi) {
    int jl = wave * 64 + mi * 16 + (lane >> 4) * 4;
    #pragma unroll
    for (int ni = 0; ni < 4; ++ni) {
      int d = ni * 16 + (lane & 15);
      float bc = bvec[h * 64 + d];
      #pragma unroll
      for (int z = 0; z < 4; ++z)
        Vt[d * 264 + jl + z] = (f16)(accV[mi][ni][z] + bc);
    }
  }
  {
    float zs[3][4];
    #pragma unroll
    for (int mu = 0; mu < 3; ++mu)
      #pragma unroll
      for (int z = 0; z < 4; ++z) zs[mu][z] = 0.f;
    #pragma unroll
    for (int mu = 0; mu < 3; ++mu)
      #pragma unroll
      for (int nj = 0; nj < 4; ++nj) {
        int j = wave * 64 + nj * 16 + (lane & 15);
        #pragma unroll
        for (int z = 0; z < 4; ++z) {
          int u = mu * 16 + (lane >> 4) * 4 + z;
          float pv = __expf(accS[mu][nj][z] * 0.125f);
          Ps[u * 264 + j] = (f16)pv;
          zs[mu][z] += pv;
        }
      }
    #pragma unroll
    for (int mu = 0; mu < 3; ++mu)
      #pragma unroll
      for (int z = 0; z < 4; ++z) {
        float v = zs[mu][z];
        v += __shfl_xor(v, 1);
        v += __shfl_xor(v, 2);
        v += __shfl_xor(v, 4);
        v += __shfl_xor(v, 8);
        int u = mu * 16 + (lane >> 4) * 4 + z;
        if ((lane & 15) == 0 && u < SK) atomicAdd(&Zb[bh * 48 + u], v);
      }
  }
  __syncthreads();

  f32x4 accO[3][4];
  #pragma unroll
  for (int i = 0; i < 3; ++i)
    #pragma unroll
    for (int j = 0; j < 4; ++j)
      #pragma unroll
      for (int z = 0; z < 4; ++z) accO[i][j][z] = 0.f;
  #pragma unroll
  for (int ks = 0; ks < 2; ++ks) {
    f16x8 ap[3], bvv[4];
    #pragma unroll
    for (int mu = 0; mu < 3; ++mu)
      ap[mu] = *(const f16x8*)(Ps + (mu * 16 + frow) * 264 + wave * 64 + ks * 32 + fk);
    #pragma unroll
    for (int nd = 0; nd < 4; ++nd)
      bvv[nd] = *(const f16x8*)(Vt + (nd * 16 + frow) * 264 + wave * 64 + ks * 32 + fk);
    #pragma unroll
    for (int mu = 0; mu < 3; ++mu)
      #pragma unroll
      for (int nd = 0; nd < 4; ++nd)
        accO[mu][nd] = __builtin_amdgcn_mfma_f32_16x16x32_f16(ap[mu], bvv[nd], accO[mu][nd], 0, 0, 0);
  }
  __syncthreads();   // Ps/Vt reads done; red (aliased) writes safe

  #pragma unroll
  for (int mu = 0; mu < 3; ++mu) {
    #pragma unroll
    for (int nd = 0; nd < 4; ++nd) {
      int d = nd * 16 + (lane & 15);
      #pragma unroll
      for (int z = 0; z < 4; ++z) {
        int u = mu * 16 + (lane >> 4) * 4 + z;
        red[wave * 3072 + u * 64 + d] = accO[mu][nd][z];
      }
    }
  }
  __syncthreads();
  for (int i = tid; i < 3072; i += 256) {
    int u = i >> 6;
    if (u < SK)
      atomicAdd(&OT[((size_t)bh * SK + u) * DH + (i & 63)],
                red[i] + red[3072 + i] + red[6144 + i] + red[9216 + i]);
  }
}

// ---------------- out = broadcast(base) ----------------
__global__ __launch_bounds__(256) void basewrite_kernel(const float* __restrict__ base,
                                                        float* __restrict__ out) {
  size_t i = (size_t)blockIdx.x * 256 + threadIdx.x;
  const size_t stride = (size_t)gridDim.x * 256;
  const size_t total = (size_t)B_ * L_ * (DM / 4);
  for (; i < total; i += stride) {
    size_t b = i >> 20;
    size_t c = i & 255;
    ((f32x4*)out)[i] = ((const f32x4*)base)[b * 256 + c];
  }
}

// ---------------- corrections: out[b, top_u, n] += (OT/Z - MV) . Wo[n, h*64:] -----
__global__ __launch_bounds__(256, 2) void corr_kernel(const float* __restrict__ OT,
    const float* __restrict__ Zb, const float* __restrict__ MV,
    const float* __restrict__ Wo, const int* __restrict__ topi,
    float* __restrict__ out) {
  __shared__ float dv[SK][64];
  __shared__ float wo[64][65];
  __shared__ float invz[SK];
  __shared__ int lidx[SK];
  const int bh = blockIdx.x, q = blockIdx.y, tid = threadIdx.x;
  const int b = bh >> 4, h = bh & 15;
  if (tid < SK) {
    invz[tid] = 1.0f / Zb[bh * 48 + tid];
    lidx[tid] = topi[bh * SK + tid];
  }
  __syncthreads();
  for (int i = tid; i < SK * 64; i += 256) {
    int u = i >> 6, d = i & 63;
    dv[u][d] = OT[((size_t)bh * SK + u) * DH + d] * invz[u] - MV[b * DM + h * DH + d];
  }
  const int nn = tid & 63, ug = tid >> 6;
  for (int c = 0; c < 4; ++c) {
    const int n0 = q * 256 + c * 64;
    __syncthreads();
    for (int t = tid; t < 1024; t += 256) {
      int row = t >> 4, vc = t & 15;
      f32x4 v = *(const f32x4*)&Wo[(size_t)(n0 + row) * DM + h * DH + vc * 4];
      *(f32x4*)&wo[row][vc * 4] = v;
    }
    __syncthreads();
    #pragma unroll
    for (int i = 0; i < 12; ++i) {
      int u = ug + i * 4;
      if (u >= SK) break;
      float a0 = 0, a1 = 0, a2 = 0, a3 = 0;
      #pragma unroll
      for (int d4 = 0; d4 < 16; ++d4) {
        f32x4 w = *(const f32x4*)&wo[nn][d4 * 4];
        f32x4 dd = *(const f32x4*)&dv[u][d4 * 4];
        a0 += dd[0] * w[0]; a1 += dd[1] * w[1];
        a2 += dd[2] * w[2]; a3 += dd[3] * w[3];
      }
      atomicAdd(&out[((size_t)b * L_ + lidx[u]) * DM + n0 + nn], (a0 + a1) + (a2 + a3));
    }
  }
}

// ---------------- workspace layout (zero-init region contiguous) ------------------
static const size_t OFF_XH   = 0;                        // 67108864
static const size_t OFF_WQH  = OFF_XH + 67108864;        // 2097152
static const size_t OFF_WQL  = OFF_WQH + 2097152;
static const size_t OFF_WKH  = OFF_WQL + 2097152;
static const size_t OFF_WVH  = OFF_WKH + 2097152;
static const size_t OFF_KS   = OFF_WVH + 2097152;        // 1474560
static const size_t OFF_MV   = OFF_KS + 1474560;         // 32768
static const size_t OFF_BASE = OFF_MV + 32768;           // 32768
static const size_t OFF_TOPI = OFF_BASE + 32768;         // 23040 -> pad 24576
// zero-init block:
static const size_t OFF_MEANX= OFF_TOPI + 24576;         // 32768
static const size_t OFF_ZB   = OFF_MEANX + 32768;        // 24576
static const size_t OFF_QT   = OFF_ZB + 24576;           // 786432
static const size_t OFF_MMAX = OFF_QT + 786432;          // 2097152
static const size_t OFF_MSUM = OFF_MMAX + 2097152;       // 2097152
static const size_t OFF_OT   = OFF_MSUM + 2097152;       // 1474560
static const size_t ZERO_SZ  = OFF_OT + 1474560 - OFF_MEANX;   // 6512640
// end zero block:
static const size_t OFF_PH   = OFF_OT + 1474560;         // 12582912
static const size_t OFF_PL   = OFF_PH + 12582912;        // 12582912
static const size_t WS_NEED  = OFF_PL + 12582912;        // ~108.7 MB

extern "C" void kernel_launch(void* const* d_in, const int* in_sizes, int n_in,
                              void* d_out, int out_size, void* d_ws, size_t ws_size,
                              hipStream_t stream) {
  const float* x  = (const float*)d_in[0];
  const float* Wq = (const float*)d_in[1];
  const float* bq = (const float*)d_in[2];
  const float* Wk = (const float*)d_in[3];
  const float* bk = (const float*)d_in[4];
  const float* Wv = (const float*)d_in[5];
  const float* bv = (const float*)d_in[6];
  const float* Wo = (const float*)d_in[7];
  const float* bo = (const float*)d_in[8];
  const int* sidx = (const int*)d_in[9];
  float* out = (float*)d_out;
  char* ws = (char*)d_ws;

  if (ws_size < WS_NEED) {
    if (ws_size < 131072) return;
    float* MEANX = (float*)(ws + 0);
    float* MV    = (float*)(ws + 32768);
    float* BASE  = (float*)(ws + 65536);
    hipMemsetAsync(MEANX, 0, 32768, stream);
    meansum32_kernel<<<dim3(B_, 4, 16), 256, 0, stream>>>(x, MEANX);
    proj_vec_kernel<<<32, 256, 0, stream>>>(MEANX, Wv, bv, MV, 1.0f / L_);
    proj_vec_kernel<<<32, 256, 0, stream>>>(MV, Wo, bo, BASE, 1.0f);
    basewrite_kernel<<<2048, 256, 0, stream>>>(BASE, out);
    return;
  }

  f16*   XH   = (f16*)(ws + OFF_XH);
  f16*   WQH  = (f16*)(ws + OFF_WQH);
  f16*   WQL  = (f16*)(ws + OFF_WQL);
  f16*   WKH  = (f16*)(ws + OFF_WKH);
  f16*   WVH  = (f16*)(ws + OFF_WVH);
  float* KS   = (float*)(ws + OFF_KS);
  float* MV   = (float*)(ws + OFF_MV);
  float* BASE = (float*)(ws + OFF_BASE);
  int*   TOPI = (int*)(ws + OFF_TOPI);
  float* MEANX= (float*)(ws + OFF_MEANX);
  float* ZB   = (float*)(ws + OFF_ZB);
  f16*   QT   = (f16*)(ws + OFF_QT);
  unsigned* MMAXu = (unsigned*)(ws + OFF_MMAX);
  float* MSUM = (float*)(ws + OFF_MSUM);
  float* OT   = (float*)(ws + OFF_OT);
  f16*   PH   = (f16*)(ws + OFF_PH);
  f16*   PL   = (f16*)(ws + OFF_PL);

  // 1. conversions / splits / single zero-init
  xsplit16_kernel<<<2048, 256, 0, stream>>>(x, XH, (int)((size_t)B_ * L_ * DM / 4));
  wsplit3_kernel<<<dim3(256, 3), 256, 0, stream>>>(Wq, Wk, Wv, WQH, WQL, WKH, WVH,
                                                   DM * DM / 4);
  hipMemsetAsync(ws + OFF_MEANX, 0, ZERO_SZ, stream);

  // 2. mean path (reads XH f16)
  meansum_kernel<<<dim3(B_, 4, 16), 256, 0, stream>>>(XH, MEANX);
  proj_vec_kernel<<<32, 256, 0, stream>>>(MEANX, Wv, bv, MV, 1.0f / L_);
  proj_vec_kernel<<<32, 256, 0, stream>>>(MV, Wo, bo, BASE, 1.0f);

  // 3. sampled K rows -> P = Wq_h^T k_s -> scores GEMM with fused m-statistics
  ksample_kernel<<<dim3(B_, 16, 9), 256, 0, stream>>>(x, Wk, bk, sidx, KS);
  pcomp_kernel<<<dim3(B_, NH, 16), 256, 0, stream>>>(Wq, KS, PH, PL);
  gemm_sc<<<dim3(8, 192), 256, 0, stream>>>(x, PH, PL, MMAXu, MSUM);

  // 4. top-k (decodes m) + q_top recompute
  topk_kernel<<<B_ * NH, 256, 0, stream>>>(MMAXu, MSUM, TOPI);
  qtop5_kernel<<<dim3(B_, NH, 9), 256, 0, stream>>>(x, Wq, bq, TOPI, QT);

  // 5. fully fused K+V GEMM + scores + exp-PV
  kscore_kernel<<<dim3(128, 16), 256, 0, stream>>>(XH, WKH, WVH, bk, bv, QT, OT, ZB);

  // 6. output assembly
  basewrite_kernel<<<2048, 256, 0, stream>>>(BASE, out);
  corr_kernel<<<dim3(B_ * NH, 4), 256, 0, stream>>>(OT, ZB, MV, Wo, TOPI, out);
}

// Round 15
// 764.705 us; speedup vs baseline: 1.2991x; 1.0245x over previous
//
#include <hip/hip_runtime.h>
#include <cfloat>
#include <cstdint>

#define B_  8
#define L_  4096
#define DM  1024
#define NH  16
#define DH  64
#define SK  45

typedef __attribute__((ext_vector_type(4))) float f32x4;
typedef _Float16 f16;
typedef __attribute__((ext_vector_type(4))) _Float16 f16x4;
typedef __attribute__((ext_vector_type(8))) _Float16 f16x8;

__device__ __forceinline__ void gload_lds16(const void* g, void* l) {
  __builtin_amdgcn_global_load_lds(
      (const __attribute__((address_space(1))) unsigned int*)g,
      (__attribute__((address_space(3))) unsigned int*)l, 16, 0, 0);
}

// XOR-swizzled f16 index into a [rows][32] f16 tile (64B rows), granule 8 f16.
__device__ __forceinline__ int swz(int row, int c) {
  return row * 32 + (c ^ (((row >> 1) & 3) << 3));
}

// ---------------- x f32 -> f16 hi (ws) + f16 lo*2048 (d_out scratch) --------------
__global__ __launch_bounds__(256) void xsplit2_kernel(const float* __restrict__ x,
    f16* __restrict__ xh, f16* __restrict__ xl, int n4) {
  int i = blockIdx.x * 256 + threadIdx.x;
  int stride = gridDim.x * 256;
  for (; i < n4; i += stride) {
    f32x4 v = ((const f32x4*)x)[i];
    f16x4 h, l;
    #pragma unroll
    for (int j = 0; j < 4; ++j) {
      h[j] = (f16)v[j];
      l[j] = (f16)((v[j] - (float)h[j]) * 2048.0f);
    }
    ((f16x4*)xh)[i] = h;
    ((f16x4*)xl)[i] = l;
  }
}

// ---------------- all three W f32 -> f16 (Wq also lo) in one launch --------------
__global__ __launch_bounds__(256) void wsplit3_kernel(const float* __restrict__ Wq,
    const float* __restrict__ Wk, const float* __restrict__ Wv,
    f16* __restrict__ WQH, f16* __restrict__ WQL,
    f16* __restrict__ WKH, f16* __restrict__ WVH, int n4) {
  const int which = blockIdx.y;
  const float* w = (which == 0) ? Wq : ((which == 1) ? Wk : Wv);
  f16* wh = (which == 0) ? WQH : ((which == 1) ? WKH : WVH);
  const int withlo = (which == 0);
  int i = blockIdx.x * 256 + threadIdx.x;
  int stride = gridDim.x * 256;
  for (; i < n4; i += stride) {
    f32x4 v = ((const f32x4*)w)[i];
    f16x4 h, l;
    #pragma unroll
    for (int j = 0; j < 4; ++j) {
      h[j] = (f16)v[j];
      l[j] = (f16)((v[j] - (float)h[j]) * 2048.0f);
    }
    ((f16x4*)wh)[i] = h;
    if (withlo) ((f16x4*)WQL)[i] = l;
  }
}

// ---------------- mean over L from XH (f16) ----------------
__global__ __launch_bounds__(256) void meansum_kernel(const f16* __restrict__ xh,
                                                      float* __restrict__ meanx) {
  int b = blockIdx.x;
  int d = blockIdx.y * 256 + threadIdx.x;
  int l0 = blockIdx.z * 256;
  const f16* p = xh + ((size_t)b * L_ + l0) * DM + d;
  float s = 0.f;
  for (int i = 0; i < 256; ++i) s += (float)p[(size_t)i * DM];
  atomicAdd(&meanx[b * DM + d], s);
}

// f32 mean fallback (small-ws diagnostic path)
__global__ __launch_bounds__(256) void meansum32_kernel(const float* __restrict__ x,
                                                        float* __restrict__ meanx) {
  int b = blockIdx.x;
  int d = blockIdx.y * 256 + threadIdx.x;
  int l0 = blockIdx.z * 256;
  const float* p = x + ((size_t)b * L_ + l0) * DM + d;
  float s = 0.f;
  for (int i = 0; i < 256; ++i) s += p[(size_t)i * DM];
  atomicAdd(&meanx[b * DM + d], s);
}

// vout(b,n) = (vin(b,:) . W[n,:]) * scale + bias[n]
__global__ __launch_bounds__(256) void proj_vec_kernel(const float* __restrict__ vin,
    const float* __restrict__ W, const float* __restrict__ bias,
    float* __restrict__ vout, float scale) {
  int g = blockIdx.x * 256 + threadIdx.x;
  int b = g >> 10, n = g & 1023;
  const float* xr = vin + b * DM;
  const float* wr = W + (size_t)n * DM;
  float a0 = 0, a1 = 0, a2 = 0, a3 = 0;
  for (int d = 0; d < DM; d += 4) {
    a0 += xr[d + 0] * wr[d + 0];
    a1 += xr[d + 1] * wr[d + 1];
    a2 += xr[d + 2] * wr[d + 2];
    a3 += xr[d + 3] * wr[d + 3];
  }
  vout[g] = ((a0 + a1) + (a2 + a3)) * scale + bias[n];
}

// ---------------- k_sample rows, f32 LDS-tiled: KS[b][s][n] ----------------
__global__ __launch_bounds__(256, 4) void ksample_kernel(const float* __restrict__ x,
    const float* __restrict__ Wk, const float* __restrict__ bk,
    const int* __restrict__ sidx, float* __restrict__ KS) {
  const int b = blockIdx.x, nc = blockIdx.y, sg = blockIdx.z;
  __shared__ float xs[5][32];
  __shared__ float wk[64][33];
  __shared__ float red[4][5][64];
  __shared__ int ls[5];
  const int tid = threadIdx.x;
  const int nl = tid & 63, kq = tid >> 6;
  if (tid < 5) ls[tid] = sidx[sg * 5 + tid];
  float acc[5] = {0.f, 0.f, 0.f, 0.f, 0.f};
  const int wrow = tid >> 2, wq = tid & 3;
  for (int kt = 0; kt < 32; ++kt) {
    const int d0 = kt * 32;
    __syncthreads();
    if (tid < 40) {
      int s = tid >> 3, q = tid & 7;
      *(f32x4*)&xs[s][q * 4] = *(const f32x4*)&x[((size_t)b * L_ + ls[s]) * DM + d0 + q * 4];
    }
    {
      const float* src = &Wk[(size_t)(nc * 64 + wrow) * DM + d0 + wq * 8];
      *(f32x4*)&wk[wrow][wq * 8]     = *(const f32x4*)src;
      *(f32x4*)&wk[wrow][wq * 8 + 4] = *(const f32x4*)(src + 4);
    }
    __syncthreads();
    #pragma unroll
    for (int i = 0; i < 2; ++i) {
      f32x4 w = *(const f32x4*)&wk[nl][kq * 8 + i * 4];
      #pragma unroll
      for (int s = 0; s < 5; ++s) {
        f32x4 xv = *(const f32x4*)&xs[s][kq * 8 + i * 4];
        acc[s] += xv[0] * w[0] + xv[1] * w[1] + xv[2] * w[2] + xv[3] * w[3];
      }
    }
  }
  #pragma unroll
  for (int s = 0; s < 5; ++s) red[kq][s][nl] = acc[s];
  __syncthreads();
  for (int t = tid; t < 5 * 64; t += 256) {
    int s = t >> 6, j = t & 63;
    int nj = nc * 64 + j;
    KS[((size_t)b * SK + sg * 5 + s) * DM + nj] =
        red[0][s][j] + red[1][s][j] + red[2][s][j] + red[3][s][j] + bk[nj];
  }
}

// ---- P[b][h*48+s][nc*64+c] = 0.125 * sum_d Wq[h*64+d][c'] * KS[b][s][h*64+d] -----
// (0.125 score scale folded into P)
__global__ __launch_bounds__(256, 4) void pcomp_kernel(const float* __restrict__ Wq,
    const float* __restrict__ KS, f16* __restrict__ PH, f16* __restrict__ PL) {
  const int b = blockIdx.x, h = blockIdx.y, nc = blockIdx.z;
  __shared__ float ks[45][64];
  __shared__ float wqT[64][68];
  const int tid = threadIdx.x;
  const int n0 = nc * 64;
  for (int i = tid; i < 45 * 64; i += 256) {
    int s = i >> 6, d = i & 63;
    ks[s][d] = KS[((size_t)b * SK + s) * DM + h * 64 + d];
  }
  for (int t = tid; t < 1024; t += 256) {
    int row = t >> 4, cg = t & 15;
    f32x4 v = *(const f32x4*)&Wq[(size_t)(h * 64 + row) * DM + n0 + cg * 4];
    #pragma unroll
    for (int j = 0; j < 4; ++j) wqT[cg * 4 + j][row] = v[j];
  }
  __syncthreads();
  for (int t = tid; t < 48 * 64; t += 256) {
    int s = t >> 6, c = t & 63;
    float acc = 0.f;
    if (s < SK) {
      const f32x4* wr = (const f32x4*)&wqT[c][0];
      const f32x4* kr = (const f32x4*)&ks[s][0];
      float a0 = 0, a1 = 0, a2 = 0, a3 = 0;
      #pragma unroll
      for (int i = 0; i < 16; ++i) {
        f32x4 wv = wr[i], kv = kr[i];
        a0 += wv[0] * kv[0]; a1 += wv[1] * kv[1];
        a2 += wv[2] * kv[2]; a3 += wv[3] * kv[3];
      }
      acc = ((a0 + a1) + (a2 + a3)) * 0.125f;
    }
    f16 hv = (f16)acc;
    size_t off = ((size_t)b * 768 + h * 48 + s) * DM + n0 + c;
    PH[off] = hv;
    PL[off] = (f16)((acc - (float)hv) * 2048.0f);
  }
}

// ---- scores GEMM + fused m-statistics; A staged via global_load_lds from XH/XL ---
__global__ __launch_bounds__(256, 2) void gemm_sc(const f16* __restrict__ XH,
    const f16* __restrict__ XL, const f16* __restrict__ PH,
    const f16* __restrict__ PL, unsigned* __restrict__ MMAXu,
    float* __restrict__ MSUM) {
  __shared__ __align__(16) char pool[33792];
  f16* xh = (f16*)pool;                 // phase A: 8192
  f16* xl = (f16*)(pool + 8192);
  f16* wh = (f16*)(pool + 16384);
  f16* wl = (f16*)(pool + 24576);       // ends 32768
  float* scf = (float*)pool;            // phase B: [64][132] f32 = 33792
  const int tid = threadIdx.x;
  const int g = blockIdx.y * 8 + blockIdx.x;    // XCD = g & 7
  const int q = g >> 3;                          // 0..191
  const int nt = q % 6;                          // N-tile cycles fastest
  const int mt = (g & 7) + (q / 6) * 8;          // A-panel pinned to XCD
  const int n0 = nt * 128;
  const int m0 = mt * 128;
  const int bb = mt >> 5;                        // batch of this M-tile
  const int lane = tid & 63;
  const int wave = tid >> 6;
  const int wr = (wave >> 1) * 64;
  const int wc = (wave & 1) * 64;
  const int frow = lane & 15;
  const int fk = (lane >> 4) * 8;

  f32x4 aH[4][4], aL[4][4];
  #pragma unroll
  for (int i = 0; i < 4; ++i)
    #pragma unroll
    for (int j = 0; j < 4; ++j)
      #pragma unroll
      for (int z = 0; z < 4; ++z) { aH[i][j][z] = 0.f; aL[i][j][z] = 0.f; }

  const int r2 = tid >> 2;
  const int cb = (tid & 3) * 8;
  const int cbs = cb ^ (((r2 >> 1) & 3) << 3);   // pre-swizzled source col
  // note: (r2+64)>>1 & 3 == r2>>1 & 3, so cbs is valid for both row halves

  const size_t pbase = (size_t)bb * 768;
  for (int kt = 0; kt < 32; ++kt) {
    const int kcol = kt * 32;
    gload_lds16(XH + (size_t)(m0 + r2) * DM + kcol + cbs,      xh + r2 * 32 + cb);
    gload_lds16(XH + (size_t)(m0 + r2 + 64) * DM + kcol + cbs, xh + (r2 + 64) * 32 + cb);
    gload_lds16(XL + (size_t)(m0 + r2) * DM + kcol + cbs,      xl + r2 * 32 + cb);
    gload_lds16(XL + (size_t)(m0 + r2 + 64) * DM + kcol + cbs, xl + (r2 + 64) * 32 + cb);
    gload_lds16(PH + (pbase + n0 + r2) * DM + kcol + cbs,      wh + r2 * 32 + cb);
    gload_lds16(PH + (pbase + n0 + r2 + 64) * DM + kcol + cbs, wh + (r2 + 64) * 32 + cb);
    gload_lds16(PL + (pbase + n0 + r2) * DM + kcol + cbs,      wl + r2 * 32 + cb);
    gload_lds16(PL + (pbase + n0 + r2 + 64) * DM + kcol + cbs, wl + (r2 + 64) * 32 + cb);
    __syncthreads();
    f16x8 ah[4], al[4], bh[4], bl[4];
    #pragma unroll
    for (int mi = 0; mi < 4; ++mi) {
      ah[mi] = *(const f16x8*)(xh + swz(wr + mi * 16 + frow, fk));
      al[mi] = *(const f16x8*)(xl + swz(wr + mi * 16 + frow, fk));
    }
    #pragma unroll
    for (int ni = 0; ni < 4; ++ni) {
      bh[ni] = *(const f16x8*)(wh + swz(wc + ni * 16 + frow, fk));
      bl[ni] = *(const f16x8*)(wl + swz(wc + ni * 16 + frow, fk));
    }
    #pragma unroll
    for (int mi = 0; mi < 4; ++mi)
      #pragma unroll
      for (int ni = 0; ni < 4; ++ni) {
        aH[mi][ni] = __builtin_amdgcn_mfma_f32_16x16x32_f16(ah[mi], bh[ni], aH[mi][ni], 0, 0, 0);
        aL[mi][ni] = __builtin_amdgcn_mfma_f32_16x16x32_f16(ah[mi], bl[ni], aL[mi][ni], 0, 0, 0);
        aL[mi][ni] = __builtin_amdgcn_mfma_f32_16x16x32_f16(al[mi], bh[ni], aL[mi][ni], 0, 0, 0);
      }
    __syncthreads();
  }

  // fused epilogue: two 64-row halves through aliased LDS -> per-(row,h) partials
  const int hbase = n0 / 48;
  #pragma unroll
  for (int half = 0; half < 2; ++half) {
    __syncthreads();
    if ((wave >> 1) == half) {
      #pragma unroll
      for (int mi = 0; mi < 4; ++mi)
        #pragma unroll
        for (int ni = 0; ni < 4; ++ni) {
          int coll = wc + ni * 16 + (lane & 15);
          #pragma unroll
          for (int j = 0; j < 4; ++j) {
            int rowl = mi * 16 + (lane >> 4) * 4 + j;
            scf[rowl * 132 + coll] = aH[mi][ni][j] + aL[mi][ni][j] * (1.0f / 2048.0f);
          }
        }
    }
    __syncthreads();
    {
      int row = tid >> 2, gidx = tid & 3;
      int h = hbase + gidx;
      if (h < NH) {
        int slo = n0 - h * 48; if (slo < 0) slo = 0;
        int shi = n0 + 128 - h * 48; if (shi > SK) shi = SK;
        if (slo < shi) {
          float mx = -FLT_MAX, sum = 0.f;
          const float* pr = scf + row * 132 + (h * 48 - n0);
          for (int s = slo; s < shi; ++s) {
            float v = pr[s];
            mx = fmaxf(mx, v);
            sum += v;
          }
          int gl = (m0 & 4095) + half * 64 + row;
          size_t idx = ((size_t)(bb * NH + h)) * L_ + gl;
          int bmx = __float_as_int(mx);
          unsigned key = (unsigned)(bmx ^ ((bmx >> 31) | (int)0x80000000));
          atomicMax(&MMAXu[idx], key);
          atomicAdd(&MSUM[idx], sum);
        }
      }
    }
  }
}

// ---------------- top-45 per (b,h): decode m = max - mean, iterative argmax -------
__global__ __launch_bounds__(256) void topk_kernel(const unsigned* __restrict__ MMAXu,
    const float* __restrict__ MSUM, int* __restrict__ topi) {
  __shared__ float vals[L_];
  __shared__ float wv[4];
  __shared__ int wi[4];
  const int bh = blockIdx.x, tid = threadIdx.x;
  for (int i = tid; i < L_; i += 256) {
    unsigned key = MMAXu[(size_t)bh * L_ + i];
    int bits = (key & 0x80000000u) ? (int)(key ^ 0x80000000u) : ~(int)key;
    vals[i] = __int_as_float(bits) - MSUM[(size_t)bh * L_ + i] * (1.0f / SK);
  }
  __syncthreads();
  const int lane = tid & 63, wave = tid >> 6;
  for (int it = 0; it < SK; ++it) {
    float best = -FLT_MAX;
    int bi = 1 << 30;
    for (int i = tid; i < L_; i += 256) {
      float v = vals[i];
      if (v > best || (v == best && i < bi)) { best = v; bi = i; }
    }
    #pragma unroll
    for (int off = 32; off; off >>= 1) {
      float ov = __shfl_down(best, off);
      int oi = __shfl_down(bi, off);
      if (ov > best || (ov == best && oi < bi)) { best = ov; bi = oi; }
    }
    if (lane == 0) { wv[wave] = best; wi[wave] = bi; }
    __syncthreads();
    if (tid == 0) {
      float bb = wv[0]; int bj = wi[0];
      for (int w = 1; w < 4; ++w)
        if (wv[w] > bb || (wv[w] == bb && wi[w] < bj)) { bb = wv[w]; bj = wi[w]; }
      topi[bh * SK + it] = bj;
      vals[bj] = -FLT_MAX;
    }
    __syncthreads();
  }
}

// ---- q_top recompute, ksample-style f32 tiles: QT[bh][48][64] f16 ----------------
__global__ __launch_bounds__(256, 4) void qtop5_kernel(const float* __restrict__ x,
    const float* __restrict__ Wq, const float* __restrict__ bq,
    const int* __restrict__ topi, f16* __restrict__ QT) {
  const int b = blockIdx.x, h = blockIdx.y, sg = blockIdx.z;
  const int bh = b * NH + h;
  __shared__ float xs[5][32];
  __shared__ float wq[64][33];
  __shared__ float red[4][5][64];
  __shared__ int ls[5];
  const int tid = threadIdx.x;
  const int nl = tid & 63, kq = tid >> 6;
  if (tid < 5) ls[tid] = topi[bh * SK + sg * 5 + tid];
  float acc[5] = {0.f, 0.f, 0.f, 0.f, 0.f};
  const int wrow = tid >> 2, wqc = tid & 3;
  for (int kt = 0; kt < 32; ++kt) {
    const int d0 = kt * 32;
    __syncthreads();
    if (tid < 40) {
      int s = tid >> 3, q = tid & 7;
      *(f32x4*)&xs[s][q * 4] = *(const f32x4*)&x[((size_t)b * L_ + ls[s]) * DM + d0 + q * 4];
    }
    {
      const float* src = &Wq[(size_t)(h * 64 + wrow) * DM + d0 + wqc * 8];
      *(f32x4*)&wq[wrow][wqc * 8]     = *(const f32x4*)src;
      *(f32x4*)&wq[wrow][wqc * 8 + 4] = *(const f32x4*)(src + 4);
    }
    __syncthreads();
    #pragma unroll
    for (int i = 0; i < 2; ++i) {
      f32x4 w = *(const f32x4*)&wq[nl][kq * 8 + i * 4];
      #pragma unroll
      for (int s = 0; s < 5; ++s) {
        f32x4 xv = *(const f32x4*)&xs[s][kq * 8 + i * 4];
        acc[s] += xv[0] * w[0] + xv[1] * w[1] + xv[2] * w[2] + xv[3] * w[3];
      }
    }
  }
  #pragma unroll
  for (int s = 0; s < 5; ++s) red[kq][s][nl] = acc[s];
  __syncthreads();
  for (int t = tid; t < 5 * 64; t += 256) {
    int s = t >> 6, j = t & 63;
    QT[bh * 3072 + (sg * 5 + s) * 64 + j] =
        (f16)(red[0][s][j] + red[1][s][j] + red[2][s][j] + red[3][s][j] + bq[h * 64 + j]);
  }
}

// ---- fused K+V GEMM + scores + inline-exp PV: atomics into OT, Zb. No S/V in HBM.
__global__ __launch_bounds__(256, 2) void kscore_kernel(const f16* __restrict__ XH,
    const f16* __restrict__ WKH, const f16* __restrict__ WVH,
    const float* __restrict__ bk, const float* __restrict__ bvec,
    const f16* __restrict__ QT, float* __restrict__ OT, float* __restrict__ Zb) {
  __shared__ __align__(16) char smem[68352];
  f16* qs = (f16*)smem;                  // phase1-2: 48*72*2 = 6912
  f16* xh = (f16*)(smem + 6912);         // phase1:   16384
  f16* wh = (f16*)(smem + 23296);        // phase1:   8192
  f16* Kt = (f16*)(smem + 31488);        // phase2:   256*72*2 = 36864
  f16* Ps = (f16*)smem;                  // phase3-4: 48*264*2 = 25344 (over qs/xh)
  f16* Vt = (f16*)(smem + 31488);        // phase3-4: 64*264*2 = 33792 (over Kt)
  float* red = (float*)smem;             // phase5:   4*48*64*4 = 49152
  const int g = blockIdx.y * 128 + blockIdx.x;  // XCD = g & 7
  const int b = g & 7;
  const int p = g >> 3;
  const int jc = p >> 4;
  const int h = p & 15;
  const int bh = b * 16 + h;
  const int tid = threadIdx.x;
  const int lane = tid & 63, wave = tid >> 6;
  const int frow = lane & 15;
  const int fk = (lane >> 4) * 8;

  for (int i = tid; i < 48 * 64; i += 256)
    qs[(i >> 6) * 72 + (i & 63)] = QT[bh * 3072 + i];

  f32x4 accK[4][4], accV[4][4];
  #pragma unroll
  for (int i = 0; i < 4; ++i)
    #pragma unroll
    for (int j = 0; j < 4; ++j)
      #pragma unroll
      for (int z = 0; z < 4; ++z) { accK[i][j][z] = 0.f; accV[i][j][z] = 0.f; }

  const int r2 = tid >> 2, cb = (tid & 3) * 8;
  const int cbs = cb ^ (((r2 >> 1) & 3) << 3);
  for (int kt = 0; kt < 32; ++kt) {
    #pragma unroll
    for (int i = 0; i < 4; ++i)
      gload_lds16(XH + (size_t)(b * L_ + jc * 256 + i * 64 + r2) * DM + kt * 32 + cbs,
                  xh + (i * 64 + r2) * 32 + cb);
    gload_lds16(WKH + (size_t)(h * 64 + r2) * DM + kt * 32 + cbs, wh + r2 * 32 + cb);
    gload_lds16(WVH + (size_t)(h * 64 + r2) * DM + kt * 32 + cbs, wh + (r2 + 64) * 32 + cb);
    __syncthreads();
    f16x8 am[4], bnK[4], bnV[4];
    #pragma unroll
    for (int mi = 0; mi < 4; ++mi)
      am[mi] = *(const f16x8*)(xh + swz(wave * 64 + mi * 16 + frow, fk));
    #pragma unroll
    for (int ni = 0; ni < 4; ++ni) {
      bnK[ni] = *(const f16x8*)(wh + swz(ni * 16 + frow, fk));
      bnV[ni] = *(const f16x8*)(wh + swz(64 + ni * 16 + frow, fk));
    }
    #pragma unroll
    for (int mi = 0; mi < 4; ++mi)
      #pragma unroll
      for (int ni = 0; ni < 4; ++ni) {
        accK[mi][ni] = __builtin_amdgcn_mfma_f32_16x16x32_f16(am[mi], bnK[ni], accK[mi][ni], 0, 0, 0);
        accV[mi][ni] = __builtin_amdgcn_mfma_f32_16x16x32_f16(am[mi], bnV[ni], accV[mi][ni], 0, 0, 0);
      }
    __syncthreads();
  }

  #pragma unroll
  for (int mi = 0; mi < 4; ++mi) {
    int jl = wave * 64 + mi * 16 + (lane >> 4) * 4;
    #pragma unroll
    for (int ni = 0; ni < 4; ++ni) {
      int d = ni * 16 + (lane & 15);
      float bc = bk[h * 64 + d];
      #pragma unroll
      for (int z = 0; z < 4; ++z)
        Kt[(jl + z) * 72 + d] = (f16)(accK[mi][ni][z] + bc);
    }
  }
  __syncthreads();

  f32x4 accS[3][4];
  #pragma unroll
  for (int i = 0; i < 3; ++i)
    #pragma unroll
    for (int j = 0; j < 4; ++j)
      #pragma unroll
      for (int z = 0; z < 4; ++z) accS[i][j][z] = 0.f;
  #pragma unroll
  for (int ks = 0; ks < 2; ++ks) {
    f16x8 aq[3], bv[4];
    #pragma unroll
    for (int mu = 0; mu < 3; ++mu)
      aq[mu] = *(const f16x8*)(qs + (mu * 16 + frow) * 72 + ks * 32 + fk);
    #pragma unroll
    for (int nj = 0; nj < 4; ++nj)
      bv[nj] = *(const f16x8*)(Kt + (wave * 64 + nj * 16 + frow) * 72 + ks * 32 + fk);
    #pragma unroll
    for (int mu = 0; mu < 3; ++mu)
      #pragma unroll
      for (int nj = 0; nj < 4; ++nj)
        accS[mu][nj] = __builtin_amdgcn_mfma_f32_16x16x32_f16(aq[mu], bv[nj], accS[mu][nj], 0, 0, 0);
  }
  __syncthreads();   // qs/Kt reads done; Ps/Vt (aliased) writes are now safe

  #pragma unroll
  for (int mi = 0; mi < 4; ++mi) {
    int jl = wave * 64 + mi * 16 + (lane >> 4) * 4;
    #pragma unroll
    for (int ni = 0; ni < 4; ++ni) {
      int d = ni * 16 + (lane & 15);
      float bc = bvec[h * 64 + d];
      #pragma unroll
      for (int z = 0; z < 4; ++z)
        Vt[d * 264 + jl + z] = (f16)(accV[mi][ni][z] + bc);
    }
  }
  {
    float zs[3][4];
    #pragma unroll
    for (int mu = 0; mu < 3; ++mu)
      #pragma unroll
      for (int z = 0; z < 4; ++z) zs[mu][z] = 0.f;
    #pragma unroll
    for (int mu = 0; mu < 3; ++mu)
      #pragma unroll
      for (int nj = 0; nj < 4; ++nj) {
        int j = wave * 64 + nj * 16 + (lane & 15);
        #pragma unroll
        for (int z = 0; z < 4; ++z) {
          int u = mu * 16 + (lane >> 4) * 4 + z;
          float pv = __expf(accS[mu][nj][z] * 0.125f);
          Ps[u * 264 + j] = (f16)pv;
          zs[mu][z] += pv;
        }
      }
    #pragma unroll
    for (int mu = 0; mu < 3; ++mu)
      #pragma unroll
      for (int z = 0; z < 4; ++z) {
        float v = zs[mu][z];
        v += __shfl_xor(v, 1);
        v += __shfl_xor(v, 2);
        v += __shfl_xor(v, 4);
        v += __shfl_xor(v, 8);
        int u = mu * 16 + (lane >> 4) * 4 + z;
        if ((lane & 15) == 0 && u < SK) atomicAdd(&Zb[bh * 48 + u], v);
      }
  }
  __syncthreads();

  f32x4 accO[3][4];
  #pragma unroll
  for (int i = 0; i < 3; ++i)
    #pragma unroll
    for (int j = 0; j < 4; ++j)
      #pragma unroll
      for (int z = 0; z < 4; ++z) accO[i][j][z] = 0.f;
  #pragma unroll
  for (int ks = 0; ks < 2; ++ks) {
    f16x8 ap[3], bvv[4];
    #pragma unroll
    for (int mu = 0; mu < 3; ++mu)
      ap[mu] = *(const f16x8*)(Ps + (mu * 16 + frow) * 264 + wave * 64 + ks * 32 + fk);
    #pragma unroll
    for (int nd = 0; nd < 4; ++nd)
      bvv[nd] = *(const f16x8*)(Vt + (nd * 16 + frow) * 264 + wave * 64 + ks * 32 + fk);
    #pragma unroll
    for (int mu = 0; mu < 3; ++mu)
      #pragma unroll
      for (int nd = 0; nd < 4; ++nd)
        accO[mu][nd] = __builtin_amdgcn_mfma_f32_16x16x32_f16(ap[mu], bvv[nd], accO[mu][nd], 0, 0, 0);
  }
  __syncthreads();   // Ps/Vt reads done; red (aliased) writes safe

  #pragma unroll
  for (int mu = 0; mu < 3; ++mu) {
    #pragma unroll
    for (int nd = 0; nd < 4; ++nd) {
      int d = nd * 16 + (lane & 15);
      #pragma unroll
      for (int z = 0; z < 4; ++z) {
        int u = mu * 16 + (lane >> 4) * 4 + z;
        red[wave * 3072 + u * 64 + d] = accO[mu][nd][z];
      }
    }
  }
  __syncthreads();
  for (int i = tid; i < 3072; i += 256) {
    int u = i >> 6;
    if (u < SK)
      atomicAdd(&OT[((size_t)bh * SK + u) * DH + (i & 63)],
                red[i] + red[3072 + i] + red[6144 + i] + red[9216 + i]);
  }
}

// ---------------- out = broadcast(base) ----------------
__global__ __launch_bounds__(256) void basewrite_kernel(const float* __restrict__ base,
                                                        float* __restrict__ out) {
  size_t i = (size_t)blockIdx.x * 256 + threadIdx.x;
  const size_t stride = (size_t)gridDim.x * 256;
  const size_t total = (size_t)B_ * L_ * (DM / 4);
  for (; i < total; i += stride) {
    size_t b = i >> 20;
    size_t c = i & 255;
    ((f32x4*)out)[i] = ((const f32x4*)base)[b * 256 + c];
  }
}

// ---------------- corrections: out[b, top_u, n] += (OT/Z - MV) . Wo[n, h*64:] -----
__global__ __launch_bounds__(256, 2) void corr_kernel(const float* __restrict__ OT,
    const float* __restrict__ Zb, const float* __restrict__ MV,
    const float* __restrict__ Wo, const int* __restrict__ topi,
    float* __restrict__ out) {
  __shared__ float dv[SK][64];
  __shared__ float wo[64][65];
  __shared__ float invz[SK];
  __shared__ int lidx[SK];
  const int bh = blockIdx.x, q = blockIdx.y, tid = threadIdx.x;
  const int b = bh >> 4, h = bh & 15;
  if (tid < SK) {
    invz[tid] = 1.0f / Zb[bh * 48 + tid];
    lidx[tid] = topi[bh * SK + tid];
  }
  __syncthreads();
  for (int i = tid; i < SK * 64; i += 256) {
    int u = i >> 6, d = i & 63;
    dv[u][d] = OT[((size_t)bh * SK + u) * DH + d] * invz[u] - MV[b * DM + h * DH + d];
  }
  const int nn = tid & 63, ug = tid >> 6;
  for (int c = 0; c < 4; ++c) {
    const int n0 = q * 256 + c * 64;
    __syncthreads();
    for (int t = tid; t < 1024; t += 256) {
      int row = t >> 4, vc = t & 15;
      f32x4 v = *(const f32x4*)&Wo[(size_t)(n0 + row) * DM + h * DH + vc * 4];
      *(f32x4*)&wo[row][vc * 4] = v;
    }
    __syncthreads();
    #pragma unroll
    for (int i = 0; i < 12; ++i) {
      int u = ug + i * 4;
      if (u >= SK) break;
      float a0 = 0, a1 = 0, a2 = 0, a3 = 0;
      #pragma unroll
      for (int d4 = 0; d4 < 16; ++d4) {
        f32x4 w = *(const f32x4*)&wo[nn][d4 * 4];
        f32x4 dd = *(const f32x4*)&dv[u][d4 * 4];
        a0 += dd[0] * w[0]; a1 += dd[1] * w[1];
        a2 += dd[2] * w[2]; a3 += dd[3] * w[3];
      }
      atomicAdd(&out[((size_t)b * L_ + lidx[u]) * DM + n0 + nn], (a0 + a1) + (a2 + a3));
    }
  }
}

// ---------------- workspace layout (zero-init region contiguous) ------------------
static const size_t OFF_XH   = 0;                        // 67108864
static const size_t OFF_WQH  = OFF_XH + 67108864;        // 2097152
static const size_t OFF_WQL  = OFF_WQH + 2097152;
static const size_t OFF_WKH  = OFF_WQL + 2097152;
static const size_t OFF_WVH  = OFF_WKH + 2097152;
static const size_t OFF_KS   = OFF_WVH + 2097152;        // 1474560
static const size_t OFF_MV   = OFF_KS + 1474560;         // 32768
static const size_t OFF_BASE = OFF_MV + 32768;           // 32768
static const size_t OFF_TOPI = OFF_BASE + 32768;         // 23040 -> pad 24576
// zero-init block:
static const size_t OFF_MEANX= OFF_TOPI + 24576;         // 32768
static const size_t OFF_ZB   = OFF_MEANX + 32768;        // 24576
static const size_t OFF_QT   = OFF_ZB + 24576;           // 786432
static const size_t OFF_MMAX = OFF_QT + 786432;          // 2097152
static const size_t OFF_MSUM = OFF_MMAX + 2097152;       // 2097152
static const size_t OFF_OT   = OFF_MSUM + 2097152;       // 1474560
static const size_t ZERO_SZ  = OFF_OT + 1474560 - OFF_MEANX;   // 6512640
// end zero block:
static const size_t OFF_PH   = OFF_OT + 1474560;         // 12582912
static const size_t OFF_PL   = OFF_PH + 12582912;        // 12582912
static const size_t WS_NEED  = OFF_PL + 12582912;        // ~108.7 MB

extern "C" void kernel_launch(void* const* d_in, const int* in_sizes, int n_in,
                              void* d_out, int out_size, void* d_ws, size_t ws_size,
                              hipStream_t stream) {
  const float* x  = (const float*)d_in[0];
  const float* Wq = (const float*)d_in[1];
  const float* bq = (const float*)d_in[2];
  const float* Wk = (const float*)d_in[3];
  const float* bk = (const float*)d_in[4];
  const float* Wv = (const float*)d_in[5];
  const float* bv = (const float*)d_in[6];
  const float* Wo = (const float*)d_in[7];
  const float* bo = (const float*)d_in[8];
  const int* sidx = (const int*)d_in[9];
  float* out = (float*)d_out;
  char* ws = (char*)d_ws;

  if (ws_size < WS_NEED) {
    if (ws_size < 131072) return;
    float* MEANX = (float*)(ws + 0);
    float* MV    = (float*)(ws + 32768);
    float* BASE  = (float*)(ws + 65536);
    hipMemsetAsync(MEANX, 0, 32768, stream);
    meansum32_kernel<<<dim3(B_, 4, 16), 256, 0, stream>>>(x, MEANX);
    proj_vec_kernel<<<32, 256, 0, stream>>>(MEANX, Wv, bv, MV, 1.0f / L_);
    proj_vec_kernel<<<32, 256, 0, stream>>>(MV, Wo, bo, BASE, 1.0f);
    basewrite_kernel<<<2048, 256, 0, stream>>>(BASE, out);
    return;
  }

  f16*   XH   = (f16*)(ws + OFF_XH);
  f16*   WQH  = (f16*)(ws + OFF_WQH);
  f16*   WQL  = (f16*)(ws + OFF_WQL);
  f16*   WKH  = (f16*)(ws + OFF_WKH);
  f16*   WVH  = (f16*)(ws + OFF_WVH);
  float* KS   = (float*)(ws + OFF_KS);
  float* MV   = (float*)(ws + OFF_MV);
  float* BASE = (float*)(ws + OFF_BASE);
  int*   TOPI = (int*)(ws + OFF_TOPI);
  float* MEANX= (float*)(ws + OFF_MEANX);
  float* ZB   = (float*)(ws + OFF_ZB);
  f16*   QT   = (f16*)(ws + OFF_QT);
  unsigned* MMAXu = (unsigned*)(ws + OFF_MMAX);
  float* MSUM = (float*)(ws + OFF_MSUM);
  float* OT   = (float*)(ws + OFF_OT);
  f16*   PH   = (f16*)(ws + OFF_PH);
  f16*   PL   = (f16*)(ws + OFF_PL);
  f16*   XL   = (f16*)out;   // x lo-part scratch in d_out (67 MB; dead by basewrite)

  // 1. conversions / splits / single zero-init
  xsplit2_kernel<<<2048, 256, 0, stream>>>(x, XH, XL, (int)((size_t)B_ * L_ * DM / 4));
  wsplit3_kernel<<<dim3(256, 3), 256, 0, stream>>>(Wq, Wk, Wv, WQH, WQL, WKH, WVH,
                                                   DM * DM / 4);
  hipMemsetAsync(ws + OFF_MEANX, 0, ZERO_SZ, stream);

  // 2. mean path (reads XH f16)
  meansum_kernel<<<dim3(B_, 4, 16), 256, 0, stream>>>(XH, MEANX);
  proj_vec_kernel<<<32, 256, 0, stream>>>(MEANX, Wv, bv, MV, 1.0f / L_);
  proj_vec_kernel<<<32, 256, 0, stream>>>(MV, Wo, bo, BASE, 1.0f);

  // 3. sampled K rows -> P(scaled) -> scores GEMM (all-gload_lds) + m-statistics
  ksample_kernel<<<dim3(B_, 16, 9), 256, 0, stream>>>(x, Wk, bk, sidx, KS);
  pcomp_kernel<<<dim3(B_, NH, 16), 256, 0, stream>>>(Wq, KS, PH, PL);
  gemm_sc<<<dim3(8, 192), 256, 0, stream>>>(XH, XL, PH, PL, MMAXu, MSUM);

  // 4. top-k (decodes m) + q_top recompute
  topk_kernel<<<B_ * NH, 256, 0, stream>>>(MMAXu, MSUM, TOPI);
  qtop5_kernel<<<dim3(B_, NH, 9), 256, 0, stream>>>(x, Wq, bq, TOPI, QT);

  // 5. fully fused K+V GEMM + scores + exp-PV
  kscore_kernel<<<dim3(128, 16), 256, 0, stream>>>(XH, WKH, WVH, bk, bv, QT, OT, ZB);

  // 6. output assembly (overwrites XL scratch)
  basewrite_kernel<<<2048, 256, 0, stream>>>(BASE, out);
  corr_kernel<<<dim3(B_ * NH, 4), 256, 0, stream>>>(OT, ZB, MV, Wo, TOPI, out);
}

// Round 16
// 710.156 us; speedup vs baseline: 1.3989x; 1.0768x over previous
//
#include <hip/hip_runtime.h>
#include <cfloat>
#include <cstdint>

#define B_  8
#define L_  4096
#define DM  1024
#define NH  16
#define DH  64
#define SK  45

typedef __attribute__((ext_vector_type(4))) float f32x4;
typedef _Float16 f16;
typedef __attribute__((ext_vector_type(4))) _Float16 f16x4;
typedef __attribute__((ext_vector_type(8))) _Float16 f16x8;

__device__ __forceinline__ void gload_lds16(const void* g, void* l) {
  __builtin_amdgcn_global_load_lds(
      (const __attribute__((address_space(1))) unsigned int*)g,
      (__attribute__((address_space(3))) unsigned int*)l, 16, 0, 0);
}

// XOR-swizzled f16 index into a [rows][32] f16 tile (64B rows), granule 8 f16.
__device__ __forceinline__ int swz(int row, int c) {
  return row * 32 + (c ^ (((row >> 1) & 3) << 3));
}

// ---- x f32 -> f16 hi (ws) + f16 lo*2048 (d_out scratch) + fused column mean -----
// grid 1024: block owns 32 consecutive rows (never crosses batch boundary).
__global__ __launch_bounds__(256) void xsplitmean_kernel(const float* __restrict__ x,
    f16* __restrict__ xh, f16* __restrict__ xl, float* __restrict__ meanx) {
  const int r0 = blockIdx.x * 32;
  const int b = r0 >> 12;
  const int d0 = threadIdx.x * 4;
  float s0 = 0.f, s1 = 0.f, s2 = 0.f, s3 = 0.f;
  for (int i = 0; i < 32; ++i) {
    const size_t off = (size_t)(r0 + i) * DM + d0;
    f32x4 v = *(const f32x4*)(x + off);
    f16x4 h, l;
    #pragma unroll
    for (int j = 0; j < 4; ++j) {
      h[j] = (f16)v[j];
      l[j] = (f16)((v[j] - (float)h[j]) * 2048.0f);
    }
    *(f16x4*)(xh + off) = h;
    *(f16x4*)(xl + off) = l;
    s0 += v[0]; s1 += v[1]; s2 += v[2]; s3 += v[3];
  }
  atomicAdd(&meanx[b * DM + d0 + 0], s0);
  atomicAdd(&meanx[b * DM + d0 + 1], s1);
  atomicAdd(&meanx[b * DM + d0 + 2], s2);
  atomicAdd(&meanx[b * DM + d0 + 3], s3);
}

// ---------------- all three W f32 -> f16 (Wq also lo) in one launch --------------
__global__ __launch_bounds__(256) void wsplit3_kernel(const float* __restrict__ Wq,
    const float* __restrict__ Wk, const float* __restrict__ Wv,
    f16* __restrict__ WQH, f16* __restrict__ WQL,
    f16* __restrict__ WKH, f16* __restrict__ WVH, int n4) {
  const int which = blockIdx.y;
  const float* w = (which == 0) ? Wq : ((which == 1) ? Wk : Wv);
  f16* wh = (which == 0) ? WQH : ((which == 1) ? WKH : WVH);
  const int withlo = (which == 0);
  int i = blockIdx.x * 256 + threadIdx.x;
  int stride = gridDim.x * 256;
  for (; i < n4; i += stride) {
    f32x4 v = ((const f32x4*)w)[i];
    f16x4 h, l;
    #pragma unroll
    for (int j = 0; j < 4; ++j) {
      h[j] = (f16)v[j];
      l[j] = (f16)((v[j] - (float)h[j]) * 2048.0f);
    }
    ((f16x4*)wh)[i] = h;
    if (withlo) ((f16x4*)WQL)[i] = l;
  }
}

// f32 mean fallback (small-ws diagnostic path)
__global__ __launch_bounds__(256) void meansum32_kernel(const float* __restrict__ x,
                                                        float* __restrict__ meanx) {
  int b = blockIdx.x;
  int d = blockIdx.y * 256 + threadIdx.x;
  int l0 = blockIdx.z * 256;
  const float* p = x + ((size_t)b * L_ + l0) * DM + d;
  float s = 0.f;
  for (int i = 0; i < 256; ++i) s += p[(size_t)i * DM];
  atomicAdd(&meanx[b * DM + d], s);
}

// vout(b,n) = (vin(b,:) . W[n,:]) * scale + bias[n]
__global__ __launch_bounds__(256) void proj_vec_kernel(const float* __restrict__ vin,
    const float* __restrict__ W, const float* __restrict__ bias,
    float* __restrict__ vout, float scale) {
  int g = blockIdx.x * 256 + threadIdx.x;
  int b = g >> 10, n = g & 1023;
  const float* xr = vin + b * DM;
  const float* wr = W + (size_t)n * DM;
  float a0 = 0, a1 = 0, a2 = 0, a3 = 0;
  for (int d = 0; d < DM; d += 4) {
    a0 += xr[d + 0] * wr[d + 0];
    a1 += xr[d + 1] * wr[d + 1];
    a2 += xr[d + 2] * wr[d + 2];
    a3 += xr[d + 3] * wr[d + 3];
  }
  vout[g] = ((a0 + a1) + (a2 + a3)) * scale + bias[n];
}

// ---------------- k_sample rows, f32 LDS-tiled: KS[b][s][n] ----------------
__global__ __launch_bounds__(256, 4) void ksample_kernel(const float* __restrict__ x,
    const float* __restrict__ Wk, const float* __restrict__ bk,
    const int* __restrict__ sidx, float* __restrict__ KS) {
  const int b = blockIdx.x, nc = blockIdx.y, sg = blockIdx.z;
  __shared__ float xs[5][32];
  __shared__ float wk[64][33];
  __shared__ float red[4][5][64];
  __shared__ int ls[5];
  const int tid = threadIdx.x;
  const int nl = tid & 63, kq = tid >> 6;
  if (tid < 5) ls[tid] = sidx[sg * 5 + tid];
  float acc[5] = {0.f, 0.f, 0.f, 0.f, 0.f};
  const int wrow = tid >> 2, wq = tid & 3;
  for (int kt = 0; kt < 32; ++kt) {
    const int d0 = kt * 32;
    __syncthreads();
    if (tid < 40) {
      int s = tid >> 3, q = tid & 7;
      *(f32x4*)&xs[s][q * 4] = *(const f32x4*)&x[((size_t)b * L_ + ls[s]) * DM + d0 + q * 4];
    }
    {
      const float* src = &Wk[(size_t)(nc * 64 + wrow) * DM + d0 + wq * 8];
      *(f32x4*)&wk[wrow][wq * 8]     = *(const f32x4*)src;
      *(f32x4*)&wk[wrow][wq * 8 + 4] = *(const f32x4*)(src + 4);
    }
    __syncthreads();
    #pragma unroll
    for (int i = 0; i < 2; ++i) {
      f32x4 w = *(const f32x4*)&wk[nl][kq * 8 + i * 4];
      #pragma unroll
      for (int s = 0; s < 5; ++s) {
        f32x4 xv = *(const f32x4*)&xs[s][kq * 8 + i * 4];
        acc[s] += xv[0] * w[0] + xv[1] * w[1] + xv[2] * w[2] + xv[3] * w[3];
      }
    }
  }
  #pragma unroll
  for (int s = 0; s < 5; ++s) red[kq][s][nl] = acc[s];
  __syncthreads();
  for (int t = tid; t < 5 * 64; t += 256) {
    int s = t >> 6, j = t & 63;
    int nj = nc * 64 + j;
    KS[((size_t)b * SK + sg * 5 + s) * DM + nj] =
        red[0][s][j] + red[1][s][j] + red[2][s][j] + red[3][s][j] + bk[nj];
  }
}

// ---- P[b][h*48+s][nc*64+c] = 0.125 * sum_d Wq[h*64+d][c'] * KS[b][s][h*64+d] -----
__global__ __launch_bounds__(256, 4) void pcomp_kernel(const float* __restrict__ Wq,
    const float* __restrict__ KS, f16* __restrict__ PH, f16* __restrict__ PL) {
  const int b = blockIdx.x, h = blockIdx.y, nc = blockIdx.z;
  __shared__ float ks[45][64];
  __shared__ float wqT[64][68];
  const int tid = threadIdx.x;
  const int n0 = nc * 64;
  for (int i = tid; i < 45 * 64; i += 256) {
    int s = i >> 6, d = i & 63;
    ks[s][d] = KS[((size_t)b * SK + s) * DM + h * 64 + d];
  }
  for (int t = tid; t < 1024; t += 256) {
    int row = t >> 4, cg = t & 15;
    f32x4 v = *(const f32x4*)&Wq[(size_t)(h * 64 + row) * DM + n0 + cg * 4];
    #pragma unroll
    for (int j = 0; j < 4; ++j) wqT[cg * 4 + j][row] = v[j];
  }
  __syncthreads();
  for (int t = tid; t < 48 * 64; t += 256) {
    int s = t >> 6, c = t & 63;
    float acc = 0.f;
    if (s < SK) {
      const f32x4* wr = (const f32x4*)&wqT[c][0];
      const f32x4* kr = (const f32x4*)&ks[s][0];
      float a0 = 0, a1 = 0, a2 = 0, a3 = 0;
      #pragma unroll
      for (int i = 0; i < 16; ++i) {
        f32x4 wv = wr[i], kv = kr[i];
        a0 += wv[0] * kv[0]; a1 += wv[1] * kv[1];
        a2 += wv[2] * kv[2]; a3 += wv[3] * kv[3];
      }
      acc = ((a0 + a1) + (a2 + a3)) * 0.125f;
    }
    f16 hv = (f16)acc;
    size_t off = ((size_t)b * 768 + h * 48 + s) * DM + n0 + c;
    PH[off] = hv;
    PL[off] = (f16)((acc - (float)hv) * 2048.0f);
  }
}

// ---- scores GEMM + fused m-statistics; A staged via global_load_lds from XH/XL ---
__global__ __launch_bounds__(256, 2) void gemm_sc(const f16* __restrict__ XH,
    const f16* __restrict__ XL, const f16* __restrict__ PH,
    const f16* __restrict__ PL, unsigned* __restrict__ MMAXu,
    float* __restrict__ MSUM) {
  __shared__ __align__(16) char pool[33792];
  f16* xh = (f16*)pool;                 // phase A: 8192
  f16* xl = (f16*)(pool + 8192);
  f16* wh = (f16*)(pool + 16384);
  f16* wl = (f16*)(pool + 24576);       // ends 32768
  float* scf = (float*)pool;            // phase B: [64][132] f32 = 33792
  const int tid = threadIdx.x;
  const int g = blockIdx.y * 8 + blockIdx.x;    // XCD = g & 7
  const int q = g >> 3;                          // 0..191
  const int nt = q % 6;                          // N-tile cycles fastest
  const int mt = (g & 7) + (q / 6) * 8;          // A-panel pinned to XCD
  const int n0 = nt * 128;
  const int m0 = mt * 128;
  const int bb = mt >> 5;                        // batch of this M-tile
  const int lane = tid & 63;
  const int wave = tid >> 6;
  const int wr = (wave >> 1) * 64;
  const int wc = (wave & 1) * 64;
  const int frow = lane & 15;
  const int fk = (lane >> 4) * 8;

  f32x4 aH[4][4], aL[4][4];
  #pragma unroll
  for (int i = 0; i < 4; ++i)
    #pragma unroll
    for (int j = 0; j < 4; ++j)
      #pragma unroll
      for (int z = 0; z < 4; ++z) { aH[i][j][z] = 0.f; aL[i][j][z] = 0.f; }

  const int r2 = tid >> 2;
  const int cb = (tid & 3) * 8;
  const int cbs = cb ^ (((r2 >> 1) & 3) << 3);   // pre-swizzled source col

  const size_t pbase = (size_t)bb * 768;
  for (int kt = 0; kt < 32; ++kt) {
    const int kcol = kt * 32;
    gload_lds16(XH + (size_t)(m0 + r2) * DM + kcol + cbs,      xh + r2 * 32 + cb);
    gload_lds16(XH + (size_t)(m0 + r2 + 64) * DM + kcol + cbs, xh + (r2 + 64) * 32 + cb);
    gload_lds16(XL + (size_t)(m0 + r2) * DM + kcol + cbs,      xl + r2 * 32 + cb);
    gload_lds16(XL + (size_t)(m0 + r2 + 64) * DM + kcol + cbs, xl + (r2 + 64) * 32 + cb);
    gload_lds16(PH + (pbase + n0 + r2) * DM + kcol + cbs,      wh + r2 * 32 + cb);
    gload_lds16(PH + (pbase + n0 + r2 + 64) * DM + kcol + cbs, wh + (r2 + 64) * 32 + cb);
    gload_lds16(PL + (pbase + n0 + r2) * DM + kcol + cbs,      wl + r2 * 32 + cb);
    gload_lds16(PL + (pbase + n0 + r2 + 64) * DM + kcol + cbs, wl + (r2 + 64) * 32 + cb);
    __syncthreads();
    f16x8 ah[4], al[4], bh[4], bl[4];
    #pragma unroll
    for (int mi = 0; mi < 4; ++mi) {
      ah[mi] = *(const f16x8*)(xh + swz(wr + mi * 16 + frow, fk));
      al[mi] = *(const f16x8*)(xl + swz(wr + mi * 16 + frow, fk));
    }
    #pragma unroll
    for (int ni = 0; ni < 4; ++ni) {
      bh[ni] = *(const f16x8*)(wh + swz(wc + ni * 16 + frow, fk));
      bl[ni] = *(const f16x8*)(wl + swz(wc + ni * 16 + frow, fk));
    }
    #pragma unroll
    for (int mi = 0; mi < 4; ++mi)
      #pragma unroll
      for (int ni = 0; ni < 4; ++ni) {
        aH[mi][ni] = __builtin_amdgcn_mfma_f32_16x16x32_f16(ah[mi], bh[ni], aH[mi][ni], 0, 0, 0);
        aL[mi][ni] = __builtin_amdgcn_mfma_f32_16x16x32_f16(ah[mi], bl[ni], aL[mi][ni], 0, 0, 0);
        aL[mi][ni] = __builtin_amdgcn_mfma_f32_16x16x32_f16(al[mi], bh[ni], aL[mi][ni], 0, 0, 0);
      }
    __syncthreads();
  }

  // fused epilogue: two 64-row halves through aliased LDS -> per-(row,h) partials
  const int hbase = n0 / 48;
  #pragma unroll
  for (int half = 0; half < 2; ++half) {
    __syncthreads();
    if ((wave >> 1) == half) {
      #pragma unroll
      for (int mi = 0; mi < 4; ++mi)
        #pragma unroll
        for (int ni = 0; ni < 4; ++ni) {
          int coll = wc + ni * 16 + (lane & 15);
          #pragma unroll
          for (int j = 0; j < 4; ++j) {
            int rowl = mi * 16 + (lane >> 4) * 4 + j;
            scf[rowl * 132 + coll] = aH[mi][ni][j] + aL[mi][ni][j] * (1.0f / 2048.0f);
          }
        }
    }
    __syncthreads();
    {
      int row = tid >> 2, gidx = tid & 3;
      int h = hbase + gidx;
      if (h < NH) {
        int slo = n0 - h * 48; if (slo < 0) slo = 0;
        int shi = n0 + 128 - h * 48; if (shi > SK) shi = SK;
        if (slo < shi) {
          float mx = -FLT_MAX, sum = 0.f;
          const float* pr = scf + row * 132 + (h * 48 - n0);
          for (int s = slo; s < shi; ++s) {
            float v = pr[s];
            mx = fmaxf(mx, v);
            sum += v;
          }
          int gl = (m0 & 4095) + half * 64 + row;
          size_t idx = ((size_t)(bb * NH + h)) * L_ + gl;
          int bmx = __float_as_int(mx);
          unsigned key = (unsigned)(bmx ^ ((bmx >> 31) | (int)0x80000000));
          atomicMax(&MMAXu[idx], key);
          atomicAdd(&MSUM[idx], sum);
        }
      }
    }
  }
}

// ---------------- top-45: decode m, packed 64-bit-key iterative argmax ------------
__global__ __launch_bounds__(256) void topk_kernel(const unsigned* __restrict__ MMAXu,
    const float* __restrict__ MSUM, int* __restrict__ topi) {
  __shared__ float vals[L_];
  __shared__ unsigned long long wk[4];
  const int bh = blockIdx.x, tid = threadIdx.x;
  for (int i = tid; i < L_; i += 256) {
    unsigned key = MMAXu[(size_t)bh * L_ + i];
    int bits = (key & 0x80000000u) ? (int)(key ^ 0x80000000u) : ~(int)key;
    vals[i] = __int_as_float(bits) - MSUM[(size_t)bh * L_ + i] * (1.0f / SK);
  }
  __syncthreads();
  const int lane = tid & 63, wave = tid >> 6;
  for (int it = 0; it < SK; ++it) {
    unsigned long long best = 0ull;
    for (int i = tid; i < L_; i += 256) {
      int b = __float_as_int(vals[i]);
      unsigned e = (unsigned)(b ^ ((b >> 31) | (int)0x80000000));
      unsigned long long key =
          ((unsigned long long)e << 32) | (unsigned)(0xFFFFFFFFu - i);
      if (key > best) best = key;
    }
    #pragma unroll
    for (int off = 32; off; off >>= 1) {
      unsigned long long o = __shfl_xor(best, off);
      if (o > best) best = o;
    }
    if (lane == 0) wk[wave] = best;
    __syncthreads();
    if (tid == 0) {
      unsigned long long bb = wk[0];
      if (wk[1] > bb) bb = wk[1];
      if (wk[2] > bb) bb = wk[2];
      if (wk[3] > bb) bb = wk[3];
      int bj = (int)(0xFFFFFFFFu - (unsigned)(bb & 0xFFFFFFFFu));
      topi[bh * SK + it] = bj;
      vals[bj] = -FLT_MAX;
    }
    __syncthreads();
  }
}

// ---- q_top recompute, ksample-style f32 tiles: QT[bh][48][64] f16 ----------------
__global__ __launch_bounds__(256, 4) void qtop5_kernel(const float* __restrict__ x,
    const float* __restrict__ Wq, const float* __restrict__ bq,
    const int* __restrict__ topi, f16* __restrict__ QT) {
  const int b = blockIdx.x, h = blockIdx.y, sg = blockIdx.z;
  const int bh = b * NH + h;
  __shared__ float xs[5][32];
  __shared__ float wq[64][33];
  __shared__ float red[4][5][64];
  __shared__ int ls[5];
  const int tid = threadIdx.x;
  const int nl = tid & 63, kq = tid >> 6;
  if (tid < 5) ls[tid] = topi[bh * SK + sg * 5 + tid];
  float acc[5] = {0.f, 0.f, 0.f, 0.f, 0.f};
  const int wrow = tid >> 2, wqc = tid & 3;
  for (int kt = 0; kt < 32; ++kt) {
    const int d0 = kt * 32;
    __syncthreads();
    if (tid < 40) {
      int s = tid >> 3, q = tid & 7;
      *(f32x4*)&xs[s][q * 4] = *(const f32x4*)&x[((size_t)b * L_ + ls[s]) * DM + d0 + q * 4];
    }
    {
      const float* src = &Wq[(size_t)(h * 64 + wrow) * DM + d0 + wqc * 8];
      *(f32x4*)&wq[wrow][wqc * 8]     = *(const f32x4*)src;
      *(f32x4*)&wq[wrow][wqc * 8 + 4] = *(const f32x4*)(src + 4);
    }
    __syncthreads();
    #pragma unroll
    for (int i = 0; i < 2; ++i) {
      f32x4 w = *(const f32x4*)&wq[nl][kq * 8 + i * 4];
      #pragma unroll
      for (int s = 0; s < 5; ++s) {
        f32x4 xv = *(const f32x4*)&xs[s][kq * 8 + i * 4];
        acc[s] += xv[0] * w[0] + xv[1] * w[1] + xv[2] * w[2] + xv[3] * w[3];
      }
    }
  }
  #pragma unroll
  for (int s = 0; s < 5; ++s) red[kq][s][nl] = acc[s];
  __syncthreads();
  for (int t = tid; t < 5 * 64; t += 256) {
    int s = t >> 6, j = t & 63;
    QT[bh * 3072 + (sg * 5 + s) * 64 + j] =
        (f16)(red[0][s][j] + red[1][s][j] + red[2][s][j] + red[3][s][j] + bq[h * 64 + j]);
  }
}

// ---- fused K+V GEMM + scores + inline-exp PV: atomics into OT, Zb. No S/V in HBM.
__global__ __launch_bounds__(256, 2) void kscore_kernel(const f16* __restrict__ XH,
    const f16* __restrict__ WKH, const f16* __restrict__ WVH,
    const float* __restrict__ bk, const float* __restrict__ bvec,
    const f16* __restrict__ QT, float* __restrict__ OT, float* __restrict__ Zb) {
  __shared__ __align__(16) char smem[68352];
  f16* qs = (f16*)smem;                  // phase1-2: 48*72*2 = 6912
  f16* xh = (f16*)(smem + 6912);         // phase1:   16384
  f16* wh = (f16*)(smem + 23296);        // phase1:   8192
  f16* Kt = (f16*)(smem + 31488);        // phase2:   256*72*2 = 36864
  f16* Ps = (f16*)smem;                  // phase3-4: 48*264*2 = 25344 (over qs/xh)
  f16* Vt = (f16*)(smem + 31488);        // phase3-4: 64*264*2 = 33792 (over Kt)
  float* red = (float*)smem;             // phase5:   4*48*64*4 = 49152
  const int g = blockIdx.y * 128 + blockIdx.x;  // XCD = g & 7
  const int b = g & 7;
  const int p = g >> 3;
  const int jc = p >> 4;
  const int h = p & 15;
  const int bh = b * 16 + h;
  const int tid = threadIdx.x;
  const int lane = tid & 63, wave = tid >> 6;
  const int frow = lane & 15;
  const int fk = (lane >> 4) * 8;

  for (int i = tid; i < 48 * 64; i += 256)
    qs[(i >> 6) * 72 + (i & 63)] = QT[bh * 3072 + i];

  f32x4 accK[4][4], accV[4][4];
  #pragma unroll
  for (int i = 0; i < 4; ++i)
    #pragma unroll
    for (int j = 0; j < 4; ++j)
      #pragma unroll
      for (int z = 0; z < 4; ++z) { accK[i][j][z] = 0.f; accV[i][j][z] = 0.f; }

  const int r2 = tid >> 2, cb = (tid & 3) * 8;
  const int cbs = cb ^ (((r2 >> 1) & 3) << 3);
  for (int kt = 0; kt < 32; ++kt) {
    #pragma unroll
    for (int i = 0; i < 4; ++i)
      gload_lds16(XH + (size_t)(b * L_ + jc * 256 + i * 64 + r2) * DM + kt * 32 + cbs,
                  xh + (i * 64 + r2) * 32 + cb);
    gload_lds16(WKH + (size_t)(h * 64 + r2) * DM + kt * 32 + cbs, wh + r2 * 32 + cb);
    gload_lds16(WVH + (size_t)(h * 64 + r2) * DM + kt * 32 + cbs, wh + (r2 + 64) * 32 + cb);
    __syncthreads();
    f16x8 am[4], bnK[4], bnV[4];
    #pragma unroll
    for (int mi = 0; mi < 4; ++mi)
      am[mi] = *(const f16x8*)(xh + swz(wave * 64 + mi * 16 + frow, fk));
    #pragma unroll
    for (int ni = 0; ni < 4; ++ni) {
      bnK[ni] = *(const f16x8*)(wh + swz(ni * 16 + frow, fk));
      bnV[ni] = *(const f16x8*)(wh + swz(64 + ni * 16 + frow, fk));
    }
    #pragma unroll
    for (int mi = 0; mi < 4; ++mi)
      #pragma unroll
      for (int ni = 0; ni < 4; ++ni) {
        accK[mi][ni] = __builtin_amdgcn_mfma_f32_16x16x32_f16(am[mi], bnK[ni], accK[mi][ni], 0, 0, 0);
        accV[mi][ni] = __builtin_amdgcn_mfma_f32_16x16x32_f16(am[mi], bnV[ni], accV[mi][ni], 0, 0, 0);
      }
    __syncthreads();
  }

  #pragma unroll
  for (int mi = 0; mi < 4; ++mi) {
    int jl = wave * 64 + mi * 16 + (lane >> 4) * 4;
    #pragma unroll
    for (int ni = 0; ni < 4; ++ni) {
      int d = ni * 16 + (lane & 15);
      float bc = bk[h * 64 + d];
      #pragma unroll
      for (int z = 0; z < 4; ++z)
        Kt[(jl + z) * 72 + d] = (f16)(accK[mi][ni][z] + bc);
    }
  }
  __syncthreads();

  f32x4 accS[3][4];
  #pragma unroll
  for (int i = 0; i < 3; ++i)
    #pragma unroll
    for (int j = 0; j < 4; ++j)
      #pragma unroll
      for (int z = 0; z < 4; ++z) accS[i][j][z] = 0.f;
  #pragma unroll
  for (int ks = 0; ks < 2; ++ks) {
    f16x8 aq[3], bv[4];
    #pragma unroll
    for (int mu = 0; mu < 3; ++mu)
      aq[mu] = *(const f16x8*)(qs + (mu * 16 + frow) * 72 + ks * 32 + fk);
    #pragma unroll
    for (int nj = 0; nj < 4; ++nj)
      bv[nj] = *(const f16x8*)(Kt + (wave * 64 + nj * 16 + frow) * 72 + ks * 32 + fk);
    #pragma unroll
    for (int mu = 0; mu < 3; ++mu)
      #pragma unroll
      for (int nj = 0; nj < 4; ++nj)
        accS[mu][nj] = __builtin_amdgcn_mfma_f32_16x16x32_f16(aq[mu], bv[nj], accS[mu][nj], 0, 0, 0);
  }
  __syncthreads();   // qs/Kt reads done; Ps/Vt (aliased) writes are now safe

  #pragma unroll
  for (int mi = 0; mi < 4; ++mi) {
    int jl = wave * 64 + mi * 16 + (lane >> 4) * 4;
    #pragma unroll
    for (int ni = 0; ni < 4; ++ni) {
      int d = ni * 16 + (lane & 15);
      float bc = bvec[h * 64 + d];
      #pragma unroll
      for (int z = 0; z < 4; ++z)
        Vt[d * 264 + jl + z] = (f16)(accV[mi][ni][z] + bc);
    }
  }
  {
    float zs[3][4];
    #pragma unroll
    for (int mu = 0; mu < 3; ++mu)
      #pragma unroll
      for (int z = 0; z < 4; ++z) zs[mu][z] = 0.f;
    #pragma unroll
    for (int mu = 0; mu < 3; ++mu)
      #pragma unroll
      for (int nj = 0; nj < 4; ++nj) {
        int j = wave * 64 + nj * 16 + (lane & 15);
        #pragma unroll
        for (int z = 0; z < 4; ++z) {
          int u = mu * 16 + (lane >> 4) * 4 + z;
          float pv = __expf(accS[mu][nj][z] * 0.125f);
          Ps[u * 264 + j] = (f16)pv;
          zs[mu][z] += pv;
        }
      }
    #pragma unroll
    for (int mu = 0; mu < 3; ++mu)
      #pragma unroll
      for (int z = 0; z < 4; ++z) {
        float v = zs[mu][z];
        v += __shfl_xor(v, 1);
        v += __shfl_xor(v, 2);
        v += __shfl_xor(v, 4);
        v += __shfl_xor(v, 8);
        int u = mu * 16 + (lane >> 4) * 4 + z;
        if ((lane & 15) == 0 && u < SK) atomicAdd(&Zb[bh * 48 + u], v);
      }
  }
  __syncthreads();

  f32x4 accO[3][4];
  #pragma unroll
  for (int i = 0; i < 3; ++i)
    #pragma unroll
    for (int j = 0; j < 4; ++j)
      #pragma unroll
      for (int z = 0; z < 4; ++z) accO[i][j][z] = 0.f;
  #pragma unroll
  for (int ks = 0; ks < 2; ++ks) {
    f16x8 ap[3], bvv[4];
    #pragma unroll
    for (int mu = 0; mu < 3; ++mu)
      ap[mu] = *(const f16x8*)(Ps + (mu * 16 + frow) * 264 + wave * 64 + ks * 32 + fk);
    #pragma unroll
    for (int nd = 0; nd < 4; ++nd)
      bvv[nd] = *(const f16x8*)(Vt + (nd * 16 + frow) * 264 + wave * 64 + ks * 32 + fk);
    #pragma unroll
    for (int mu = 0; mu < 3; ++mu)
      #pragma unroll
      for (int nd = 0; nd < 4; ++nd)
        accO[mu][nd] = __builtin_amdgcn_mfma_f32_16x16x32_f16(ap[mu], bvv[nd], accO[mu][nd], 0, 0, 0);
  }
  __syncthreads();   // Ps/Vt reads done; red (aliased) writes safe

  #pragma unroll
  for (int mu = 0; mu < 3; ++mu) {
    #pragma unroll
    for (int nd = 0; nd < 4; ++nd) {
      int d = nd * 16 + (lane & 15);
      #pragma unroll
      for (int z = 0; z < 4; ++z) {
        int u = mu * 16 + (lane >> 4) * 4 + z;
        red[wave * 3072 + u * 64 + d] = accO[mu][nd][z];
      }
    }
  }
  __syncthreads();
  for (int i = tid; i < 3072; i += 256) {
    int u = i >> 6;
    if (u < SK)
      atomicAdd(&OT[((size_t)bh * SK + u) * DH + (i & 63)],
                red[i] + red[3072 + i] + red[6144 + i] + red[9216 + i]);
  }
}

// ---------------- out = broadcast(base) ----------------
__global__ __launch_bounds__(256) void basewrite_kernel(const float* __restrict__ base,
                                                        float* __restrict__ out) {
  size_t i = (size_t)blockIdx.x * 256 + threadIdx.x;
  const size_t stride = (size_t)gridDim.x * 256;
  const size_t total = (size_t)B_ * L_ * (DM / 4);
  for (; i < total; i += stride) {
    size_t b = i >> 20;
    size_t c = i & 255;
    ((f32x4*)out)[i] = ((const f32x4*)base)[b * 256 + c];
  }
}

// ---------------- corrections: out[b, top_u, n] += (OT/Z - MV) . Wo[n, h*64:] -----
__global__ __launch_bounds__(256, 2) void corr_kernel(const float* __restrict__ OT,
    const float* __restrict__ Zb, const float* __restrict__ MV,
    const float* __restrict__ Wo, const int* __restrict__ topi,
    float* __restrict__ out) {
  __shared__ float dv[SK][64];
  __shared__ float wo[64][65];
  __shared__ float invz[SK];
  __shared__ int lidx[SK];
  const int bh = blockIdx.x, q = blockIdx.y, tid = threadIdx.x;
  const int b = bh >> 4, h = bh & 15;
  if (tid < SK) {
    invz[tid] = 1.0f / Zb[bh * 48 + tid];
    lidx[tid] = topi[bh * SK + tid];
  }
  __syncthreads();
  for (int i = tid; i < SK * 64; i += 256) {
    int u = i >> 6, d = i & 63;
    dv[u][d] = OT[((size_t)bh * SK + u) * DH + d] * invz[u] - MV[b * DM + h * DH + d];
  }
  const int nn = tid & 63, ug = tid >> 6;
  for (int c = 0; c < 4; ++c) {
    const int n0 = q * 256 + c * 64;
    __syncthreads();
    for (int t = tid; t < 1024; t += 256) {
      int row = t >> 4, vc = t & 15;
      f32x4 v = *(const f32x4*)&Wo[(size_t)(n0 + row) * DM + h * DH + vc * 4];
      *(f32x4*)&wo[row][vc * 4] = v;
    }
    __syncthreads();
    #pragma unroll
    for (int i = 0; i < 12; ++i) {
      int u = ug + i * 4;
      if (u >= SK) break;
      float a0 = 0, a1 = 0, a2 = 0, a3 = 0;
      #pragma unroll
      for (int d4 = 0; d4 < 16; ++d4) {
        f32x4 w = *(const f32x4*)&wo[nn][d4 * 4];
        f32x4 dd = *(const f32x4*)&dv[u][d4 * 4];
        a0 += dd[0] * w[0]; a1 += dd[1] * w[1];
        a2 += dd[2] * w[2]; a3 += dd[3] * w[3];
      }
      atomicAdd(&out[((size_t)b * L_ + lidx[u]) * DM + n0 + nn], (a0 + a1) + (a2 + a3));
    }
  }
}

// ---------------- workspace layout (zero-init region contiguous) ------------------
static const size_t OFF_XH   = 0;                        // 67108864
static const size_t OFF_WQH  = OFF_XH + 67108864;        // 2097152
static const size_t OFF_WQL  = OFF_WQH + 2097152;
static const size_t OFF_WKH  = OFF_WQL + 2097152;
static const size_t OFF_WVH  = OFF_WKH + 2097152;
static const size_t OFF_KS   = OFF_WVH + 2097152;        // 1474560
static const size_t OFF_MV   = OFF_KS + 1474560;         // 32768
static const size_t OFF_BASE = OFF_MV + 32768;           // 32768
static const size_t OFF_TOPI = OFF_BASE + 32768;         // 23040 -> pad 24576
// zero-init block:
static const size_t OFF_MEANX= OFF_TOPI + 24576;         // 32768
static const size_t OFF_ZB   = OFF_MEANX + 32768;        // 24576
static const size_t OFF_QT   = OFF_ZB + 24576;           // 786432
static const size_t OFF_MMAX = OFF_QT + 786432;          // 2097152
static const size_t OFF_MSUM = OFF_MMAX + 2097152;       // 2097152
static const size_t OFF_OT   = OFF_MSUM + 2097152;       // 1474560
static const size_t ZERO_SZ  = OFF_OT + 1474560 - OFF_MEANX;   // 6512640
// end zero block:
static const size_t OFF_PH   = OFF_OT + 1474560;         // 12582912
static const size_t OFF_PL   = OFF_PH + 12582912;        // 12582912
static const size_t WS_NEED  = OFF_PL + 12582912;        // ~108.7 MB

extern "C" void kernel_launch(void* const* d_in, const int* in_sizes, int n_in,
                              void* d_out, int out_size, void* d_ws, size_t ws_size,
                              hipStream_t stream) {
  const float* x  = (const float*)d_in[0];
  const float* Wq = (const float*)d_in[1];
  const float* bq = (const float*)d_in[2];
  const float* Wk = (const float*)d_in[3];
  const float* bk = (const float*)d_in[4];
  const float* Wv = (const float*)d_in[5];
  const float* bv = (const float*)d_in[6];
  const float* Wo = (const float*)d_in[7];
  const float* bo = (const float*)d_in[8];
  const int* sidx = (const int*)d_in[9];
  float* out = (float*)d_out;
  char* ws = (char*)d_ws;

  if (ws_size < WS_NEED) {
    if (ws_size < 131072) return;
    float* MEANX = (float*)(ws + 0);
    float* MV    = (float*)(ws + 32768);
    float* BASE  = (float*)(ws + 65536);
    hipMemsetAsync(MEANX, 0, 32768, stream);
    meansum32_kernel<<<dim3(B_, 4, 16), 256, 0, stream>>>(x, MEANX);
    proj_vec_kernel<<<32, 256, 0, stream>>>(MEANX, Wv, bv, MV, 1.0f / L_);
    proj_vec_kernel<<<32, 256, 0, stream>>>(MV, Wo, bo, BASE, 1.0f);
    basewrite_kernel<<<2048, 256, 0, stream>>>(BASE, out);
    return;
  }

  f16*   XH   = (f16*)(ws + OFF_XH);
  f16*   WQH  = (f16*)(ws + OFF_WQH);
  f16*   WQL  = (f16*)(ws + OFF_WQL);
  f16*   WKH  = (f16*)(ws + OFF_WKH);
  f16*   WVH  = (f16*)(ws + OFF_WVH);
  float* KS   = (float*)(ws + OFF_KS);
  float* MV   = (float*)(ws + OFF_MV);
  float* BASE = (float*)(ws + OFF_BASE);
  int*   TOPI = (int*)(ws + OFF_TOPI);
  float* MEANX= (float*)(ws + OFF_MEANX);
  float* ZB   = (float*)(ws + OFF_ZB);
  f16*   QT   = (f16*)(ws + OFF_QT);
  unsigned* MMAXu = (unsigned*)(ws + OFF_MMAX);
  float* MSUM = (float*)(ws + OFF_MSUM);
  float* OT   = (float*)(ws + OFF_OT);
  f16*   PH   = (f16*)(ws + OFF_PH);
  f16*   PL   = (f16*)(ws + OFF_PL);
  f16*   XL   = (f16*)out;   // x lo-part scratch in d_out (67 MB; dead by basewrite)

  // 1. zero-init, then fused split+mean, weight splits
  hipMemsetAsync(ws + OFF_MEANX, 0, ZERO_SZ, stream);
  xsplitmean_kernel<<<1024, 256, 0, stream>>>(x, XH, XL, MEANX);
  wsplit3_kernel<<<dim3(256, 3), 256, 0, stream>>>(Wq, Wk, Wv, WQH, WQL, WKH, WVH,
                                                   DM * DM / 4);

  // 2. mean path
  proj_vec_kernel<<<32, 256, 0, stream>>>(MEANX, Wv, bv, MV, 1.0f / L_);
  proj_vec_kernel<<<32, 256, 0, stream>>>(MV, Wo, bo, BASE, 1.0f);

  // 3. sampled K rows -> P(scaled) -> scores GEMM (all-gload_lds) + m-statistics
  ksample_kernel<<<dim3(B_, 16, 9), 256, 0, stream>>>(x, Wk, bk, sidx, KS);
  pcomp_kernel<<<dim3(B_, NH, 16), 256, 0, stream>>>(Wq, KS, PH, PL);
  gemm_sc<<<dim3(8, 192), 256, 0, stream>>>(XH, XL, PH, PL, MMAXu, MSUM);

  // 4. top-k (packed-key argmax) + q_top recompute
  topk_kernel<<<B_ * NH, 256, 0, stream>>>(MMAXu, MSUM, TOPI);
  qtop5_kernel<<<dim3(B_, NH, 9), 256, 0, stream>>>(x, Wq, bq, TOPI, QT);

  // 5. fully fused K+V GEMM + scores + exp-PV
  kscore_kernel<<<dim3(128, 16), 256, 0, stream>>>(XH, WKH, WVH, bk, bv, QT, OT, ZB);

  // 6. output assembly (overwrites XL scratch)
  basewrite_kernel<<<2048, 256, 0, stream>>>(BASE, out);
  corr_kernel<<<dim3(B_ * NH, 4), 256, 0, stream>>>(OT, ZB, MV, Wo, TOPI, out);
}

// Round 17
// 703.091 us; speedup vs baseline: 1.4130x; 1.0100x over previous
//
#include <hip/hip_runtime.h>
#include <cfloat>
#include <cstdint>

#define B_  8
#define L_  4096
#define DM  1024
#define NH  16
#define DH  64
#define SK  45

typedef __attribute__((ext_vector_type(4))) float f32x4;
typedef _Float16 f16;
typedef __attribute__((ext_vector_type(4))) _Float16 f16x4;
typedef __attribute__((ext_vector_type(8))) _Float16 f16x8;

__device__ __forceinline__ void gload_lds16(const void* g, void* l) {
  __builtin_amdgcn_global_load_lds(
      (const __attribute__((address_space(1))) unsigned int*)g,
      (__attribute__((address_space(3))) unsigned int*)l, 16, 0, 0);
}

// XOR-swizzled f16 index into a [rows][32] f16 tile (64B rows), granule 8 f16.
__device__ __forceinline__ int swz(int row, int c) {
  return row * 32 + (c ^ (((row >> 1) & 3) << 3));
}

// ---- x f32 -> f16 hi (ws) + f16 lo*2048 (d_out scratch) + fused column mean -----
__global__ __launch_bounds__(256) void xsplitmean_kernel(const float* __restrict__ x,
    f16* __restrict__ xh, f16* __restrict__ xl, float* __restrict__ meanx) {
  const int r0 = blockIdx.x * 32;
  const int b = r0 >> 12;
  const int d0 = threadIdx.x * 4;
  float s0 = 0.f, s1 = 0.f, s2 = 0.f, s3 = 0.f;
  for (int i = 0; i < 32; ++i) {
    const size_t off = (size_t)(r0 + i) * DM + d0;
    f32x4 v = *(const f32x4*)(x + off);
    f16x4 h, l;
    #pragma unroll
    for (int j = 0; j < 4; ++j) {
      h[j] = (f16)v[j];
      l[j] = (f16)((v[j] - (float)h[j]) * 2048.0f);
    }
    *(f16x4*)(xh + off) = h;
    *(f16x4*)(xl + off) = l;
    s0 += v[0]; s1 += v[1]; s2 += v[2]; s3 += v[3];
  }
  atomicAdd(&meanx[b * DM + d0 + 0], s0);
  atomicAdd(&meanx[b * DM + d0 + 1], s1);
  atomicAdd(&meanx[b * DM + d0 + 2], s2);
  atomicAdd(&meanx[b * DM + d0 + 3], s3);
}

// ---------------- Wk, Wv f32 -> f16 in one launch (Wq splits are dead) ------------
__global__ __launch_bounds__(256) void wsplit2_kernel(const float* __restrict__ Wk,
    const float* __restrict__ Wv, f16* __restrict__ WKH, f16* __restrict__ WVH,
    int n4) {
  const int which = blockIdx.y;
  const float* w = (which == 0) ? Wk : Wv;
  f16* wh = (which == 0) ? WKH : WVH;
  int i = blockIdx.x * 256 + threadIdx.x;
  int stride = gridDim.x * 256;
  for (; i < n4; i += stride) {
    f32x4 v = ((const f32x4*)w)[i];
    f16x4 h;
    #pragma unroll
    for (int j = 0; j < 4; ++j) h[j] = (f16)v[j];
    ((f16x4*)wh)[i] = h;
  }
}

// f32 mean fallback (small-ws diagnostic path)
__global__ __launch_bounds__(256) void meansum32_kernel(const float* __restrict__ x,
                                                        float* __restrict__ meanx) {
  int b = blockIdx.x;
  int d = blockIdx.y * 256 + threadIdx.x;
  int l0 = blockIdx.z * 256;
  const float* p = x + ((size_t)b * L_ + l0) * DM + d;
  float s = 0.f;
  for (int i = 0; i < 256; ++i) s += p[(size_t)i * DM];
  atomicAdd(&meanx[b * DM + d], s);
}

// vout(b,n) = (vin(b,:) . W[n,:]) * scale + bias[n]
__global__ __launch_bounds__(256) void proj_vec_kernel(const float* __restrict__ vin,
    const float* __restrict__ W, const float* __restrict__ bias,
    float* __restrict__ vout, float scale) {
  int g = blockIdx.x * 256 + threadIdx.x;
  int b = g >> 10, n = g & 1023;
  const float* xr = vin + b * DM;
  const float* wr = W + (size_t)n * DM;
  float a0 = 0, a1 = 0, a2 = 0, a3 = 0;
  for (int d = 0; d < DM; d += 4) {
    a0 += xr[d + 0] * wr[d + 0];
    a1 += xr[d + 1] * wr[d + 1];
    a2 += xr[d + 2] * wr[d + 2];
    a3 += xr[d + 3] * wr[d + 3];
  }
  vout[g] = ((a0 + a1) + (a2 + a3)) * scale + bias[n];
}

// ---------------- k_sample rows, f32 LDS-tiled: KS[b][s][n] ----------------
__global__ __launch_bounds__(256, 4) void ksample_kernel(const float* __restrict__ x,
    const float* __restrict__ Wk, const float* __restrict__ bk,
    const int* __restrict__ sidx, float* __restrict__ KS) {
  const int b = blockIdx.x, nc = blockIdx.y, sg = blockIdx.z;
  __shared__ float xs[5][32];
  __shared__ float wk[64][33];
  __shared__ float red[4][5][64];
  __shared__ int ls[5];
  const int tid = threadIdx.x;
  const int nl = tid & 63, kq = tid >> 6;
  if (tid < 5) ls[tid] = sidx[sg * 5 + tid];
  float acc[5] = {0.f, 0.f, 0.f, 0.f, 0.f};
  const int wrow = tid >> 2, wq = tid & 3;
  for (int kt = 0; kt < 32; ++kt) {
    const int d0 = kt * 32;
    __syncthreads();
    if (tid < 40) {
      int s = tid >> 3, q = tid & 7;
      *(f32x4*)&xs[s][q * 4] = *(const f32x4*)&x[((size_t)b * L_ + ls[s]) * DM + d0 + q * 4];
    }
    {
      const float* src = &Wk[(size_t)(nc * 64 + wrow) * DM + d0 + wq * 8];
      *(f32x4*)&wk[wrow][wq * 8]     = *(const f32x4*)src;
      *(f32x4*)&wk[wrow][wq * 8 + 4] = *(const f32x4*)(src + 4);
    }
    __syncthreads();
    #pragma unroll
    for (int i = 0; i < 2; ++i) {
      f32x4 w = *(const f32x4*)&wk[nl][kq * 8 + i * 4];
      #pragma unroll
      for (int s = 0; s < 5; ++s) {
        f32x4 xv = *(const f32x4*)&xs[s][kq * 8 + i * 4];
        acc[s] += xv[0] * w[0] + xv[1] * w[1] + xv[2] * w[2] + xv[3] * w[3];
      }
    }
  }
  #pragma unroll
  for (int s = 0; s < 5; ++s) red[kq][s][nl] = acc[s];
  __syncthreads();
  for (int t = tid; t < 5 * 64; t += 256) {
    int s = t >> 6, j = t & 63;
    int nj = nc * 64 + j;
    KS[((size_t)b * SK + sg * 5 + s) * DM + nj] =
        red[0][s][j] + red[1][s][j] + red[2][s][j] + red[3][s][j] + bk[nj];
  }
}

// ---- P[b][h*48+s][nc*64+c] = 0.125 * sum_d Wq[h*64+d][c'] * KS[b][s][h*64+d] -----
__global__ __launch_bounds__(256, 4) void pcomp_kernel(const float* __restrict__ Wq,
    const float* __restrict__ KS, f16* __restrict__ PH, f16* __restrict__ PL) {
  const int b = blockIdx.x, h = blockIdx.y, nc = blockIdx.z;
  __shared__ float ks[45][64];
  __shared__ float wqT[64][68];
  const int tid = threadIdx.x;
  const int n0 = nc * 64;
  for (int i = tid; i < 45 * 64; i += 256) {
    int s = i >> 6, d = i & 63;
    ks[s][d] = KS[((size_t)b * SK + s) * DM + h * 64 + d];
  }
  for (int t = tid; t < 1024; t += 256) {
    int row = t >> 4, cg = t & 15;
    f32x4 v = *(const f32x4*)&Wq[(size_t)(h * 64 + row) * DM + n0 + cg * 4];
    #pragma unroll
    for (int j = 0; j < 4; ++j) wqT[cg * 4 + j][row] = v[j];
  }
  __syncthreads();
  for (int t = tid; t < 48 * 64; t += 256) {
    int s = t >> 6, c = t & 63;
    float acc = 0.f;
    if (s < SK) {
      const f32x4* wr = (const f32x4*)&wqT[c][0];
      const f32x4* kr = (const f32x4*)&ks[s][0];
      float a0 = 0, a1 = 0, a2 = 0, a3 = 0;
      #pragma unroll
      for (int i = 0; i < 16; ++i) {
        f32x4 wv = wr[i], kv = kr[i];
        a0 += wv[0] * kv[0]; a1 += wv[1] * kv[1];
        a2 += wv[2] * kv[2]; a3 += wv[3] * kv[3];
      }
      acc = ((a0 + a1) + (a2 + a3)) * 0.125f;
    }
    f16 hv = (f16)acc;
    size_t off = ((size_t)b * 768 + h * 48 + s) * DM + n0 + c;
    PH[off] = hv;
    PL[off] = (f16)((acc - (float)hv) * 2048.0f);
  }
}

// ---- scores GEMM + fused m-statistics; A staged via global_load_lds from XH/XL ---
__global__ __launch_bounds__(256, 2) void gemm_sc(const f16* __restrict__ XH,
    const f16* __restrict__ XL, const f16* __restrict__ PH,
    const f16* __restrict__ PL, unsigned* __restrict__ MMAXu,
    float* __restrict__ MSUM) {
  __shared__ __align__(16) char pool[33792];
  f16* xh = (f16*)pool;                 // phase A: 8192
  f16* xl = (f16*)(pool + 8192);
  f16* wh = (f16*)(pool + 16384);
  f16* wl = (f16*)(pool + 24576);       // ends 32768
  float* scf = (float*)pool;            // phase B: [64][132] f32 = 33792
  const int tid = threadIdx.x;
  const int g = blockIdx.y * 8 + blockIdx.x;    // XCD = g & 7
  const int q = g >> 3;                          // 0..191
  const int nt = q % 6;                          // N-tile cycles fastest
  const int mt = (g & 7) + (q / 6) * 8;          // A-panel pinned to XCD
  const int n0 = nt * 128;
  const int m0 = mt * 128;
  const int bb = mt >> 5;                        // batch of this M-tile
  const int lane = tid & 63;
  const int wave = tid >> 6;
  const int wr = (wave >> 1) * 64;
  const int wc = (wave & 1) * 64;
  const int frow = lane & 15;
  const int fk = (lane >> 4) * 8;

  f32x4 aH[4][4], aL[4][4];
  #pragma unroll
  for (int i = 0; i < 4; ++i)
    #pragma unroll
    for (int j = 0; j < 4; ++j)
      #pragma unroll
      for (int z = 0; z < 4; ++z) { aH[i][j][z] = 0.f; aL[i][j][z] = 0.f; }

  const int r2 = tid >> 2;
  const int cb = (tid & 3) * 8;
  const int cbs = cb ^ (((r2 >> 1) & 3) << 3);   // pre-swizzled source col

  const size_t pbase = (size_t)bb * 768;
  for (int kt = 0; kt < 32; ++kt) {
    const int kcol = kt * 32;
    gload_lds16(XH + (size_t)(m0 + r2) * DM + kcol + cbs,      xh + r2 * 32 + cb);
    gload_lds16(XH + (size_t)(m0 + r2 + 64) * DM + kcol + cbs, xh + (r2 + 64) * 32 + cb);
    gload_lds16(XL + (size_t)(m0 + r2) * DM + kcol + cbs,      xl + r2 * 32 + cb);
    gload_lds16(XL + (size_t)(m0 + r2 + 64) * DM + kcol + cbs, xl + (r2 + 64) * 32 + cb);
    gload_lds16(PH + (pbase + n0 + r2) * DM + kcol + cbs,      wh + r2 * 32 + cb);
    gload_lds16(PH + (pbase + n0 + r2 + 64) * DM + kcol + cbs, wh + (r2 + 64) * 32 + cb);
    gload_lds16(PL + (pbase + n0 + r2) * DM + kcol + cbs,      wl + r2 * 32 + cb);
    gload_lds16(PL + (pbase + n0 + r2 + 64) * DM + kcol + cbs, wl + (r2 + 64) * 32 + cb);
    __syncthreads();
    f16x8 ah[4], al[4], bh[4], bl[4];
    #pragma unroll
    for (int mi = 0; mi < 4; ++mi) {
      ah[mi] = *(const f16x8*)(xh + swz(wr + mi * 16 + frow, fk));
      al[mi] = *(const f16x8*)(xl + swz(wr + mi * 16 + frow, fk));
    }
    #pragma unroll
    for (int ni = 0; ni < 4; ++ni) {
      bh[ni] = *(const f16x8*)(wh + swz(wc + ni * 16 + frow, fk));
      bl[ni] = *(const f16x8*)(wl + swz(wc + ni * 16 + frow, fk));
    }
    #pragma unroll
    for (int mi = 0; mi < 4; ++mi)
      #pragma unroll
      for (int ni = 0; ni < 4; ++ni) {
        aH[mi][ni] = __builtin_amdgcn_mfma_f32_16x16x32_f16(ah[mi], bh[ni], aH[mi][ni], 0, 0, 0);
        aL[mi][ni] = __builtin_amdgcn_mfma_f32_16x16x32_f16(ah[mi], bl[ni], aL[mi][ni], 0, 0, 0);
        aL[mi][ni] = __builtin_amdgcn_mfma_f32_16x16x32_f16(al[mi], bh[ni], aL[mi][ni], 0, 0, 0);
      }
    __syncthreads();
  }

  // fused epilogue: two 64-row halves through aliased LDS -> per-(row,h) partials
  const int hbase = n0 / 48;
  #pragma unroll
  for (int half = 0; half < 2; ++half) {
    __syncthreads();
    if ((wave >> 1) == half) {
      #pragma unroll
      for (int mi = 0; mi < 4; ++mi)
        #pragma unroll
        for (int ni = 0; ni < 4; ++ni) {
          int coll = wc + ni * 16 + (lane & 15);
          #pragma unroll
          for (int j = 0; j < 4; ++j) {
            int rowl = mi * 16 + (lane >> 4) * 4 + j;
            scf[rowl * 132 + coll] = aH[mi][ni][j] + aL[mi][ni][j] * (1.0f / 2048.0f);
          }
        }
    }
    __syncthreads();
    {
      int row = tid >> 2, gidx = tid & 3;
      int h = hbase + gidx;
      if (h < NH) {
        int slo = n0 - h * 48; if (slo < 0) slo = 0;
        int shi = n0 + 128 - h * 48; if (shi > SK) shi = SK;
        if (slo < shi) {
          float mx = -FLT_MAX, sum = 0.f;
          const float* pr = scf + row * 132 + (h * 48 - n0);
          for (int s = slo; s < shi; ++s) {
            float v = pr[s];
            mx = fmaxf(mx, v);
            sum += v;
          }
          int gl = (m0 & 4095) + half * 64 + row;
          size_t idx = ((size_t)(bb * NH + h)) * L_ + gl;
          int bmx = __float_as_int(mx);
          unsigned key = (unsigned)(bmx ^ ((bmx >> 31) | (int)0x80000000));
          atomicMax(&MMAXu[idx], key);
          atomicAdd(&MSUM[idx], sum);
        }
      }
    }
  }
}

// ---------------- top-45: decode m, packed 64-bit-key iterative argmax ------------
__global__ __launch_bounds__(256) void topk_kernel(const unsigned* __restrict__ MMAXu,
    const float* __restrict__ MSUM, int* __restrict__ topi) {
  __shared__ float vals[L_];
  __shared__ unsigned long long wk[4];
  const int bh = blockIdx.x, tid = threadIdx.x;
  for (int i = tid; i < L_; i += 256) {
    unsigned key = MMAXu[(size_t)bh * L_ + i];
    int bits = (key & 0x80000000u) ? (int)(key ^ 0x80000000u) : ~(int)key;
    vals[i] = __int_as_float(bits) - MSUM[(size_t)bh * L_ + i] * (1.0f / SK);
  }
  __syncthreads();
  const int lane = tid & 63, wave = tid >> 6;
  for (int it = 0; it < SK; ++it) {
    unsigned long long best = 0ull;
    for (int i = tid; i < L_; i += 256) {
      int b = __float_as_int(vals[i]);
      unsigned e = (unsigned)(b ^ ((b >> 31) | (int)0x80000000));
      unsigned long long key =
          ((unsigned long long)e << 32) | (unsigned)(0xFFFFFFFFu - i);
      if (key > best) best = key;
    }
    #pragma unroll
    for (int off = 32; off; off >>= 1) {
      unsigned long long o = __shfl_xor(best, off);
      if (o > best) best = o;
    }
    if (lane == 0) wk[wave] = best;
    __syncthreads();
    if (tid == 0) {
      unsigned long long bb = wk[0];
      if (wk[1] > bb) bb = wk[1];
      if (wk[2] > bb) bb = wk[2];
      if (wk[3] > bb) bb = wk[3];
      int bj = (int)(0xFFFFFFFFu - (unsigned)(bb & 0xFFFFFFFFu));
      topi[bh * SK + it] = bj;
      vals[bj] = -FLT_MAX;
    }
    __syncthreads();
  }
}

// ---- q_top recompute, ksample-style f32 tiles: QT[bh][48][64] f16 ----------------
__global__ __launch_bounds__(256, 4) void qtop5_kernel(const float* __restrict__ x,
    const float* __restrict__ Wq, const float* __restrict__ bq,
    const int* __restrict__ topi, f16* __restrict__ QT) {
  const int b = blockIdx.x, h = blockIdx.y, sg = blockIdx.z;
  const int bh = b * NH + h;
  __shared__ float xs[5][32];
  __shared__ float wq[64][33];
  __shared__ float red[4][5][64];
  __shared__ int ls[5];
  const int tid = threadIdx.x;
  const int nl = tid & 63, kq = tid >> 6;
  if (tid < 5) ls[tid] = topi[bh * SK + sg * 5 + tid];
  float acc[5] = {0.f, 0.f, 0.f, 0.f, 0.f};
  const int wrow = tid >> 2, wqc = tid & 3;
  for (int kt = 0; kt < 32; ++kt) {
    const int d0 = kt * 32;
    __syncthreads();
    if (tid < 40) {
      int s = tid >> 3, q = tid & 7;
      *(f32x4*)&xs[s][q * 4] = *(const f32x4*)&x[((size_t)b * L_ + ls[s]) * DM + d0 + q * 4];
    }
    {
      const float* src = &Wq[(size_t)(h * 64 + wrow) * DM + d0 + wqc * 8];
      *(f32x4*)&wq[wrow][wqc * 8]     = *(const f32x4*)src;
      *(f32x4*)&wq[wrow][wqc * 8 + 4] = *(const f32x4*)(src + 4);
    }
    __syncthreads();
    #pragma unroll
    for (int i = 0; i < 2; ++i) {
      f32x4 w = *(const f32x4*)&wq[nl][kq * 8 + i * 4];
      #pragma unroll
      for (int s = 0; s < 5; ++s) {
        f32x4 xv = *(const f32x4*)&xs[s][kq * 8 + i * 4];
        acc[s] += xv[0] * w[0] + xv[1] * w[1] + xv[2] * w[2] + xv[3] * w[3];
      }
    }
  }
  #pragma unroll
  for (int s = 0; s < 5; ++s) red[kq][s][nl] = acc[s];
  __syncthreads();
  for (int t = tid; t < 5 * 64; t += 256) {
    int s = t >> 6, j = t & 63;
    QT[bh * 3072 + (sg * 5 + s) * 64 + j] =
        (f16)(red[0][s][j] + red[1][s][j] + red[2][s][j] + red[3][s][j] + bq[h * 64 + j]);
  }
}

// ---- fused K+V GEMM + scores + inline-exp PV: atomics into OT, Zb. No S/V in HBM.
__global__ __launch_bounds__(256, 2) void kscore_kernel(const f16* __restrict__ XH,
    const f16* __restrict__ WKH, const f16* __restrict__ WVH,
    const float* __restrict__ bk, const float* __restrict__ bvec,
    const f16* __restrict__ QT, float* __restrict__ OT, float* __restrict__ Zb) {
  __shared__ __align__(16) char smem[68352];
  f16* qs = (f16*)smem;                  // phase1-2: 48*72*2 = 6912
  f16* xh = (f16*)(smem + 6912);         // phase1:   16384
  f16* wh = (f16*)(smem + 23296);        // phase1:   8192
  f16* Kt = (f16*)(smem + 31488);        // phase2:   256*72*2 = 36864
  f16* Ps = (f16*)smem;                  // phase3-4: 48*264*2 = 25344 (over qs/xh)
  f16* Vt = (f16*)(smem + 31488);        // phase3-4: 64*264*2 = 33792 (over Kt)
  float* red = (float*)smem;             // phase5:   4*48*64*4 = 49152
  const int g = blockIdx.y * 128 + blockIdx.x;  // XCD = g & 7
  const int b = g & 7;
  const int p = g >> 3;
  const int jc = p >> 4;
  const int h = p & 15;
  const int bh = b * 16 + h;
  const int tid = threadIdx.x;
  const int lane = tid & 63, wave = tid >> 6;
  const int frow = lane & 15;
  const int fk = (lane >> 4) * 8;

  for (int i = tid; i < 48 * 64; i += 256)
    qs[(i >> 6) * 72 + (i & 63)] = QT[bh * 3072 + i];

  f32x4 accK[4][4], accV[4][4];
  #pragma unroll
  for (int i = 0; i < 4; ++i)
    #pragma unroll
    for (int j = 0; j < 4; ++j)
      #pragma unroll
      for (int z = 0; z < 4; ++z) { accK[i][j][z] = 0.f; accV[i][j][z] = 0.f; }

  const int r2 = tid >> 2, cb = (tid & 3) * 8;
  const int cbs = cb ^ (((r2 >> 1) & 3) << 3);
  for (int kt = 0; kt < 32; ++kt) {
    #pragma unroll
    for (int i = 0; i < 4; ++i)
      gload_lds16(XH + (size_t)(b * L_ + jc * 256 + i * 64 + r2) * DM + kt * 32 + cbs,
                  xh + (i * 64 + r2) * 32 + cb);
    gload_lds16(WKH + (size_t)(h * 64 + r2) * DM + kt * 32 + cbs, wh + r2 * 32 + cb);
    gload_lds16(WVH + (size_t)(h * 64 + r2) * DM + kt * 32 + cbs, wh + (r2 + 64) * 32 + cb);
    __syncthreads();
    f16x8 am[4], bnK[4], bnV[4];
    #pragma unroll
    for (int mi = 0; mi < 4; ++mi)
      am[mi] = *(const f16x8*)(xh + swz(wave * 64 + mi * 16 + frow, fk));
    #pragma unroll
    for (int ni = 0; ni < 4; ++ni) {
      bnK[ni] = *(const f16x8*)(wh + swz(ni * 16 + frow, fk));
      bnV[ni] = *(const f16x8*)(wh + swz(64 + ni * 16 + frow, fk));
    }
    #pragma unroll
    for (int mi = 0; mi < 4; ++mi)
      #pragma unroll
      for (int ni = 0; ni < 4; ++ni) {
        accK[mi][ni] = __builtin_amdgcn_mfma_f32_16x16x32_f16(am[mi], bnK[ni], accK[mi][ni], 0, 0, 0);
        accV[mi][ni] = __builtin_amdgcn_mfma_f32_16x16x32_f16(am[mi], bnV[ni], accV[mi][ni], 0, 0, 0);
      }
    __syncthreads();
  }

  #pragma unroll
  for (int mi = 0; mi < 4; ++mi) {
    int jl = wave * 64 + mi * 16 + (lane >> 4) * 4;
    #pragma unroll
    for (int ni = 0; ni < 4; ++ni) {
      int d = ni * 16 + (lane & 15);
      float bc = bk[h * 64 + d];
      #pragma unroll
      for (int z = 0; z < 4; ++z)
        Kt[(jl + z) * 72 + d] = (f16)(accK[mi][ni][z] + bc);
    }
  }
  __syncthreads();

  f32x4 accS[3][4];
  #pragma unroll
  for (int i = 0; i < 3; ++i)
    #pragma unroll
    for (int j = 0; j < 4; ++j)
      #pragma unroll
      for (int z = 0; z < 4; ++z) accS[i][j][z] = 0.f;
  #pragma unroll
  for (int ks = 0; ks < 2; ++ks) {
    f16x8 aq[3], bv[4];
    #pragma unroll
    for (int mu = 0; mu < 3; ++mu)
      aq[mu] = *(const f16x8*)(qs + (mu * 16 + frow) * 72 + ks * 32 + fk);
    #pragma unroll
    for (int nj = 0; nj < 4; ++nj)
      bv[nj] = *(const f16x8*)(Kt + (wave * 64 + nj * 16 + frow) * 72 + ks * 32 + fk);
    #pragma unroll
    for (int mu = 0; mu < 3; ++mu)
      #pragma unroll
      for (int nj = 0; nj < 4; ++nj)
        accS[mu][nj] = __builtin_amdgcn_mfma_f32_16x16x32_f16(aq[mu], bv[nj], accS[mu][nj], 0, 0, 0);
  }
  __syncthreads();   // qs/Kt reads done; Ps/Vt (aliased) writes are now safe

  #pragma unroll
  for (int mi = 0; mi < 4; ++mi) {
    int jl = wave * 64 + mi * 16 + (lane >> 4) * 4;
    #pragma unroll
    for (int ni = 0; ni < 4; ++ni) {
      int d = ni * 16 + (lane & 15);
      float bc = bvec[h * 64 + d];
      #pragma unroll
      for (int z = 0; z < 4; ++z)
        Vt[d * 264 + jl + z] = (f16)(accV[mi][ni][z] + bc);
    }
  }
  {
    float zs[3][4];
    #pragma unroll
    for (int mu = 0; mu < 3; ++mu)
      #pragma unroll
      for (int z = 0; z < 4; ++z) zs[mu][z] = 0.f;
    #pragma unroll
    for (int mu = 0; mu < 3; ++mu)
      #pragma unroll
      for (int nj = 0; nj < 4; ++nj) {
        int j = wave * 64 + nj * 16 + (lane & 15);
        #pragma unroll
        for (int z = 0; z < 4; ++z) {
          int u = mu * 16 + (lane >> 4) * 4 + z;
          float pv = __expf(accS[mu][nj][z] * 0.125f);
          Ps[u * 264 + j] = (f16)pv;
          zs[mu][z] += pv;
        }
      }
    #pragma unroll
    for (int mu = 0; mu < 3; ++mu)
      #pragma unroll
      for (int z = 0; z < 4; ++z) {
        float v = zs[mu][z];
        v += __shfl_xor(v, 1);
        v += __shfl_xor(v, 2);
        v += __shfl_xor(v, 4);
        v += __shfl_xor(v, 8);
        int u = mu * 16 + (lane >> 4) * 4 + z;
        if ((lane & 15) == 0 && u < SK) atomicAdd(&Zb[bh * 48 + u], v);
      }
  }
  __syncthreads();

  f32x4 accO[3][4];
  #pragma unroll
  for (int i = 0; i < 3; ++i)
    #pragma unroll
    for (int j = 0; j < 4; ++j)
      #pragma unroll
      for (int z = 0; z < 4; ++z) accO[i][j][z] = 0.f;
  #pragma unroll
  for (int ks = 0; ks < 2; ++ks) {
    f16x8 ap[3], bvv[4];
    #pragma unroll
    for (int mu = 0; mu < 3; ++mu)
      ap[mu] = *(const f16x8*)(Ps + (mu * 16 + frow) * 264 + wave * 64 + ks * 32 + fk);
    #pragma unroll
    for (int nd = 0; nd < 4; ++nd)
      bvv[nd] = *(const f16x8*)(Vt + (nd * 16 + frow) * 264 + wave * 64 + ks * 32 + fk);
    #pragma unroll
    for (int mu = 0; mu < 3; ++mu)
      #pragma unroll
      for (int nd = 0; nd < 4; ++nd)
        accO[mu][nd] = __builtin_amdgcn_mfma_f32_16x16x32_f16(ap[mu], bvv[nd], accO[mu][nd], 0, 0, 0);
  }
  __syncthreads();   // Ps/Vt reads done; red (aliased) writes safe

  #pragma unroll
  for (int mu = 0; mu < 3; ++mu) {
    #pragma unroll
    for (int nd = 0; nd < 4; ++nd) {
      int d = nd * 16 + (lane & 15);
      #pragma unroll
      for (int z = 0; z < 4; ++z) {
        int u = mu * 16 + (lane >> 4) * 4 + z;
        red[wave * 3072 + u * 64 + d] = accO[mu][nd][z];
      }
    }
  }
  __syncthreads();
  for (int i = tid; i < 3072; i += 256) {
    int u = i >> 6;
    if (u < SK)
      atomicAdd(&OT[((size_t)bh * SK + u) * DH + (i & 63)],
                red[i] + red[3072 + i] + red[6144 + i] + red[9216 + i]);
  }
}

// ---------------- out = broadcast(base) ----------------
__global__ __launch_bounds__(256) void basewrite_kernel(const float* __restrict__ base,
                                                        float* __restrict__ out) {
  size_t i = (size_t)blockIdx.x * 256 + threadIdx.x;
  const size_t stride = (size_t)gridDim.x * 256;
  const size_t total = (size_t)B_ * L_ * (DM / 4);
  for (; i < total; i += stride) {
    size_t b = i >> 20;
    size_t c = i & 255;
    ((f32x4*)out)[i] = ((const f32x4*)base)[b * 256 + c];
  }
}

// ---- corrections: grid (BH,16), one 64-col chunk per block (4x parallelism) -----
__global__ __launch_bounds__(256, 2) void corr_kernel(const float* __restrict__ OT,
    const float* __restrict__ Zb, const float* __restrict__ MV,
    const float* __restrict__ Wo, const int* __restrict__ topi,
    float* __restrict__ out) {
  __shared__ float dv[SK][64];
  __shared__ float wo[64][65];
  __shared__ float invz[SK];
  __shared__ int lidx[SK];
  const int bh = blockIdx.x, q = blockIdx.y, tid = threadIdx.x;
  const int b = bh >> 4, h = bh & 15;
  const int n0 = q * 64;
  if (tid < SK) {
    invz[tid] = 1.0f / Zb[bh * 48 + tid];
    lidx[tid] = topi[bh * SK + tid];
  }
  __syncthreads();
  for (int i = tid; i < SK * 64; i += 256) {
    int u = i >> 6, d = i & 63;
    dv[u][d] = OT[((size_t)bh * SK + u) * DH + d] * invz[u] - MV[b * DM + h * DH + d];
  }
  for (int t = tid; t < 1024; t += 256) {
    int row = t >> 4, vc = t & 15;
    f32x4 v = *(const f32x4*)&Wo[(size_t)(n0 + row) * DM + h * DH + vc * 4];
    *(f32x4*)&wo[row][vc * 4] = v;
  }
  __syncthreads();
  const int nn = tid & 63, ug = tid >> 6;
  #pragma unroll
  for (int i = 0; i < 12; ++i) {
    int u = ug + i * 4;
    if (u >= SK) break;
    float a0 = 0, a1 = 0, a2 = 0, a3 = 0;
    #pragma unroll
    for (int d4 = 0; d4 < 16; ++d4) {
      f32x4 w = *(const f32x4*)&wo[nn][d4 * 4];
      f32x4 dd = *(const f32x4*)&dv[u][d4 * 4];
      a0 += dd[0] * w[0]; a1 += dd[1] * w[1];
      a2 += dd[2] * w[2]; a3 += dd[3] * w[3];
    }
    atomicAdd(&out[((size_t)b * L_ + lidx[u]) * DM + n0 + nn], (a0 + a1) + (a2 + a3));
  }
}

// ---------------- workspace layout (zero-init region contiguous) ------------------
static const size_t OFF_XH   = 0;                        // 67108864
static const size_t OFF_WQH  = OFF_XH + 67108864;        // 2097152 (unused, kept)
static const size_t OFF_WQL  = OFF_WQH + 2097152;        // (unused, kept)
static const size_t OFF_WKH  = OFF_WQL + 2097152;
static const size_t OFF_WVH  = OFF_WKH + 2097152;
static const size_t OFF_KS   = OFF_WVH + 2097152;        // 1474560
static const size_t OFF_MV   = OFF_KS + 1474560;         // 32768
static const size_t OFF_BASE = OFF_MV + 32768;           // 32768
static const size_t OFF_TOPI = OFF_BASE + 32768;         // 23040 -> pad 24576
// zero-init block:
static const size_t OFF_MEANX= OFF_TOPI + 24576;         // 32768
static const size_t OFF_ZB   = OFF_MEANX + 32768;        // 24576
static const size_t OFF_QT   = OFF_ZB + 24576;           // 786432
static const size_t OFF_MMAX = OFF_QT + 786432;          // 2097152
static const size_t OFF_MSUM = OFF_MMAX + 2097152;       // 2097152
static const size_t OFF_OT   = OFF_MSUM + 2097152;       // 1474560
static const size_t ZERO_SZ  = OFF_OT + 1474560 - OFF_MEANX;   // 6512640
// end zero block:
static const size_t OFF_PH   = OFF_OT + 1474560;         // 12582912
static const size_t OFF_PL   = OFF_PH + 12582912;        // 12582912
static const size_t WS_NEED  = OFF_PL + 12582912;        // ~108.7 MB

extern "C" void kernel_launch(void* const* d_in, const int* in_sizes, int n_in,
                              void* d_out, int out_size, void* d_ws, size_t ws_size,
                              hipStream_t stream) {
  const float* x  = (const float*)d_in[0];
  const float* Wq = (const float*)d_in[1];
  const float* bq = (const float*)d_in[2];
  const float* Wk = (const float*)d_in[3];
  const float* bk = (const float*)d_in[4];
  const float* Wv = (const float*)d_in[5];
  const float* bv = (const float*)d_in[6];
  const float* Wo = (const float*)d_in[7];
  const float* bo = (const float*)d_in[8];
  const int* sidx = (const int*)d_in[9];
  float* out = (float*)d_out;
  char* ws = (char*)d_ws;

  if (ws_size < WS_NEED) {
    if (ws_size < 131072) return;
    float* MEANX = (float*)(ws + 0);
    float* MV    = (float*)(ws + 32768);
    float* BASE  = (float*)(ws + 65536);
    hipMemsetAsync(MEANX, 0, 32768, stream);
    meansum32_kernel<<<dim3(B_, 4, 16), 256, 0, stream>>>(x, MEANX);
    proj_vec_kernel<<<32, 256, 0, stream>>>(MEANX, Wv, bv, MV, 1.0f / L_);
    proj_vec_kernel<<<32, 256, 0, stream>>>(MV, Wo, bo, BASE, 1.0f);
    basewrite_kernel<<<2048, 256, 0, stream>>>(BASE, out);
    return;
  }

  f16*   XH   = (f16*)(ws + OFF_XH);
  f16*   WKH  = (f16*)(ws + OFF_WKH);
  f16*   WVH  = (f16*)(ws + OFF_WVH);
  float* KS   = (float*)(ws + OFF_KS);
  float* MV   = (float*)(ws + OFF_MV);
  float* BASE = (float*)(ws + OFF_BASE);
  int*   TOPI = (int*)(ws + OFF_TOPI);
  float* MEANX= (float*)(ws + OFF_MEANX);
  float* ZB   = (float*)(ws + OFF_ZB);
  f16*   QT   = (f16*)(ws + OFF_QT);
  unsigned* MMAXu = (unsigned*)(ws + OFF_MMAX);
  float* MSUM = (float*)(ws + OFF_MSUM);
  float* OT   = (float*)(ws + OFF_OT);
  f16*   PH   = (f16*)(ws + OFF_PH);
  f16*   PL   = (f16*)(ws + OFF_PL);
  f16*   XL   = (f16*)out;   // x lo-part scratch in d_out (67 MB; dead by basewrite)

  // 1. zero-init, then fused split+mean, weight splits (K,V only; Wq splits dead)
  hipMemsetAsync(ws + OFF_MEANX, 0, ZERO_SZ, stream);
  xsplitmean_kernel<<<1024, 256, 0, stream>>>(x, XH, XL, MEANX);
  wsplit2_kernel<<<dim3(256, 2), 256, 0, stream>>>(Wk, Wv, WKH, WVH, DM * DM / 4);

  // 2. mean path
  proj_vec_kernel<<<32, 256, 0, stream>>>(MEANX, Wv, bv, MV, 1.0f / L_);
  proj_vec_kernel<<<32, 256, 0, stream>>>(MV, Wo, bo, BASE, 1.0f);

  // 3. sampled K rows -> P(scaled) -> scores GEMM (all-gload_lds) + m-statistics
  ksample_kernel<<<dim3(B_, 16, 9), 256, 0, stream>>>(x, Wk, bk, sidx, KS);
  pcomp_kernel<<<dim3(B_, NH, 16), 256, 0, stream>>>(Wq, KS, PH, PL);
  gemm_sc<<<dim3(8, 192), 256, 0, stream>>>(XH, XL, PH, PL, MMAXu, MSUM);

  // 4. top-k (packed-key argmax) + q_top recompute
  topk_kernel<<<B_ * NH, 256, 0, stream>>>(MMAXu, MSUM, TOPI);
  qtop5_kernel<<<dim3(B_, NH, 9), 256, 0, stream>>>(x, Wq, bq, TOPI, QT);

  // 5. fully fused K+V GEMM + scores + exp-PV
  kscore_kernel<<<dim3(128, 16), 256, 0, stream>>>(XH, WKH, WVH, bk, bv, QT, OT, ZB);

  // 6. output assembly (overwrites XL scratch)
  basewrite_kernel<<<2048, 256, 0, stream>>>(BASE, out);
  corr_kernel<<<dim3(B_ * NH, 16), 256, 0, stream>>>(OT, ZB, MV, Wo, TOPI, out);
}